// Round 1
// baseline (7758.430 us; speedup 1.0000x reference)
//
#include <hip/hip_runtime.h>
#include <math.h>

#define NN 50000
#define NE 600000
#define NG 1024
#define NL 5
// Hd = 128, Fin = 74, C = 2

__device__ __forceinline__ float sig_(float x) { return 1.f / (1.f + expf(-x)); }

// ---------------- input projection: h = feats @ W_in + b_in ----------------
__global__ __launch_bounds__(128) void k_input_proj(
    const float* __restrict__ feats, const float* __restrict__ W_in,
    const float* __restrict__ b_in, float* __restrict__ h)
{
  __shared__ float fs[74];
  int n = blockIdx.x;
  int j = threadIdx.x;
  if (j < 74) fs[j] = feats[n * 74 + j];
  __syncthreads();
  float acc = b_in[j];
#pragma unroll
  for (int k = 0; k < 74; ++k) acc = fmaf(fs[k], W_in[k * 128 + j], acc);
  h[n * 128 + j] = acc;
}

// ---------------- per-layer BN scale/shift precompute ----------------
__global__ void k_bnprep(const float* __restrict__ g, const float* __restrict__ b,
                         const float* __restrict__ m, const float* __restrict__ v,
                         int layer, float* __restrict__ bnp)
{
  int j = threadIdx.x;  // 128 threads
  float s = g[layer * 128 + j] * rsqrtf(v[layer * 128 + j] + 1e-5f);
  bnp[j] = s;
  bnp[128 + j] = b[layer * 128 + j] - m[layer * 128 + j] * s;
}

// ---------------- edge scatter: agg[dst] += BN(h[src]) ----------------
// one thread = (edge, 4 features); 32 threads per edge
__global__ __launch_bounds__(256) void k_scatter(
    const float* __restrict__ h, const int* __restrict__ src, const int* __restrict__ dst,
    const float* __restrict__ bnp, float* __restrict__ agg)
{
  int t = blockIdx.x * 256 + threadIdx.x;
  int e = t >> 5;
  int f = (t & 31) << 2;
  int sn = src[e], dn = dst[e];
  float4 hv = *(const float4*)(h + sn * 128 + f);
  float4 sc = *(const float4*)(bnp + f);
  float4 sh = *(const float4*)(bnp + 128 + f);
  float* ap = agg + dn * 128 + f;
  unsafeAtomicAdd(ap + 0, fmaf(hv.x, sc.x, sh.x));
  unsafeAtomicAdd(ap + 1, fmaf(hv.y, sc.y, sh.y));
  unsafeAtomicAdd(ap + 2, fmaf(hv.z, sc.z, sh.z));
  unsafeAtomicAdd(ap + 3, fmaf(hv.w, sc.w, sh.w));
}

// ---------------- per-node attention weight: wnode = sigmoid(h . w_aw + b_aw) ----------------
__global__ __launch_bounds__(256) void k_wnode(
    const float* __restrict__ h, const float* __restrict__ w_aw,
    const float* __restrict__ b_aw, float* __restrict__ wnode)
{
  int wv = threadIdx.x >> 6;
  int lane = threadIdx.x & 63;
  int n = blockIdx.x * 4 + wv;
  float p = h[n * 128 + lane] * w_aw[lane] + h[n * 128 + 64 + lane] * w_aw[64 + lane];
#pragma unroll
  for (int o = 32; o > 0; o >>= 1) p += __shfl_xor(p, o);
  if (lane == 0) wnode[n] = sig_(p + b_aw[0]);
}

__device__ __forceinline__ int lbound_(const int* __restrict__ a, int n, int key)
{
  int lo = 0, hi = n;
  while (lo < hi) { int mid = (lo + hi) >> 1; if (a[mid] < key) lo = mid + 1; else hi = mid; }
  return lo;
}

// ---------------- graph readout: reps[l][g] = [sum w*h | max h] ----------------
__global__ __launch_bounds__(128) void k_readout(
    const float* __restrict__ h, const float* __restrict__ wnode,
    const int* __restrict__ n2g, float* __restrict__ reps, int layer)
{
  int g = blockIdx.x;
  int j = threadIdx.x;
  int lo = lbound_(n2g, NN, g);
  int hi = lbound_(n2g, NN, g + 1);
  float ws = 0.f, hm = -INFINITY;
  for (int n = lo; n < hi; ++n) {
    float hv = h[n * 128 + j];
    ws = fmaf(wnode[n], hv, ws);
    hm = fmaxf(hm, hv);
  }
  if (hi == lo) hm = 0.f;  // empty segment: segment_max -> -inf -> where(isfinite)->0
  float* r = reps + ((size_t)layer * NG + g) * 256;
  r[j] = ws;
  r[128 + j] = hm;
}

// ---------------- fused GRU + celu + residual, in-place h update ----------------
// block: 256 thr (tx=tid&63, ty=tid>>6); tile: 16 nodes; grid: NN/16
__global__ __launch_bounds__(256) void k_gru(
    float* __restrict__ h, const float* __restrict__ agg, const float* __restrict__ bnp,
    const float* __restrict__ w_ih, const float* __restrict__ w_hh,
    const float* __restrict__ b_ih, const float* __restrict__ b_hh)
{
  __shared__ float V[16][384];     // [u=1.00001x | agg | x]
  __shared__ float WT[16][388];    // k-tile x channel, padded (388%32==4 -> conflict-free)
  const int tid = threadIdx.x;
  const int tx = tid & 63;
  const int ty = tid >> 6;
  const int n0 = blockIdx.x * 16;

  for (int idx = tid; idx < 16 * 128; idx += 256) {
    int nn = idx >> 7, j = idx & 127;
    float hv = h[(n0 + nn) * 128 + j];
    float x = fmaf(hv, bnp[j], bnp[128 + j]);
    V[nn][j] = 1.00001f * x;
    V[nn][128 + j] = agg[(n0 + nn) * 128 + j];
    V[nn][256 + j] = x;
  }

  // acc rows: 0:r(tx) 1:r(64+tx) 2:z(tx) 3:z(64+tx) 4:in(tx) 5:in(64+tx) 6:hn(tx) 7:hn(64+tx)
  float acc[8][4];
#pragma unroll
  for (int i = 0; i < 4; ++i) {
    float b = b_ih[i * 64 + tx] + b_hh[i * 64 + tx];
    acc[i][0] = acc[i][1] = acc[i][2] = acc[i][3] = b;
  }
#pragma unroll
  for (int i = 4; i < 6; ++i) {
    float b = b_ih[i * 64 + tx];
    acc[i][0] = acc[i][1] = acc[i][2] = acc[i][3] = b;
  }
#pragma unroll
  for (int i = 6; i < 8; ++i) {
    float b = b_hh[(i - 2) * 64 + tx];
    acc[i][0] = acc[i][1] = acc[i][2] = acc[i][3] = b;
  }

  // Loop A: k in [0,256) over input [u|agg], weights w_ih [384][256]
  for (int t = 0; t < 16; ++t) {
    __syncthreads();
    {
      int c = tid >> 2, q = tid & 3;
#pragma unroll
      for (int p = 0; p < 6; ++p) {
        int cc = c + p * 64;
        const float4 w = *(const float4*)(w_ih + cc * 256 + t * 16 + q * 4);
        WT[q * 4 + 0][cc] = w.x; WT[q * 4 + 1][cc] = w.y;
        WT[q * 4 + 2][cc] = w.z; WT[q * 4 + 3][cc] = w.w;
      }
    }
    __syncthreads();
#pragma unroll
    for (int kk = 0; kk < 16; ++kk) {
      int k = t * 16 + kk;
      float a0 = V[ty * 4 + 0][k], a1 = V[ty * 4 + 1][k];
      float a2 = V[ty * 4 + 2][k], a3 = V[ty * 4 + 3][k];
#pragma unroll
      for (int i = 0; i < 6; ++i) {
        float w = WT[kk][i * 64 + tx];
        acc[i][0] = fmaf(w, a0, acc[i][0]);
        acc[i][1] = fmaf(w, a1, acc[i][1]);
        acc[i][2] = fmaf(w, a2, acc[i][2]);
        acc[i][3] = fmaf(w, a3, acc[i][3]);
      }
    }
  }

  // Loop B: k in [0,128) over x, weights w_hh [384][128]
  for (int t = 0; t < 8; ++t) {
    __syncthreads();
    {
      int c = tid >> 2, q = tid & 3;
#pragma unroll
      for (int p = 0; p < 6; ++p) {
        int cc = c + p * 64;
        const float4 w = *(const float4*)(w_hh + cc * 128 + t * 16 + q * 4);
        WT[q * 4 + 0][cc] = w.x; WT[q * 4 + 1][cc] = w.y;
        WT[q * 4 + 2][cc] = w.z; WT[q * 4 + 3][cc] = w.w;
      }
    }
    __syncthreads();
#pragma unroll
    for (int kk = 0; kk < 16; ++kk) {
      int k = t * 16 + kk;
      float a0 = V[ty * 4 + 0][256 + k], a1 = V[ty * 4 + 1][256 + k];
      float a2 = V[ty * 4 + 2][256 + k], a3 = V[ty * 4 + 3][256 + k];
#pragma unroll
      for (int i = 0; i < 6; ++i) {
        float w = WT[kk][i * 64 + tx];
        int ai = (i < 4) ? i : i + 2;  // hn rows go to acc[6],[7]
        acc[ai][0] = fmaf(w, a0, acc[ai][0]);
        acc[ai][1] = fmaf(w, a1, acc[ai][1]);
        acc[ai][2] = fmaf(w, a2, acc[ai][2]);
        acc[ai][3] = fmaf(w, a3, acc[ai][3]);
      }
    }
  }

  // epilogue: gates + celu + residual (in place; each block owns its rows)
#pragma unroll
  for (int nd = 0; nd < 4; ++nd) {
    int n = n0 + ty * 4 + nd;
#pragma unroll
    for (int half = 0; half < 2; ++half) {
      int j = half * 64 + tx;
      float r = sig_(acc[0 + half][nd]);
      float z = sig_(acc[2 + half][nd]);
      float ng = tanhf(fmaf(r, acc[6 + half][nd], acc[4 + half][nd]));
      float xj = V[ty * 4 + nd][256 + j];
      float o = (1.f - z) * ng + z * xj;
      float hc = (o > 0.f) ? o : expm1f(o);
      h[n * 128 + j] += hc;
    }
  }
}

// ---------------- fused LSTM step ----------------
// gates i,f,g,o; block 256 thr, 16 batch rows, grid NG/16 = 64
__global__ __launch_bounds__(256) void k_lstm(
    const float* __restrict__ x,     // [NG][256]
    const float* __restrict__ h_in, const float* __restrict__ c_in,
    const float* __restrict__ w_ih, const float* __restrict__ w_hh,
    const float* __restrict__ b_ih, const float* __restrict__ b_hh,
    float* __restrict__ h_out, float* __restrict__ c_out)
{
  __shared__ float V[16][384];   // [x(256) | h(128)]
  __shared__ float WT[16][516];  // 516%32==4 -> conflict-free
  const int tid = threadIdx.x;
  const int tx = tid & 63;
  const int ty = tid >> 6;
  const int n0 = blockIdx.x * 16;

  for (int idx = tid; idx < 16 * 256; idx += 256) {
    int nn = idx >> 8, j = idx & 255;
    V[nn][j] = x[(n0 + nn) * 256 + j];
  }
  for (int idx = tid; idx < 16 * 128; idx += 256) {
    int nn = idx >> 7, j = idx & 127;
    V[nn][256 + j] = h_in[(n0 + nn) * 128 + j];
  }

  float acc[8][4];
#pragma unroll
  for (int i = 0; i < 8; ++i) {
    float b = b_ih[i * 64 + tx] + b_hh[i * 64 + tx];
    acc[i][0] = acc[i][1] = acc[i][2] = acc[i][3] = b;
  }

  for (int t = 0; t < 16; ++t) {  // w_ih [512][256]
    __syncthreads();
    {
      int c = tid >> 2, q = tid & 3;
#pragma unroll
      for (int p = 0; p < 8; ++p) {
        int cc = c + p * 64;
        const float4 w = *(const float4*)(w_ih + cc * 256 + t * 16 + q * 4);
        WT[q * 4 + 0][cc] = w.x; WT[q * 4 + 1][cc] = w.y;
        WT[q * 4 + 2][cc] = w.z; WT[q * 4 + 3][cc] = w.w;
      }
    }
    __syncthreads();
#pragma unroll
    for (int kk = 0; kk < 16; ++kk) {
      int k = t * 16 + kk;
      float a0 = V[ty * 4 + 0][k], a1 = V[ty * 4 + 1][k];
      float a2 = V[ty * 4 + 2][k], a3 = V[ty * 4 + 3][k];
#pragma unroll
      for (int i = 0; i < 8; ++i) {
        float w = WT[kk][i * 64 + tx];
        acc[i][0] = fmaf(w, a0, acc[i][0]);
        acc[i][1] = fmaf(w, a1, acc[i][1]);
        acc[i][2] = fmaf(w, a2, acc[i][2]);
        acc[i][3] = fmaf(w, a3, acc[i][3]);
      }
    }
  }

  for (int t = 0; t < 8; ++t) {  // w_hh [512][128]
    __syncthreads();
    {
      int c = tid >> 2, q = tid & 3;
#pragma unroll
      for (int p = 0; p < 8; ++p) {
        int cc = c + p * 64;
        const float4 w = *(const float4*)(w_hh + cc * 128 + t * 16 + q * 4);
        WT[q * 4 + 0][cc] = w.x; WT[q * 4 + 1][cc] = w.y;
        WT[q * 4 + 2][cc] = w.z; WT[q * 4 + 3][cc] = w.w;
      }
    }
    __syncthreads();
#pragma unroll
    for (int kk = 0; kk < 16; ++kk) {
      int k = t * 16 + kk;
      float a0 = V[ty * 4 + 0][256 + k], a1 = V[ty * 4 + 1][256 + k];
      float a2 = V[ty * 4 + 2][256 + k], a3 = V[ty * 4 + 3][256 + k];
#pragma unroll
      for (int i = 0; i < 8; ++i) {
        float w = WT[kk][i * 64 + tx];
        acc[i][0] = fmaf(w, a0, acc[i][0]);
        acc[i][1] = fmaf(w, a1, acc[i][1]);
        acc[i][2] = fmaf(w, a2, acc[i][2]);
        acc[i][3] = fmaf(w, a3, acc[i][3]);
      }
    }
  }

#pragma unroll
  for (int nd = 0; nd < 4; ++nd) {
    int n = n0 + ty * 4 + nd;
#pragma unroll
    for (int half = 0; half < 2; ++half) {
      int j = half * 64 + tx;
      float ig = sig_(acc[0 + half][nd]);
      float fg = sig_(acc[2 + half][nd]);
      float gg = tanhf(acc[4 + half][nd]);
      float og = sig_(acc[6 + half][nd]);
      float cn = fmaf(fg, c_in[n * 128 + j], ig * gg);
      c_out[n * 128 + j] = cn;
      h_out[n * 128 + j] = og * tanhf(cn);
    }
  }
}

// ---------------- final projection ----------------
__global__ __launch_bounds__(256) void k_final(
    const float* __restrict__ yf, const float* __restrict__ yb,
    const float* __restrict__ W_out, const float* __restrict__ b_out,
    float* __restrict__ out)
{
  int tid = threadIdx.x;
  int g = blockIdx.x * 4 + (tid >> 6);
  int lane = tid & 63;
  float a0 = 0.f, a1 = 0.f;
  for (int k = lane; k < 128; k += 64) {
    float v = yf[g * 128 + k];
    a0 = fmaf(v, W_out[k * 2 + 0], a0);
    a1 = fmaf(v, W_out[k * 2 + 1], a1);
    float u = yb[g * 128 + k];
    a0 = fmaf(u, W_out[(128 + k) * 2 + 0], a0);
    a1 = fmaf(u, W_out[(128 + k) * 2 + 1], a1);
  }
#pragma unroll
  for (int o = 32; o > 0; o >>= 1) { a0 += __shfl_xor(a0, o); a1 += __shfl_xor(a1, o); }
  if (lane == 0) {
    out[g * 2 + 0] = a0 + b_out[0];
    out[g * 2 + 1] = a1 + b_out[1];
  }
}

extern "C" void kernel_launch(void* const* d_in, const int* in_sizes, int n_in,
                              void* d_out, int out_size, void* d_ws, size_t ws_size,
                              hipStream_t stream)
{
  (void)in_sizes; (void)n_in; (void)out_size; (void)ws_size;
  const float* feats   = (const float*)d_in[0];
  const int*   src     = (const int*)d_in[1];
  const int*   dst     = (const int*)d_in[2];
  const int*   n2g     = (const int*)d_in[3];
  const float* W_in    = (const float*)d_in[4];
  const float* b_in    = (const float*)d_in[5];
  const float* bng     = (const float*)d_in[6];
  const float* bnb     = (const float*)d_in[7];
  const float* bnm     = (const float*)d_in[8];
  const float* bnv     = (const float*)d_in[9];
  const float* gw_ih   = (const float*)d_in[10];
  const float* gw_hh   = (const float*)d_in[11];
  const float* gb_ih   = (const float*)d_in[12];
  const float* gb_hh   = (const float*)d_in[13];
  const float* w_aw    = (const float*)d_in[14];
  const float* b_aw    = (const float*)d_in[15];
  const float* lwih_f  = (const float*)d_in[16];
  const float* lwhh_f  = (const float*)d_in[17];
  const float* lbih_f  = (const float*)d_in[18];
  const float* lbhh_f  = (const float*)d_in[19];
  const float* lwih_b  = (const float*)d_in[20];
  const float* lwhh_b  = (const float*)d_in[21];
  const float* lbih_b  = (const float*)d_in[22];
  const float* lbhh_b  = (const float*)d_in[23];
  const float* W_out   = (const float*)d_in[24];
  const float* b_out   = (const float*)d_in[25];
  float* out = (float*)d_out;

  float* ws = (float*)d_ws;
  size_t off = 0;
  auto alloc = [&](size_t n) { float* p = ws + off; off += (n + 63) & ~(size_t)63; return p; };
  float* h     = alloc((size_t)NN * 128);
  float* agg   = alloc((size_t)NN * 128);
  float* wnode = alloc(NN);
  float* bnp   = alloc(256);
  float* reps  = alloc((size_t)NL * NG * 256);
  float* zh    = alloc((size_t)NG * 128);
  float* zc    = alloc((size_t)NG * 128);
  float* ha    = alloc((size_t)NG * 128);
  float* ca    = alloc((size_t)NG * 128);
  float* hb    = alloc((size_t)NG * 128);
  float* cb    = alloc((size_t)NG * 128);
  float* yf    = alloc((size_t)NG * 128);
  float* cf    = alloc((size_t)NG * 128);

  k_input_proj<<<NN, 128, 0, stream>>>(feats, W_in, b_in, h);

  for (int l = 0; l < NL; ++l) {
    k_bnprep<<<1, 128, 0, stream>>>(bng, bnb, bnm, bnv, l, bnp);
    hipMemsetAsync(agg, 0, (size_t)NN * 128 * sizeof(float), stream);
    k_scatter<<<NE * 32 / 256, 256, 0, stream>>>(h, src, dst, bnp, agg);
    k_wnode<<<NN / 4, 256, 0, stream>>>(h, w_aw, b_aw, wnode);
    k_readout<<<NG, 128, 0, stream>>>(h, wnode, n2g, reps, l);
    k_gru<<<NN / 16, 256, 0, stream>>>(h, agg, bnp, gw_ih, gw_hh, gb_ih, gb_hh);
  }

  hipMemsetAsync(zh, 0, (size_t)NG * 128 * sizeof(float), stream);
  hipMemsetAsync(zc, 0, (size_t)NG * 128 * sizeof(float), stream);

  // forward: only step 0 is needed for y_f[0]
  k_lstm<<<NG / 16, 256, 0, stream>>>(reps, zh, zc, lwih_f, lwhh_f, lbih_f, lbhh_f, yf, cf);

  // backward: 5 steps over rep[4..0]; ping-pong z->a->b->a->b->a
  k_lstm<<<NG / 16, 256, 0, stream>>>(reps + (size_t)4 * NG * 256, zh, zc, lwih_b, lwhh_b, lbih_b, lbhh_b, ha, ca);
  k_lstm<<<NG / 16, 256, 0, stream>>>(reps + (size_t)3 * NG * 256, ha, ca, lwih_b, lwhh_b, lbih_b, lbhh_b, hb, cb);
  k_lstm<<<NG / 16, 256, 0, stream>>>(reps + (size_t)2 * NG * 256, hb, cb, lwih_b, lwhh_b, lbih_b, lbhh_b, ha, ca);
  k_lstm<<<NG / 16, 256, 0, stream>>>(reps + (size_t)1 * NG * 256, ha, ca, lwih_b, lwhh_b, lbih_b, lbhh_b, hb, cb);
  k_lstm<<<NG / 16, 256, 0, stream>>>(reps + (size_t)0 * NG * 256, hb, cb, lwih_b, lwhh_b, lbih_b, lbhh_b, ha, ca);

  k_final<<<NG / 4, 256, 0, stream>>>(yf, ha, W_out, b_out, out);
}

// Round 2
// 2995.450 us; speedup vs baseline: 2.5901x; 2.5901x over previous
//
#include <hip/hip_runtime.h>
#include <math.h>

#define NN 50000
#define NE 600000
#define NG 1024
#define NL 5
// Hd = 128, Fin = 74, C = 2

__device__ __forceinline__ float sig_(float x) { return 1.f / (1.f + expf(-x)); }

// ---------------- input projection: h = feats @ W_in + b_in ----------------
__global__ __launch_bounds__(128) void k_input_proj(
    const float* __restrict__ feats, const float* __restrict__ W_in,
    const float* __restrict__ b_in, float* __restrict__ h)
{
  __shared__ float fs[74];
  int n = blockIdx.x;
  int j = threadIdx.x;
  if (j < 74) fs[j] = feats[n * 74 + j];
  __syncthreads();
  float acc = b_in[j];
#pragma unroll
  for (int k = 0; k < 74; ++k) acc = fmaf(fs[k], W_in[k * 128 + j], acc);
  h[n * 128 + j] = acc;
}

// ---------------- per-layer BN scale/shift precompute ----------------
__global__ void k_bnprep(const float* __restrict__ g, const float* __restrict__ b,
                         const float* __restrict__ m, const float* __restrict__ v,
                         int layer, float* __restrict__ bnp)
{
  int j = threadIdx.x;  // 128 threads
  float s = g[layer * 128 + j] * rsqrtf(v[layer * 128 + j] + 1e-5f);
  bnp[j] = s;
  bnp[128 + j] = b[layer * 128 + j] - m[layer * 128 + j] * s;
}

// ---------------- CSR build: histogram -> scan -> fill ----------------
__global__ __launch_bounds__(256) void k_hist(const int* __restrict__ dst, int* __restrict__ deg)
{
  int t = blockIdx.x * 256 + threadIdx.x;
  if (t < NE) atomicAdd(&deg[dst[t]], 1);
}

__global__ __launch_bounds__(1024) void k_scan(const int* __restrict__ deg, int* __restrict__ rowptr)
{
  __shared__ int part[1024];
  const int t = threadIdx.x;
  const int CH = 49;  // 1024*49 = 50176 >= NN
  int beg = t * CH, end = min(beg + CH, NN);
  int s = 0;
  for (int i = beg; i < end; ++i) s += deg[i];
  part[t] = s;
  __syncthreads();
  for (int o = 1; o < 1024; o <<= 1) {
    int v = (t >= o) ? part[t - o] : 0;
    __syncthreads();
    part[t] += v;
    __syncthreads();
  }
  int base = part[t] - s;  // exclusive prefix
  for (int i = beg; i < end; ++i) { rowptr[i] = base; base += deg[i]; }
  if (t == 0) rowptr[NN] = NE;
}

__global__ __launch_bounds__(256) void k_fill(
    const int* __restrict__ src, const int* __restrict__ dst,
    int* __restrict__ pos, int* __restrict__ col)
{
  int t = blockIdx.x * 256 + threadIdx.x;
  if (t >= NE) return;
  int p = atomicAdd(&pos[dst[t]], 1);
  col[p] = src[t];
}

// ---------------- CSR gather: agg[n] = sc*sum(h[nbrs]) + deg*sh ----------------
// one wave per node, lane holds 2 feature columns (float2)
__global__ __launch_bounds__(256) void k_gather(
    const float* __restrict__ h, const int* __restrict__ rowptr,
    const int* __restrict__ col, const float* __restrict__ bnp,
    float* __restrict__ agg)
{
  int n = blockIdx.x * 4 + (threadIdx.x >> 6);
  int lane = threadIdx.x & 63;
  int lo = rowptr[n], hi = rowptr[n + 1];
  float a0 = 0.f, b0 = 0.f, a1 = 0.f, b1 = 0.f;
  int e = lo;
  for (; e + 1 < hi; e += 2) {
    int s0 = col[e], s1 = col[e + 1];
    float2 v0 = *(const float2*)(h + (size_t)s0 * 128 + lane * 2);
    float2 v1 = *(const float2*)(h + (size_t)s1 * 128 + lane * 2);
    a0 += v0.x; b0 += v0.y;
    a1 += v1.x; b1 += v1.y;
  }
  if (e < hi) {
    int s0 = col[e];
    float2 v0 = *(const float2*)(h + (size_t)s0 * 128 + lane * 2);
    a0 += v0.x; b0 += v0.y;
  }
  float sum0 = a0 + a1, sum1 = b0 + b1;
  float deg = (float)(hi - lo);
  int j = lane * 2;
  float2 sc = *(const float2*)(bnp + j);
  float2 sh = *(const float2*)(bnp + 128 + j);
  float2 r;
  r.x = fmaf(sc.x, sum0, deg * sh.x);
  r.y = fmaf(sc.y, sum1, deg * sh.y);
  *(float2*)(agg + (size_t)n * 128 + j) = r;
}

// ---------------- per-node attention weight: wnode = sigmoid(h . w_aw + b_aw) ----------------
__global__ __launch_bounds__(256) void k_wnode(
    const float* __restrict__ h, const float* __restrict__ w_aw,
    const float* __restrict__ b_aw, float* __restrict__ wnode)
{
  int wv = threadIdx.x >> 6;
  int lane = threadIdx.x & 63;
  int n = blockIdx.x * 4 + wv;
  float p = h[n * 128 + lane] * w_aw[lane] + h[n * 128 + 64 + lane] * w_aw[64 + lane];
#pragma unroll
  for (int o = 32; o > 0; o >>= 1) p += __shfl_xor(p, o);
  if (lane == 0) wnode[n] = sig_(p + b_aw[0]);
}

__device__ __forceinline__ int lbound_(const int* __restrict__ a, int n, int key)
{
  int lo = 0, hi = n;
  while (lo < hi) { int mid = (lo + hi) >> 1; if (a[mid] < key) lo = mid + 1; else hi = mid; }
  return lo;
}

// ---------------- graph readout: reps[l][g] = [sum w*h | max h] ----------------
__global__ __launch_bounds__(128) void k_readout(
    const float* __restrict__ h, const float* __restrict__ wnode,
    const int* __restrict__ n2g, float* __restrict__ reps, int layer)
{
  int g = blockIdx.x;
  int j = threadIdx.x;
  int lo = lbound_(n2g, NN, g);
  int hi = lbound_(n2g, NN, g + 1);
  float ws = 0.f, hm = -INFINITY;
  for (int n = lo; n < hi; ++n) {
    float hv = h[n * 128 + j];
    ws = fmaf(wnode[n], hv, ws);
    hm = fmaxf(hm, hv);
  }
  if (hi == lo) hm = 0.f;  // empty segment: segment_max -> -inf -> where(isfinite)->0
  float* r = reps + ((size_t)layer * NG + g) * 256;
  r[j] = ws;
  r[128 + j] = hm;
}

// ---------------- fused GRU + celu + residual, in-place h update ----------------
// block: 256 thr (tx=tid&63, ty=tid>>6); tile: 16 nodes; grid: NN/16
__global__ __launch_bounds__(256) void k_gru(
    float* __restrict__ h, const float* __restrict__ agg, const float* __restrict__ bnp,
    const float* __restrict__ w_ih, const float* __restrict__ w_hh,
    const float* __restrict__ b_ih, const float* __restrict__ b_hh)
{
  __shared__ float V[16][384];     // [u=1.00001x | agg | x]
  __shared__ float WT[16][388];    // k-tile x channel, padded (388%32==4 -> conflict-free)
  const int tid = threadIdx.x;
  const int tx = tid & 63;
  const int ty = tid >> 6;
  const int n0 = blockIdx.x * 16;

  for (int idx = tid; idx < 16 * 128; idx += 256) {
    int nn = idx >> 7, j = idx & 127;
    float hv = h[(n0 + nn) * 128 + j];
    float x = fmaf(hv, bnp[j], bnp[128 + j]);
    V[nn][j] = 1.00001f * x;
    V[nn][128 + j] = agg[(n0 + nn) * 128 + j];
    V[nn][256 + j] = x;
  }

  // acc rows: 0:r(tx) 1:r(64+tx) 2:z(tx) 3:z(64+tx) 4:in(tx) 5:in(64+tx) 6:hn(tx) 7:hn(64+tx)
  float acc[8][4];
#pragma unroll
  for (int i = 0; i < 4; ++i) {
    float b = b_ih[i * 64 + tx] + b_hh[i * 64 + tx];
    acc[i][0] = acc[i][1] = acc[i][2] = acc[i][3] = b;
  }
#pragma unroll
  for (int i = 4; i < 6; ++i) {
    float b = b_ih[i * 64 + tx];
    acc[i][0] = acc[i][1] = acc[i][2] = acc[i][3] = b;
  }
#pragma unroll
  for (int i = 6; i < 8; ++i) {
    float b = b_hh[(i - 2) * 64 + tx];
    acc[i][0] = acc[i][1] = acc[i][2] = acc[i][3] = b;
  }

  // Loop A: k in [0,256) over input [u|agg], weights w_ih [384][256]
  for (int t = 0; t < 16; ++t) {
    __syncthreads();
    {
      int c = tid >> 2, q = tid & 3;
#pragma unroll
      for (int p = 0; p < 6; ++p) {
        int cc = c + p * 64;
        const float4 w = *(const float4*)(w_ih + cc * 256 + t * 16 + q * 4);
        WT[q * 4 + 0][cc] = w.x; WT[q * 4 + 1][cc] = w.y;
        WT[q * 4 + 2][cc] = w.z; WT[q * 4 + 3][cc] = w.w;
      }
    }
    __syncthreads();
#pragma unroll
    for (int kk = 0; kk < 16; ++kk) {
      int k = t * 16 + kk;
      float a0 = V[ty * 4 + 0][k], a1 = V[ty * 4 + 1][k];
      float a2 = V[ty * 4 + 2][k], a3 = V[ty * 4 + 3][k];
#pragma unroll
      for (int i = 0; i < 6; ++i) {
        float w = WT[kk][i * 64 + tx];
        acc[i][0] = fmaf(w, a0, acc[i][0]);
        acc[i][1] = fmaf(w, a1, acc[i][1]);
        acc[i][2] = fmaf(w, a2, acc[i][2]);
        acc[i][3] = fmaf(w, a3, acc[i][3]);
      }
    }
  }

  // Loop B: k in [0,128) over x, weights w_hh [384][128]
  for (int t = 0; t < 8; ++t) {
    __syncthreads();
    {
      int c = tid >> 2, q = tid & 3;
#pragma unroll
      for (int p = 0; p < 6; ++p) {
        int cc = c + p * 64;
        const float4 w = *(const float4*)(w_hh + cc * 128 + t * 16 + q * 4);
        WT[q * 4 + 0][cc] = w.x; WT[q * 4 + 1][cc] = w.y;
        WT[q * 4 + 2][cc] = w.z; WT[q * 4 + 3][cc] = w.w;
      }
    }
    __syncthreads();
#pragma unroll
    for (int kk = 0; kk < 16; ++kk) {
      int k = t * 16 + kk;
      float a0 = V[ty * 4 + 0][256 + k], a1 = V[ty * 4 + 1][256 + k];
      float a2 = V[ty * 4 + 2][256 + k], a3 = V[ty * 4 + 3][256 + k];
#pragma unroll
      for (int i = 0; i < 6; ++i) {
        float w = WT[kk][i * 64 + tx];
        int ai = (i < 4) ? i : i + 2;  // hn rows go to acc[6],[7]
        acc[ai][0] = fmaf(w, a0, acc[ai][0]);
        acc[ai][1] = fmaf(w, a1, acc[ai][1]);
        acc[ai][2] = fmaf(w, a2, acc[ai][2]);
        acc[ai][3] = fmaf(w, a3, acc[ai][3]);
      }
    }
  }

  // epilogue: gates + celu + residual (in place; each block owns its rows)
#pragma unroll
  for (int nd = 0; nd < 4; ++nd) {
    int n = n0 + ty * 4 + nd;
#pragma unroll
    for (int half = 0; half < 2; ++half) {
      int j = half * 64 + tx;
      float r = sig_(acc[0 + half][nd]);
      float z = sig_(acc[2 + half][nd]);
      float ng = tanhf(fmaf(r, acc[6 + half][nd], acc[4 + half][nd]));
      float xj = V[ty * 4 + nd][256 + j];
      float o = (1.f - z) * ng + z * xj;
      float hc = (o > 0.f) ? o : expm1f(o);
      h[n * 128 + j] += hc;
    }
  }
}

// ---------------- fused LSTM step ----------------
// gates i,f,g,o; block 256 thr, 16 batch rows, grid NG/16 = 64
__global__ __launch_bounds__(256) void k_lstm(
    const float* __restrict__ x,     // [NG][256]
    const float* __restrict__ h_in, const float* __restrict__ c_in,
    const float* __restrict__ w_ih, const float* __restrict__ w_hh,
    const float* __restrict__ b_ih, const float* __restrict__ b_hh,
    float* __restrict__ h_out, float* __restrict__ c_out)
{
  __shared__ float V[16][384];   // [x(256) | h(128)]
  __shared__ float WT[16][516];  // 516%32==4 -> conflict-free
  const int tid = threadIdx.x;
  const int tx = tid & 63;
  const int ty = tid >> 6;
  const int n0 = blockIdx.x * 16;

  for (int idx = tid; idx < 16 * 256; idx += 256) {
    int nn = idx >> 8, j = idx & 255;
    V[nn][j] = x[(n0 + nn) * 256 + j];
  }
  for (int idx = tid; idx < 16 * 128; idx += 256) {
    int nn = idx >> 7, j = idx & 127;
    V[nn][256 + j] = h_in[(n0 + nn) * 128 + j];
  }

  float acc[8][4];
#pragma unroll
  for (int i = 0; i < 8; ++i) {
    float b = b_ih[i * 64 + tx] + b_hh[i * 64 + tx];
    acc[i][0] = acc[i][1] = acc[i][2] = acc[i][3] = b;
  }

  for (int t = 0; t < 16; ++t) {  // w_ih [512][256]
    __syncthreads();
    {
      int c = tid >> 2, q = tid & 3;
#pragma unroll
      for (int p = 0; p < 8; ++p) {
        int cc = c + p * 64;
        const float4 w = *(const float4*)(w_ih + cc * 256 + t * 16 + q * 4);
        WT[q * 4 + 0][cc] = w.x; WT[q * 4 + 1][cc] = w.y;
        WT[q * 4 + 2][cc] = w.z; WT[q * 4 + 3][cc] = w.w;
      }
    }
    __syncthreads();
#pragma unroll
    for (int kk = 0; kk < 16; ++kk) {
      int k = t * 16 + kk;
      float a0 = V[ty * 4 + 0][k], a1 = V[ty * 4 + 1][k];
      float a2 = V[ty * 4 + 2][k], a3 = V[ty * 4 + 3][k];
#pragma unroll
      for (int i = 0; i < 8; ++i) {
        float w = WT[kk][i * 64 + tx];
        acc[i][0] = fmaf(w, a0, acc[i][0]);
        acc[i][1] = fmaf(w, a1, acc[i][1]);
        acc[i][2] = fmaf(w, a2, acc[i][2]);
        acc[i][3] = fmaf(w, a3, acc[i][3]);
      }
    }
  }

  for (int t = 0; t < 8; ++t) {  // w_hh [512][128]
    __syncthreads();
    {
      int c = tid >> 2, q = tid & 3;
#pragma unroll
      for (int p = 0; p < 8; ++p) {
        int cc = c + p * 64;
        const float4 w = *(const float4*)(w_hh + cc * 128 + t * 16 + q * 4);
        WT[q * 4 + 0][cc] = w.x; WT[q * 4 + 1][cc] = w.y;
        WT[q * 4 + 2][cc] = w.z; WT[q * 4 + 3][cc] = w.w;
      }
    }
    __syncthreads();
#pragma unroll
    for (int kk = 0; kk < 16; ++kk) {
      int k = t * 16 + kk;
      float a0 = V[ty * 4 + 0][256 + k], a1 = V[ty * 4 + 1][256 + k];
      float a2 = V[ty * 4 + 2][256 + k], a3 = V[ty * 4 + 3][256 + k];
#pragma unroll
      for (int i = 0; i < 8; ++i) {
        float w = WT[kk][i * 64 + tx];
        acc[i][0] = fmaf(w, a0, acc[i][0]);
        acc[i][1] = fmaf(w, a1, acc[i][1]);
        acc[i][2] = fmaf(w, a2, acc[i][2]);
        acc[i][3] = fmaf(w, a3, acc[i][3]);
      }
    }
  }

#pragma unroll
  for (int nd = 0; nd < 4; ++nd) {
    int n = n0 + ty * 4 + nd;
#pragma unroll
    for (int half = 0; half < 2; ++half) {
      int j = half * 64 + tx;
      float ig = sig_(acc[0 + half][nd]);
      float fg = sig_(acc[2 + half][nd]);
      float gg = tanhf(acc[4 + half][nd]);
      float og = sig_(acc[6 + half][nd]);
      float cn = fmaf(fg, c_in[n * 128 + j], ig * gg);
      c_out[n * 128 + j] = cn;
      h_out[n * 128 + j] = og * tanhf(cn);
    }
  }
}

// ---------------- final projection ----------------
__global__ __launch_bounds__(256) void k_final(
    const float* __restrict__ yf, const float* __restrict__ yb,
    const float* __restrict__ W_out, const float* __restrict__ b_out,
    float* __restrict__ out)
{
  int tid = threadIdx.x;
  int g = blockIdx.x * 4 + (tid >> 6);
  int lane = tid & 63;
  float a0 = 0.f, a1 = 0.f;
  for (int k = lane; k < 128; k += 64) {
    float v = yf[g * 128 + k];
    a0 = fmaf(v, W_out[k * 2 + 0], a0);
    a1 = fmaf(v, W_out[k * 2 + 1], a1);
    float u = yb[g * 128 + k];
    a0 = fmaf(u, W_out[(128 + k) * 2 + 0], a0);
    a1 = fmaf(u, W_out[(128 + k) * 2 + 1], a1);
  }
#pragma unroll
  for (int o = 32; o > 0; o >>= 1) { a0 += __shfl_xor(a0, o); a1 += __shfl_xor(a1, o); }
  if (lane == 0) {
    out[g * 2 + 0] = a0 + b_out[0];
    out[g * 2 + 1] = a1 + b_out[1];
  }
}

extern "C" void kernel_launch(void* const* d_in, const int* in_sizes, int n_in,
                              void* d_out, int out_size, void* d_ws, size_t ws_size,
                              hipStream_t stream)
{
  (void)in_sizes; (void)n_in; (void)out_size; (void)ws_size;
  const float* feats   = (const float*)d_in[0];
  const int*   src     = (const int*)d_in[1];
  const int*   dst     = (const int*)d_in[2];
  const int*   n2g     = (const int*)d_in[3];
  const float* W_in    = (const float*)d_in[4];
  const float* b_in    = (const float*)d_in[5];
  const float* bng     = (const float*)d_in[6];
  const float* bnb     = (const float*)d_in[7];
  const float* bnm     = (const float*)d_in[8];
  const float* bnv     = (const float*)d_in[9];
  const float* gw_ih   = (const float*)d_in[10];
  const float* gw_hh   = (const float*)d_in[11];
  const float* gb_ih   = (const float*)d_in[12];
  const float* gb_hh   = (const float*)d_in[13];
  const float* w_aw    = (const float*)d_in[14];
  const float* b_aw    = (const float*)d_in[15];
  const float* lwih_f  = (const float*)d_in[16];
  const float* lwhh_f  = (const float*)d_in[17];
  const float* lbih_f  = (const float*)d_in[18];
  const float* lbhh_f  = (const float*)d_in[19];
  const float* lwih_b  = (const float*)d_in[20];
  const float* lwhh_b  = (const float*)d_in[21];
  const float* lbih_b  = (const float*)d_in[22];
  const float* lbhh_b  = (const float*)d_in[23];
  const float* W_out   = (const float*)d_in[24];
  const float* b_out   = (const float*)d_in[25];
  float* out = (float*)d_out;

  float* ws = (float*)d_ws;
  size_t off = 0;
  auto alloc = [&](size_t n) { float* p = ws + off; off += (n + 63) & ~(size_t)63; return p; };
  float* h      = alloc((size_t)NN * 128);
  float* agg    = alloc((size_t)NN * 128);
  float* wnode  = alloc(NN);
  float* bnp    = alloc(256);
  float* reps   = alloc((size_t)NL * NG * 256);
  float* zh     = alloc((size_t)NG * 128);
  float* zc     = alloc((size_t)NG * 128);
  float* ha     = alloc((size_t)NG * 128);
  float* ca     = alloc((size_t)NG * 128);
  float* hb     = alloc((size_t)NG * 128);
  float* cb     = alloc((size_t)NG * 128);
  float* yf     = alloc((size_t)NG * 128);
  float* cf     = alloc((size_t)NG * 128);
  int* deg    = (int*)alloc(NN);
  int* rowptr = (int*)alloc(NN + 1);
  int* pos    = (int*)alloc(NN);
  int* colidx = (int*)alloc(NE);

  // ---- one-time CSR build (graph is fixed across layers) ----
  hipMemsetAsync(deg, 0, (size_t)NN * sizeof(int), stream);
  k_hist<<<(NE + 255) / 256, 256, 0, stream>>>(dst, deg);
  k_scan<<<1, 1024, 0, stream>>>(deg, rowptr);
  hipMemcpyAsync(pos, rowptr, (size_t)NN * sizeof(int), hipMemcpyDeviceToDevice, stream);
  k_fill<<<(NE + 255) / 256, 256, 0, stream>>>(src, dst, pos, colidx);

  k_input_proj<<<NN, 128, 0, stream>>>(feats, W_in, b_in, h);

  for (int l = 0; l < NL; ++l) {
    k_bnprep<<<1, 128, 0, stream>>>(bng, bnb, bnm, bnv, l, bnp);
    k_gather<<<NN / 4, 256, 0, stream>>>(h, rowptr, colidx, bnp, agg);
    k_wnode<<<NN / 4, 256, 0, stream>>>(h, w_aw, b_aw, wnode);
    k_readout<<<NG, 128, 0, stream>>>(h, wnode, n2g, reps, l);
    k_gru<<<NN / 16, 256, 0, stream>>>(h, agg, bnp, gw_ih, gw_hh, gb_ih, gb_hh);
  }

  hipMemsetAsync(zh, 0, (size_t)NG * 128 * sizeof(float), stream);
  hipMemsetAsync(zc, 0, (size_t)NG * 128 * sizeof(float), stream);

  // forward: only step 0 is needed for y_f[0]
  k_lstm<<<NG / 16, 256, 0, stream>>>(reps, zh, zc, lwih_f, lwhh_f, lbih_f, lbhh_f, yf, cf);

  // backward: 5 steps over rep[4..0]; ping-pong
  k_lstm<<<NG / 16, 256, 0, stream>>>(reps + (size_t)4 * NG * 256, zh, zc, lwih_b, lwhh_b, lbih_b, lbhh_b, ha, ca);
  k_lstm<<<NG / 16, 256, 0, stream>>>(reps + (size_t)3 * NG * 256, ha, ca, lwih_b, lwhh_b, lbih_b, lbhh_b, hb, cb);
  k_lstm<<<NG / 16, 256, 0, stream>>>(reps + (size_t)2 * NG * 256, hb, cb, lwih_b, lwhh_b, lbih_b, lbhh_b, ha, ca);
  k_lstm<<<NG / 16, 256, 0, stream>>>(reps + (size_t)1 * NG * 256, ha, ca, lwih_b, lwhh_b, lbih_b, lbhh_b, hb, cb);
  k_lstm<<<NG / 16, 256, 0, stream>>>(reps + (size_t)0 * NG * 256, hb, cb, lwih_b, lwhh_b, lbih_b, lbhh_b, ha, ca);

  k_final<<<NG / 4, 256, 0, stream>>>(yf, ha, W_out, b_out, out);
}

// Round 3
// 1747.488 us; speedup vs baseline: 4.4398x; 1.7141x over previous
//
#include <hip/hip_runtime.h>
#include <math.h>

#define NN 50000
#define NP 50048   // padded rows (multiple of 64)
#define NE 600000
#define NG 1024
#define NL 5
// Hd = 128, Fin = 74, C = 2

typedef __attribute__((ext_vector_type(8))) short bfrag8;
typedef __attribute__((ext_vector_type(4))) float f32x4;

__device__ __forceinline__ float sig_(float x) { return 1.f / (1.f + expf(-x)); }

__device__ __forceinline__ unsigned short bf16r_(float x) {
  union { float f; unsigned u; } v; v.f = x;
  unsigned u = v.u;
  return (unsigned short)((u + 0x7FFFu + ((u >> 16) & 1u)) >> 16);
}
__device__ __forceinline__ float bf16tof_(unsigned short h) {
  union { float f; unsigned u; } v; v.u = ((unsigned)h) << 16;
  return v.f;
}

// ---------------- input projection: h = feats @ W_in + b_in ----------------
__global__ __launch_bounds__(128) void k_input_proj(
    const float* __restrict__ feats, const float* __restrict__ W_in,
    const float* __restrict__ b_in, float* __restrict__ h)
{
  __shared__ float fs[74];
  int n = blockIdx.x;
  int j = threadIdx.x;
  if (j < 74) fs[j] = feats[n * 74 + j];
  __syncthreads();
  float acc = b_in[j];
#pragma unroll
  for (int k = 0; k < 74; ++k) acc = fmaf(fs[k], W_in[k * 128 + j], acc);
  h[(size_t)n * 128 + j] = acc;
}

// ---------------- per-layer BN scale/shift precompute ----------------
__global__ void k_bnprep(const float* __restrict__ g, const float* __restrict__ b,
                         const float* __restrict__ m, const float* __restrict__ v,
                         int layer, float* __restrict__ bnp)
{
  int j = threadIdx.x;  // 128 threads
  float s = g[layer * 128 + j] * rsqrtf(v[layer * 128 + j] + 1e-5f);
  bnp[j] = s;
  bnp[128 + j] = b[layer * 128 + j] - m[layer * 128 + j] * s;
}

// ---------------- GRU weight prepack (once): Wp[kb][n][32k] bf16 + bcat ----------------
// Wcat[512][256]: n<128:r n<256:z n<384:inn n<512:hn. A = [x | agg], K=256.
__global__ __launch_bounds__(256) void k_wpack(
    const float* __restrict__ w_ih, const float* __restrict__ w_hh,
    const float* __restrict__ b_ih, const float* __restrict__ b_hh,
    unsigned short* __restrict__ Wp, float* __restrict__ bcat)
{
  int idx = blockIdx.x * 256 + threadIdx.x;  // 512*256 threads
  int n = idx >> 8, k = idx & 255;
  float val;
  if (n < 256) {
    val = (k < 128) ? fmaf(1.00001f, w_ih[n * 256 + k], w_hh[n * 128 + k])
                    : w_ih[n * 256 + k];
  } else if (n < 384) {
    val = (k < 128) ? 1.00001f * w_ih[n * 256 + k] : w_ih[n * 256 + k];
  } else {
    int g = n - 128;
    val = (k < 128) ? w_hh[g * 128 + k] : 0.f;
  }
  Wp[(size_t)(k >> 5) * 16384 + n * 32 + (k & 31)] = bf16r_(val);
  if (k == 0) {
    float bc;
    if (n < 256) bc = b_ih[n] + b_hh[n];
    else if (n < 384) bc = b_ih[n];
    else bc = b_hh[n - 128];
    bcat[n] = bc;
  }
}

// ---------------- prep: x = BN(h) -> swizzled bf16 hi/lo planes; + wnode ----------------
// thread t: row = t>>4, chunk c = t&15 (8 channels). Swizzle: chunk stored at c^(row&7).
__global__ __launch_bounds__(256) void k_prep(
    const float* __restrict__ h, const float* __restrict__ bnp,
    const float* __restrict__ w_aw, const float* __restrict__ b_aw,
    unsigned short* __restrict__ xhi, unsigned short* __restrict__ xlo,
    float* __restrict__ wnode)
{
  int t = blockIdx.x * 256 + threadIdx.x;
  int row = t >> 4, c = t & 15;
  const float* hp = h + (size_t)row * 128 + c * 8;
  float4 h0 = *(const float4*)(hp);
  float4 h1 = *(const float4*)(hp + 4);
  float4 s0 = *(const float4*)(bnp + c * 8);
  float4 s1 = *(const float4*)(bnp + c * 8 + 4);
  float4 t0 = *(const float4*)(bnp + 128 + c * 8);
  float4 t1 = *(const float4*)(bnp + 128 + c * 8 + 4);
  float x[8] = { fmaf(h0.x, s0.x, t0.x), fmaf(h0.y, s0.y, t0.y),
                 fmaf(h0.z, s0.z, t0.z), fmaf(h0.w, s0.w, t0.w),
                 fmaf(h1.x, s1.x, t1.x), fmaf(h1.y, s1.y, t1.y),
                 fmaf(h1.z, s1.z, t1.z), fmaf(h1.w, s1.w, t1.w) };
  unsigned hiw[4], low[4];
#pragma unroll
  for (int i = 0; i < 4; ++i) {
    unsigned short ha = bf16r_(x[2 * i]), hb = bf16r_(x[2 * i + 1]);
    unsigned short la = bf16r_(x[2 * i] - bf16tof_(ha));
    unsigned short lb = bf16r_(x[2 * i + 1] - bf16tof_(hb));
    hiw[i] = (unsigned)ha | ((unsigned)hb << 16);
    low[i] = (unsigned)la | ((unsigned)lb << 16);
  }
  size_t dst = (size_t)row * 16 + (c ^ (row & 7));
  ((uint4*)xhi)[dst] = make_uint4(hiw[0], hiw[1], hiw[2], hiw[3]);
  ((uint4*)xlo)[dst] = make_uint4(low[0], low[1], low[2], low[3]);
  // wnode = sigmoid(h . w_aw + b): reduce across 16 threads of this row
  const float4 wa0 = *(const float4*)(w_aw + c * 8);
  const float4 wa1 = *(const float4*)(w_aw + c * 8 + 4);
  float p = h0.x * wa0.x + h0.y * wa0.y + h0.z * wa0.z + h0.w * wa0.w +
            h1.x * wa1.x + h1.y * wa1.y + h1.z * wa1.z + h1.w * wa1.w;
#pragma unroll
  for (int o = 8; o > 0; o >>= 1) p += __shfl_xor(p, o);
  if (c == 0) wnode[row] = sig_(p + b_aw[0]);
}

// ---------------- CSR build: histogram -> scan -> fill ----------------
__global__ __launch_bounds__(256) void k_hist(const int* __restrict__ dst, int* __restrict__ deg)
{
  int t = blockIdx.x * 256 + threadIdx.x;
  if (t < NE) atomicAdd(&deg[dst[t]], 1);
}

__global__ __launch_bounds__(1024) void k_scan(const int* __restrict__ deg, int* __restrict__ rowptr)
{
  __shared__ int part[1024];
  const int t = threadIdx.x;
  const int CH = 49;
  int beg = t * CH, end = min(beg + CH, NN);
  int s = 0;
  for (int i = beg; i < end; ++i) s += deg[i];
  part[t] = s;
  __syncthreads();
  for (int o = 1; o < 1024; o <<= 1) {
    int v = (t >= o) ? part[t - o] : 0;
    __syncthreads();
    part[t] += v;
    __syncthreads();
  }
  int base = part[t] - s;
  for (int i = beg; i < end; ++i) { rowptr[i] = base; base += deg[i]; }
  if (t == 0) rowptr[NN] = NE;
}

__global__ __launch_bounds__(256) void k_fill(
    const int* __restrict__ src, const int* __restrict__ dst,
    int* __restrict__ pos, int* __restrict__ col)
{
  int t = blockIdx.x * 256 + threadIdx.x;
  if (t >= NE) return;
  int p = atomicAdd(&pos[dst[t]], 1);
  col[p] = src[t];
}

// ---------------- CSR gather from x_hi plane -> split-bf16 agg planes ----------------
// one wave per node; lane handles 2 channels (one uint of a swizzled chunk)
__global__ __launch_bounds__(256) void k_gather(
    const unsigned short* __restrict__ xhi, const int* __restrict__ rowptr,
    const int* __restrict__ col,
    unsigned short* __restrict__ agghi, unsigned short* __restrict__ agglo)
{
  int n = blockIdx.x * 4 + (threadIdx.x >> 6);
  int lane = threadIdx.x & 63;
  int c = lane >> 2, q = lane & 3;
  int lo = rowptr[n], hi = rowptr[n + 1];
  const unsigned* xp = (const unsigned*)xhi;
  float s0 = 0.f, s1 = 0.f, s2 = 0.f, s3 = 0.f;
  int e = lo;
  for (; e + 1 < hi; e += 2) {
    int r0 = col[e], r1 = col[e + 1];
    unsigned u0 = xp[(size_t)r0 * 64 + ((c ^ (r0 & 7)) << 2) + q];
    unsigned u1 = xp[(size_t)r1 * 64 + ((c ^ (r1 & 7)) << 2) + q];
    s0 += bf16tof_((unsigned short)(u0 & 0xFFFF));
    s1 += bf16tof_((unsigned short)(u0 >> 16));
    s2 += bf16tof_((unsigned short)(u1 & 0xFFFF));
    s3 += bf16tof_((unsigned short)(u1 >> 16));
  }
  if (e < hi) {
    int r0 = col[e];
    unsigned u0 = xp[(size_t)r0 * 64 + ((c ^ (r0 & 7)) << 2) + q];
    s0 += bf16tof_((unsigned short)(u0 & 0xFFFF));
    s1 += bf16tof_((unsigned short)(u0 >> 16));
  }
  float a0 = s0 + s2, a1 = s1 + s3;
  unsigned short h0 = bf16r_(a0), h1 = bf16r_(a1);
  unsigned short l0 = bf16r_(a0 - bf16tof_(h0)), l1 = bf16r_(a1 - bf16tof_(h1));
  size_t w = (size_t)n * 64 + ((c ^ (n & 7)) << 2) + q;
  ((unsigned*)agghi)[w] = (unsigned)h0 | ((unsigned)h1 << 16);
  ((unsigned*)agglo)[w] = (unsigned)l0 | ((unsigned)l1 << 16);
}

__device__ __forceinline__ int lbound_(const int* __restrict__ a, int n, int key)
{
  int lo = 0, hi = n;
  while (lo < hi) { int mid = (lo + hi) >> 1; if (a[mid] < key) lo = mid + 1; else hi = mid; }
  return lo;
}

// ---------------- graph readout: reps[l][g] = [sum w*h | max h] ----------------
__global__ __launch_bounds__(128) void k_readout(
    const float* __restrict__ h, const float* __restrict__ wnode,
    const int* __restrict__ n2g, float* __restrict__ reps, int layer)
{
  int g = blockIdx.x;
  int j = threadIdx.x;
  int lo = lbound_(n2g, NN, g);
  int hi = lbound_(n2g, NN, g + 1);
  float ws = 0.f, hm = -INFINITY;
  for (int n = lo; n < hi; ++n) {
    float hv = h[(size_t)n * 128 + j];
    ws = fmaf(wnode[n], hv, ws);
    hm = fmaxf(hm, hv);
  }
  if (hi == lo) hm = 0.f;
  float* r = reps + ((size_t)layer * NG + g) * 256;
  r[j] = ws;
  r[128 + j] = hm;
}

// ---------------- MFMA GRU: gates = [x|agg] @ Wcat^T; epilogue gates+celu+residual ----------------
// block 256 thr (4 waves), M-tile = 64 rows (wave w owns rows w*16..+15), N=512, K=256
__global__ __launch_bounds__(256, 2) void k_gru_mfma(
    float* __restrict__ h,
    const unsigned short* __restrict__ xhi, const unsigned short* __restrict__ xlo,
    const unsigned short* __restrict__ agghi, const unsigned short* __restrict__ agglo,
    const unsigned short* __restrict__ Wp, const float* __restrict__ bcat,
    const float* __restrict__ bnp)
{
  __shared__ alignas(16) unsigned short Axh[8192];  // 64 rows x 128 bf16 (swizzled chunks)
  __shared__ alignas(16) unsigned short Axl[8192];
  __shared__ alignas(16) unsigned short Aah[8192];
  __shared__ alignas(16) unsigned short Aal[8192];
  const int tid = threadIdx.x;
  const int m0 = blockIdx.x * 64;

  {  // stage 4 plane tiles (verbatim: planes are pre-swizzled; m0%8==0 keeps alignment)
    const uint4* sxh = (const uint4*)(xhi + (size_t)m0 * 128);
    const uint4* sxl = (const uint4*)(xlo + (size_t)m0 * 128);
    const uint4* sah = (const uint4*)(agghi + (size_t)m0 * 128);
    const uint4* sal = (const uint4*)(agglo + (size_t)m0 * 128);
    uint4* dxh = (uint4*)Axh; uint4* dxl = (uint4*)Axl;
    uint4* dah = (uint4*)Aah; uint4* dal = (uint4*)Aal;
    for (int i = tid; i < 1024; i += 256) { dxh[i] = sxh[i]; dxl[i] = sxl[i]; }
    for (int i = tid; i < 1024; i += 256) { dah[i] = sah[i]; dal[i] = sal[i]; }
  }
  __syncthreads();

  const int lane = tid & 63;
  const int wv = tid >> 6;
  const int mfr = lane & 15;   // A-row / D-col selector
  const int kq = lane >> 4;    // k-quad
  const int mm = wv * 16 + mfr;
  const int rowb = mm * 256;   // byte offset of LDS row
  const int sw = mm & 7;

  f32x4 acc[32];
#pragma unroll
  for (int i = 0; i < 32; ++i) acc[i] = (f32x4){0.f, 0.f, 0.f, 0.f};

  for (int kb = 0; kb < 8; ++kb) {
    int cs = ((((kb & 3) * 4 + kq) ^ sw) << 4);
    const char* phi = (kb < 4) ? (const char*)Axh : (const char*)Aah;
    const char* plo = (kb < 4) ? (const char*)Axl : (const char*)Aal;
    bfrag8 ahi = *(const bfrag8*)(phi + rowb + cs);
    bfrag8 alo = *(const bfrag8*)(plo + rowb + cs);
    const unsigned short* wb = Wp + (size_t)kb * 16384 + mfr * 32 + kq * 8;
#pragma unroll
    for (int nf = 0; nf < 32; ++nf) {
      bfrag8 bw = *(const bfrag8*)(wb + nf * 512);
      acc[nf] = __builtin_amdgcn_mfma_f32_16x16x32_bf16(ahi, bw, acc[nf], 0, 0, 0);
      acc[nf] = __builtin_amdgcn_mfma_f32_16x16x32_bf16(alo, bw, acc[nf], 0, 0, 0);
    }
  }

  // epilogue: node = m0 + wv*16 + kq*4 + reg, channel j = nf*16 + mfr (nf 0..7)
  int nodeb = m0 + wv * 16 + kq * 4;
#pragma unroll
  for (int nf = 0; nf < 8; ++nf) {
    int j = nf * 16 + mfr;
    float sc = bnp[j], sh = bnp[128 + j];
    float br = bcat[j], bz = bcat[128 + j], bi = bcat[256 + j], bh = bcat[384 + j];
#pragma unroll
    for (int reg = 0; reg < 4; ++reg) {
      int node = nodeb + reg;
      if (node < NN) {
        float hv = h[(size_t)node * 128 + j];
        float x = fmaf(hv, sc, sh);
        float r = sig_(acc[nf][reg] + br);
        float z = sig_(acc[nf + 8][reg] + bz);
        float ng = tanhf(fmaf(r, acc[nf + 24][reg] + bh, acc[nf + 16][reg] + bi));
        float o = (1.f - z) * ng + z * x;
        float hc = (o > 0.f) ? o : expm1f(o);
        h[(size_t)node * 128 + j] = hv + hc;
      }
    }
  }
}

// ---------------- fused LSTM step (fp32) ----------------
__global__ __launch_bounds__(256) void k_lstm(
    const float* __restrict__ x, const float* __restrict__ h_in, const float* __restrict__ c_in,
    const float* __restrict__ w_ih, const float* __restrict__ w_hh,
    const float* __restrict__ b_ih, const float* __restrict__ b_hh,
    float* __restrict__ h_out, float* __restrict__ c_out)
{
  __shared__ float V[16][384];
  __shared__ float WT[16][516];
  const int tid = threadIdx.x;
  const int tx = tid & 63;
  const int ty = tid >> 6;
  const int n0 = blockIdx.x * 16;

  for (int idx = tid; idx < 16 * 256; idx += 256) {
    int nn = idx >> 8, j = idx & 255;
    V[nn][j] = x[(n0 + nn) * 256 + j];
  }
  for (int idx = tid; idx < 16 * 128; idx += 256) {
    int nn = idx >> 7, j = idx & 127;
    V[nn][256 + j] = h_in[(n0 + nn) * 128 + j];
  }

  float acc[8][4];
#pragma unroll
  for (int i = 0; i < 8; ++i) {
    float b = b_ih[i * 64 + tx] + b_hh[i * 64 + tx];
    acc[i][0] = acc[i][1] = acc[i][2] = acc[i][3] = b;
  }

  for (int t = 0; t < 16; ++t) {
    __syncthreads();
    {
      int c = tid >> 2, q = tid & 3;
#pragma unroll
      for (int p = 0; p < 8; ++p) {
        int cc = c + p * 64;
        const float4 w = *(const float4*)(w_ih + cc * 256 + t * 16 + q * 4);
        WT[q * 4 + 0][cc] = w.x; WT[q * 4 + 1][cc] = w.y;
        WT[q * 4 + 2][cc] = w.z; WT[q * 4 + 3][cc] = w.w;
      }
    }
    __syncthreads();
#pragma unroll
    for (int kk = 0; kk < 16; ++kk) {
      int k = t * 16 + kk;
      float a0 = V[ty * 4 + 0][k], a1 = V[ty * 4 + 1][k];
      float a2 = V[ty * 4 + 2][k], a3 = V[ty * 4 + 3][k];
#pragma unroll
      for (int i = 0; i < 8; ++i) {
        float w = WT[kk][i * 64 + tx];
        acc[i][0] = fmaf(w, a0, acc[i][0]);
        acc[i][1] = fmaf(w, a1, acc[i][1]);
        acc[i][2] = fmaf(w, a2, acc[i][2]);
        acc[i][3] = fmaf(w, a3, acc[i][3]);
      }
    }
  }

  for (int t = 0; t < 8; ++t) {
    __syncthreads();
    {
      int c = tid >> 2, q = tid & 3;
#pragma unroll
      for (int p = 0; p < 8; ++p) {
        int cc = c + p * 64;
        const float4 w = *(const float4*)(w_hh + cc * 128 + t * 16 + q * 4);
        WT[q * 4 + 0][cc] = w.x; WT[q * 4 + 1][cc] = w.y;
        WT[q * 4 + 2][cc] = w.z; WT[q * 4 + 3][cc] = w.w;
      }
    }
    __syncthreads();
#pragma unroll
    for (int kk = 0; kk < 16; ++kk) {
      int k = t * 16 + kk;
      float a0 = V[ty * 4 + 0][256 + k], a1 = V[ty * 4 + 1][256 + k];
      float a2 = V[ty * 4 + 2][256 + k], a3 = V[ty * 4 + 3][256 + k];
#pragma unroll
      for (int i = 0; i < 8; ++i) {
        float w = WT[kk][i * 64 + tx];
        acc[i][0] = fmaf(w, a0, acc[i][0]);
        acc[i][1] = fmaf(w, a1, acc[i][1]);
        acc[i][2] = fmaf(w, a2, acc[i][2]);
        acc[i][3] = fmaf(w, a3, acc[i][3]);
      }
    }
  }

#pragma unroll
  for (int nd = 0; nd < 4; ++nd) {
    int n = n0 + ty * 4 + nd;
#pragma unroll
    for (int half = 0; half < 2; ++half) {
      int j = half * 64 + tx;
      float ig = sig_(acc[0 + half][nd]);
      float fg = sig_(acc[2 + half][nd]);
      float gg = tanhf(acc[4 + half][nd]);
      float og = sig_(acc[6 + half][nd]);
      float cn = fmaf(fg, c_in[n * 128 + j], ig * gg);
      c_out[n * 128 + j] = cn;
      h_out[n * 128 + j] = og * tanhf(cn);
    }
  }
}

// ---------------- final projection ----------------
__global__ __launch_bounds__(256) void k_final(
    const float* __restrict__ yf, const float* __restrict__ yb,
    const float* __restrict__ W_out, const float* __restrict__ b_out,
    float* __restrict__ out)
{
  int tid = threadIdx.x;
  int g = blockIdx.x * 4 + (tid >> 6);
  int lane = tid & 63;
  float a0 = 0.f, a1 = 0.f;
  for (int k = lane; k < 128; k += 64) {
    float v = yf[g * 128 + k];
    a0 = fmaf(v, W_out[k * 2 + 0], a0);
    a1 = fmaf(v, W_out[k * 2 + 1], a1);
    float u = yb[g * 128 + k];
    a0 = fmaf(u, W_out[(128 + k) * 2 + 0], a0);
    a1 = fmaf(u, W_out[(128 + k) * 2 + 1], a1);
  }
#pragma unroll
  for (int o = 32; o > 0; o >>= 1) { a0 += __shfl_xor(a0, o); a1 += __shfl_xor(a1, o); }
  if (lane == 0) {
    out[g * 2 + 0] = a0 + b_out[0];
    out[g * 2 + 1] = a1 + b_out[1];
  }
}

extern "C" void kernel_launch(void* const* d_in, const int* in_sizes, int n_in,
                              void* d_out, int out_size, void* d_ws, size_t ws_size,
                              hipStream_t stream)
{
  (void)in_sizes; (void)n_in; (void)out_size; (void)ws_size;
  const float* feats   = (const float*)d_in[0];
  const int*   src     = (const int*)d_in[1];
  const int*   dst     = (const int*)d_in[2];
  const int*   n2g     = (const int*)d_in[3];
  const float* W_in    = (const float*)d_in[4];
  const float* b_in    = (const float*)d_in[5];
  const float* bng     = (const float*)d_in[6];
  const float* bnb     = (const float*)d_in[7];
  const float* bnm     = (const float*)d_in[8];
  const float* bnv     = (const float*)d_in[9];
  const float* gw_ih   = (const float*)d_in[10];
  const float* gw_hh   = (const float*)d_in[11];
  const float* gb_ih   = (const float*)d_in[12];
  const float* gb_hh   = (const float*)d_in[13];
  const float* w_aw    = (const float*)d_in[14];
  const float* b_aw    = (const float*)d_in[15];
  const float* lwih_f  = (const float*)d_in[16];
  const float* lwhh_f  = (const float*)d_in[17];
  const float* lbih_f  = (const float*)d_in[18];
  const float* lbhh_f  = (const float*)d_in[19];
  const float* lwih_b  = (const float*)d_in[20];
  const float* lwhh_b  = (const float*)d_in[21];
  const float* lbih_b  = (const float*)d_in[22];
  const float* lbhh_b  = (const float*)d_in[23];
  const float* W_out   = (const float*)d_in[24];
  const float* b_out   = (const float*)d_in[25];
  float* out = (float*)d_out;

  float* ws = (float*)d_ws;
  size_t off = 0;
  auto alloc = [&](size_t n) { float* p = ws + off; off += (n + 63) & ~(size_t)63; return p; };
  float* h      = alloc((size_t)NP * 128);
  unsigned short* xhi   = (unsigned short*)alloc((size_t)NP * 64);
  unsigned short* xlo   = (unsigned short*)alloc((size_t)NP * 64);
  unsigned short* agghi = (unsigned short*)alloc((size_t)NP * 64);
  unsigned short* agglo = (unsigned short*)alloc((size_t)NP * 64);
  unsigned short* Wp    = (unsigned short*)alloc(65536);
  float* bcat   = alloc(512);
  float* wnode  = alloc(NN);
  float* bnp    = alloc(256);
  float* reps   = alloc((size_t)NL * NG * 256);
  float* zz     = alloc((size_t)NG * 128);   // zeros for h0 and c0
  float* ha     = alloc((size_t)NG * 128);
  float* ca     = alloc((size_t)NG * 128);
  float* hb     = alloc((size_t)NG * 128);
  float* cb     = alloc((size_t)NG * 128);
  float* yf     = alloc((size_t)NG * 128);
  float* cf     = alloc((size_t)NG * 128);
  int* deg    = (int*)alloc(NN);
  int* rowptr = (int*)alloc(NN + 1);
  int* pos    = (int*)alloc(NN);
  int* colidx = (int*)alloc(NE);

  // ---- one-time: CSR build + GRU weight prepack ----
  hipMemsetAsync(deg, 0, (size_t)NN * sizeof(int), stream);
  k_hist<<<(NE + 255) / 256, 256, 0, stream>>>(dst, deg);
  k_scan<<<1, 1024, 0, stream>>>(deg, rowptr);
  hipMemcpyAsync(pos, rowptr, (size_t)NN * sizeof(int), hipMemcpyDeviceToDevice, stream);
  k_fill<<<(NE + 255) / 256, 256, 0, stream>>>(src, dst, pos, colidx);
  k_wpack<<<512, 256, 0, stream>>>(gw_ih, gw_hh, gb_ih, gb_hh, Wp, bcat);

  k_input_proj<<<NN, 128, 0, stream>>>(feats, W_in, b_in, h);

  for (int l = 0; l < NL; ++l) {
    k_bnprep<<<1, 128, 0, stream>>>(bng, bnb, bnm, bnv, l, bnp);
    k_prep<<<3125, 256, 0, stream>>>(h, bnp, w_aw, b_aw, xhi, xlo, wnode);
    k_gather<<<NN / 4, 256, 0, stream>>>(xhi, rowptr, colidx, agghi, agglo);
    k_readout<<<NG, 128, 0, stream>>>(h, wnode, n2g, reps, l);
    k_gru_mfma<<<NP / 64, 256, 0, stream>>>(h, xhi, xlo, agghi, agglo, Wp, bcat, bnp);
  }

  hipMemsetAsync(zz, 0, (size_t)NG * 128 * sizeof(float), stream);

  // forward: only step 0 needed for y_f[0]
  k_lstm<<<NG / 16, 256, 0, stream>>>(reps, zz, zz, lwih_f, lwhh_f, lbih_f, lbhh_f, yf, cf);

  // backward: 5 steps over rep[4..0]
  k_lstm<<<NG / 16, 256, 0, stream>>>(reps + (size_t)4 * NG * 256, zz, zz, lwih_b, lwhh_b, lbih_b, lbhh_b, ha, ca);
  k_lstm<<<NG / 16, 256, 0, stream>>>(reps + (size_t)3 * NG * 256, ha, ca, lwih_b, lwhh_b, lbih_b, lbhh_b, hb, cb);
  k_lstm<<<NG / 16, 256, 0, stream>>>(reps + (size_t)2 * NG * 256, hb, cb, lwih_b, lwhh_b, lbih_b, lbhh_b, ha, ca);
  k_lstm<<<NG / 16, 256, 0, stream>>>(reps + (size_t)1 * NG * 256, ha, ca, lwih_b, lwhh_b, lbih_b, lbhh_b, hb, cb);
  k_lstm<<<NG / 16, 256, 0, stream>>>(reps + (size_t)0 * NG * 256, hb, cb, lwih_b, lwhh_b, lbih_b, lbhh_b, ha, ca);

  k_final<<<NG / 4, 256, 0, stream>>>(yf, ha, W_out, b_out, out);
}

// Round 4
// 1426.707 us; speedup vs baseline: 5.4380x; 1.2248x over previous
//
#include <hip/hip_runtime.h>
#include <math.h>

#define NN 50000
#define NP 50048   // padded rows (multiple of 64)
#define NE 600000
#define NG 1024
#define NL 5
#define NT (NP / 64)     // 782 M-tiles
#define GRUGRID 256      // persistent blocks (1 per CU)
// Hd = 128, Fin = 74, C = 2

typedef __attribute__((ext_vector_type(8))) short bfrag8;
typedef __attribute__((ext_vector_type(4))) float f32x4;

__device__ __forceinline__ float sig_(float x) { return 1.f / (1.f + expf(-x)); }

__device__ __forceinline__ unsigned short bf16r_(float x) {
  union { float f; unsigned u; } v; v.f = x;
  unsigned u = v.u;
  return (unsigned short)((u + 0x7FFFu + ((u >> 16) & 1u)) >> 16);
}
__device__ __forceinline__ float bf16tof_(unsigned short h) {
  union { float f; unsigned u; } v; v.u = ((unsigned)h) << 16;
  return v.f;
}

// async global->LDS, 16B per lane; lds dst = uniform base + lane*16
__device__ __forceinline__ void gl_lds16(const unsigned short* g, unsigned short* l) {
  __builtin_amdgcn_global_load_lds(
      (const __attribute__((address_space(1))) unsigned int*)g,
      (__attribute__((address_space(3))) unsigned int*)l, 16, 0, 0);
}

// ---------------- input projection: h = feats @ W_in + b_in ----------------
__global__ __launch_bounds__(128) void k_input_proj(
    const float* __restrict__ feats, const float* __restrict__ W_in,
    const float* __restrict__ b_in, float* __restrict__ h)
{
  __shared__ float fs[74];
  int n = blockIdx.x;
  int j = threadIdx.x;
  if (j < 74) fs[j] = feats[n * 74 + j];
  __syncthreads();
  float acc = b_in[j];
#pragma unroll
  for (int k = 0; k < 74; ++k) acc = fmaf(fs[k], W_in[k * 128 + j], acc);
  h[(size_t)n * 128 + j] = acc;
}

// ---------------- per-layer BN scale/shift precompute ----------------
__global__ void k_bnprep(const float* __restrict__ g, const float* __restrict__ b,
                         const float* __restrict__ m, const float* __restrict__ v,
                         int layer, float* __restrict__ bnp)
{
  int j = threadIdx.x;  // 128 threads
  float s = g[layer * 128 + j] * rsqrtf(v[layer * 128 + j] + 1e-5f);
  bnp[j] = s;
  bnp[128 + j] = b[layer * 128 + j] - m[layer * 128 + j] * s;
}

// ---------------- GRU weight prepack (once): Wp[kb][n][32k] bf16 + bcat ----------------
// Wcat[512][256]: n<128:r n<256:z n<384:inn n<512:hn. A = [x | agg], K=256.
__global__ __launch_bounds__(256) void k_wpack(
    const float* __restrict__ w_ih, const float* __restrict__ w_hh,
    const float* __restrict__ b_ih, const float* __restrict__ b_hh,
    unsigned short* __restrict__ Wp, float* __restrict__ bcat)
{
  int idx = blockIdx.x * 256 + threadIdx.x;  // 512*256 threads
  int n = idx >> 8, k = idx & 255;
  float val;
  if (n < 256) {
    val = (k < 128) ? fmaf(1.00001f, w_ih[n * 256 + k], w_hh[n * 128 + k])
                    : w_ih[n * 256 + k];
  } else if (n < 384) {
    val = (k < 128) ? 1.00001f * w_ih[n * 256 + k] : w_ih[n * 256 + k];
  } else {
    int g = n - 128;
    val = (k < 128) ? w_hh[g * 128 + k] : 0.f;
  }
  Wp[(size_t)(k >> 5) * 16384 + n * 32 + (k & 31)] = bf16r_(val);
  if (k == 0) {
    float bc;
    if (n < 256) bc = b_ih[n] + b_hh[n];
    else if (n < 384) bc = b_ih[n];
    else bc = b_hh[n - 128];
    bcat[n] = bc;
  }
}

// ---------------- prep: x = BN(h) -> swizzled bf16 hi/lo planes; + wnode ----------------
// thread t: row = t>>4, chunk c = t&15 (8 channels). Swizzle: chunk stored at c^(row&7).
__global__ __launch_bounds__(256) void k_prep(
    const float* __restrict__ h, const float* __restrict__ bnp,
    const float* __restrict__ w_aw, const float* __restrict__ b_aw,
    unsigned short* __restrict__ xhi, unsigned short* __restrict__ xlo,
    float* __restrict__ wnode)
{
  int t = blockIdx.x * 256 + threadIdx.x;
  int row = t >> 4, c = t & 15;
  const float* hp = h + (size_t)row * 128 + c * 8;
  float4 h0 = *(const float4*)(hp);
  float4 h1 = *(const float4*)(hp + 4);
  float4 s0 = *(const float4*)(bnp + c * 8);
  float4 s1 = *(const float4*)(bnp + c * 8 + 4);
  float4 t0 = *(const float4*)(bnp + 128 + c * 8);
  float4 t1 = *(const float4*)(bnp + 128 + c * 8 + 4);
  float x[8] = { fmaf(h0.x, s0.x, t0.x), fmaf(h0.y, s0.y, t0.y),
                 fmaf(h0.z, s0.z, t0.z), fmaf(h0.w, s0.w, t0.w),
                 fmaf(h1.x, s1.x, t1.x), fmaf(h1.y, s1.y, t1.y),
                 fmaf(h1.z, s1.z, t1.z), fmaf(h1.w, s1.w, t1.w) };
  unsigned hiw[4], low[4];
#pragma unroll
  for (int i = 0; i < 4; ++i) {
    unsigned short ha = bf16r_(x[2 * i]), hb = bf16r_(x[2 * i + 1]);
    unsigned short la = bf16r_(x[2 * i] - bf16tof_(ha));
    unsigned short lb = bf16r_(x[2 * i + 1] - bf16tof_(hb));
    hiw[i] = (unsigned)ha | ((unsigned)hb << 16);
    low[i] = (unsigned)la | ((unsigned)lb << 16);
  }
  size_t dst = (size_t)row * 16 + (c ^ (row & 7));
  ((uint4*)xhi)[dst] = make_uint4(hiw[0], hiw[1], hiw[2], hiw[3]);
  ((uint4*)xlo)[dst] = make_uint4(low[0], low[1], low[2], low[3]);
  // wnode = sigmoid(h . w_aw + b): reduce across 16 threads of this row
  const float4 wa0 = *(const float4*)(w_aw + c * 8);
  const float4 wa1 = *(const float4*)(w_aw + c * 8 + 4);
  float p = h0.x * wa0.x + h0.y * wa0.y + h0.z * wa0.z + h0.w * wa0.w +
            h1.x * wa1.x + h1.y * wa1.y + h1.z * wa1.z + h1.w * wa1.w;
#pragma unroll
  for (int o = 8; o > 0; o >>= 1) p += __shfl_xor(p, o);
  if (c == 0) wnode[row] = sig_(p + b_aw[0]);
}

// ---------------- CSR build: histogram -> scan -> fill ----------------
__global__ __launch_bounds__(256) void k_hist(const int* __restrict__ dst, int* __restrict__ deg)
{
  int t = blockIdx.x * 256 + threadIdx.x;
  if (t < NE) atomicAdd(&deg[dst[t]], 1);
}

__global__ __launch_bounds__(1024) void k_scan(const int* __restrict__ deg, int* __restrict__ rowptr)
{
  __shared__ int part[1024];
  const int t = threadIdx.x;
  const int CH = 49;
  int beg = t * CH, end = min(beg + CH, NN);
  int s = 0;
  for (int i = beg; i < end; ++i) s += deg[i];
  part[t] = s;
  __syncthreads();
  for (int o = 1; o < 1024; o <<= 1) {
    int v = (t >= o) ? part[t - o] : 0;
    __syncthreads();
    part[t] += v;
    __syncthreads();
  }
  int base = part[t] - s;
  for (int i = beg; i < end; ++i) { rowptr[i] = base; base += deg[i]; }
  if (t == 0) rowptr[NN] = NE;
}

__global__ __launch_bounds__(256) void k_fill(
    const int* __restrict__ src, const int* __restrict__ dst,
    int* __restrict__ pos, int* __restrict__ col)
{
  int t = blockIdx.x * 256 + threadIdx.x;
  if (t >= NE) return;
  int p = atomicAdd(&pos[dst[t]], 1);
  col[p] = src[t];
}

// ---------------- CSR gather from x_hi plane -> split-bf16 agg planes ----------------
__global__ __launch_bounds__(256) void k_gather(
    const unsigned short* __restrict__ xhi, const int* __restrict__ rowptr,
    const int* __restrict__ col,
    unsigned short* __restrict__ agghi, unsigned short* __restrict__ agglo)
{
  int n = blockIdx.x * 4 + (threadIdx.x >> 6);
  int lane = threadIdx.x & 63;
  int c = lane >> 2, q = lane & 3;
  int lo = rowptr[n], hi = rowptr[n + 1];
  const unsigned* xp = (const unsigned*)xhi;
  float s0 = 0.f, s1 = 0.f, s2 = 0.f, s3 = 0.f;
  int e = lo;
  for (; e + 1 < hi; e += 2) {
    int r0 = col[e], r1 = col[e + 1];
    unsigned u0 = xp[(size_t)r0 * 64 + ((c ^ (r0 & 7)) << 2) + q];
    unsigned u1 = xp[(size_t)r1 * 64 + ((c ^ (r1 & 7)) << 2) + q];
    s0 += bf16tof_((unsigned short)(u0 & 0xFFFF));
    s1 += bf16tof_((unsigned short)(u0 >> 16));
    s2 += bf16tof_((unsigned short)(u1 & 0xFFFF));
    s3 += bf16tof_((unsigned short)(u1 >> 16));
  }
  if (e < hi) {
    int r0 = col[e];
    unsigned u0 = xp[(size_t)r0 * 64 + ((c ^ (r0 & 7)) << 2) + q];
    s0 += bf16tof_((unsigned short)(u0 & 0xFFFF));
    s1 += bf16tof_((unsigned short)(u0 >> 16));
  }
  float a0 = s0 + s2, a1 = s1 + s3;
  unsigned short h0 = bf16r_(a0), h1 = bf16r_(a1);
  unsigned short l0 = bf16r_(a0 - bf16tof_(h0)), l1 = bf16r_(a1 - bf16tof_(h1));
  size_t w = (size_t)n * 64 + ((c ^ (n & 7)) << 2) + q;
  ((unsigned*)agghi)[w] = (unsigned)h0 | ((unsigned)h1 << 16);
  ((unsigned*)agglo)[w] = (unsigned)l0 | ((unsigned)l1 << 16);
}

__device__ __forceinline__ int lbound_(const int* __restrict__ a, int n, int key)
{
  int lo = 0, hi = n;
  while (lo < hi) { int mid = (lo + hi) >> 1; if (a[mid] < key) lo = mid + 1; else hi = mid; }
  return lo;
}

// ---------------- graph readout: reps[l][g] = [sum w*h | max h] ----------------
__global__ __launch_bounds__(128) void k_readout(
    const float* __restrict__ h, const float* __restrict__ wnode,
    const int* __restrict__ n2g, float* __restrict__ reps, int layer)
{
  int g = blockIdx.x;
  int j = threadIdx.x;
  int lo = lbound_(n2g, NN, g);
  int hi = lbound_(n2g, NN, g + 1);
  float ws = 0.f, hm = -INFINITY;
  for (int n = lo; n < hi; ++n) {
    float hv = h[(size_t)n * 128 + j];
    ws = fmaf(wnode[n], hv, ws);
    hm = fmaxf(hm, hv);
  }
  if (hi == lo) hm = 0.f;
  float* r = reps + ((size_t)layer * NG + g) * 256;
  r[j] = ws;
  r[128 + j] = hm;
}

// ---------------- persistent MFMA GRU: W in registers, A double-buffered in LDS ----------------
// grid 256 (1 block/CU), 4 waves; wave wv owns channel group [wv*32, wv*32+32) across all 4 gates.
// Per M-tile of 64 rows: stage 4 A-planes (64KB) via global_load_lds (prefetch t+GRUGRID),
// compute 8 kb x {8 ds_read_b128 + 64 MFMA}, fused gate/celu/residual epilogue.
__global__ __launch_bounds__(256, 1) void k_gru_mfma(
    float* __restrict__ h,
    const unsigned short* __restrict__ xhi, const unsigned short* __restrict__ xlo,
    const unsigned short* __restrict__ agghi, const unsigned short* __restrict__ agglo,
    const unsigned short* __restrict__ Wp, const float* __restrict__ bcat,
    const float* __restrict__ bnp)
{
  __shared__ alignas(16) unsigned short A[2][32768];  // 2 x 64KB: [xhi|xlo|agghi|agglo] tiles
  const int tid = threadIdx.x;
  const int lane = tid & 63;
  const int wv = tid >> 6;
  const int mfr = lane & 15;   // A-row / B-col / D-col selector
  const int kq = lane >> 4;    // k-quad / D-row-quad

  // ---- load this wave's W slice into registers (stays resident) ----
  // nf = g*2+u -> col n = g*128 + wv*32 + u*16 + mfr
  bfrag8 wreg[8][8];
#pragma unroll
  for (int kb = 0; kb < 8; ++kb) {
#pragma unroll
    for (int f = 0; f < 8; ++f) {
      int g = f >> 1, u = f & 1;
      int n = g * 128 + wv * 32 + u * 16 + mfr;
      wreg[kb][f] = *(const bfrag8*)(Wp + (size_t)kb * 16384 + n * 32 + kq * 8);
    }
  }

  // ---- stage helper (issues 16 async 1KB-per-wave chunks) ----
  auto stage = [&](int buf, int tile) {
    size_t goff = (size_t)tile * 64 * 128;  // shorts
    const unsigned short* srcs[4] = { xhi + goff, xlo + goff, agghi + goff, agglo + goff };
#pragma unroll
    for (int p = 0; p < 4; ++p) {
#pragma unroll
      for (int it = 0; it < 4; ++it) {
        int off = it * 2048 + wv * 512;  // shorts
        gl_lds16(srcs[p] + off + lane * 8, &A[buf][p * 8192 + off]);
      }
    }
  };

  int tile = blockIdx.x;
  stage(0, tile);
  __syncthreads();  // drains vmcnt + barrier
  int cur = 0;

  while (true) {
    int nxt = tile + GRUGRID;
    if (nxt < NT) stage(cur ^ 1, nxt);  // async prefetch overlaps compute

    f32x4 acc[4][8];
#pragma unroll
    for (int m = 0; m < 4; ++m)
#pragma unroll
      for (int f = 0; f < 8; ++f) acc[m][f] = (f32x4){0.f, 0.f, 0.f, 0.f};

    const char* Ab = (const char*)&A[cur][0];
#pragma unroll
    for (int kb = 0; kb < 8; ++kb) {
      int kp = kb & 3;
      int hoff = (kb < 4) ? 0 : 32768;  // bytes: x-hi vs agg-hi plane
      bfrag8 ah[4], al[4];
#pragma unroll
      for (int m = 0; m < 4; ++m) {
        int row = m * 16 + mfr;
        int cs = (((kp * 4 + kq) ^ (row & 7)) << 4);
        ah[m] = *(const bfrag8*)(Ab + hoff + row * 256 + cs);
        al[m] = *(const bfrag8*)(Ab + hoff + 16384 + row * 256 + cs);
      }
#pragma unroll
      for (int m = 0; m < 4; ++m)
#pragma unroll
        for (int f = 0; f < 8; ++f) {
          acc[m][f] = __builtin_amdgcn_mfma_f32_16x16x32_bf16(ah[m], wreg[kb][f], acc[m][f], 0, 0, 0);
          acc[m][f] = __builtin_amdgcn_mfma_f32_16x16x32_bf16(al[m], wreg[kb][f], acc[m][f], 0, 0, 0);
        }
    }

    // ---- epilogue: rows m*16+kq*4+reg, channels j = wv*32 + u*16 + mfr ----
    int m0 = tile * 64;
#pragma unroll
    for (int u = 0; u < 2; ++u) {
      int j = wv * 32 + u * 16 + mfr;
      float sc = bnp[j], sh = bnp[128 + j];
      float br = bcat[j], bz = bcat[128 + j], bi = bcat[256 + j], bh = bcat[384 + j];
#pragma unroll
      for (int m = 0; m < 4; ++m) {
#pragma unroll
        for (int reg = 0; reg < 4; ++reg) {
          int node = m0 + m * 16 + kq * 4 + reg;
          if (node < NN) {
            float hv = h[(size_t)node * 128 + j];
            float x = fmaf(hv, sc, sh);
            float r = sig_(acc[m][0 + u][reg] + br);
            float z = sig_(acc[m][2 + u][reg] + bz);
            float ng = tanhf(fmaf(r, acc[m][6 + u][reg] + bh, acc[m][4 + u][reg] + bi));
            float o = (1.f - z) * ng + z * x;
            float hc = (o > 0.f) ? o : expm1f(o);
            h[(size_t)node * 128 + j] = hv + hc;
          }
        }
      }
    }

    if (nxt >= NT) break;
    __syncthreads();  // drain prefetch (vmcnt 0) + sync before swapping buffers
    cur ^= 1;
    tile = nxt;
  }
}

// ---------------- fused LSTM step (fp32) ----------------
__global__ __launch_bounds__(256) void k_lstm(
    const float* __restrict__ x, const float* __restrict__ h_in, const float* __restrict__ c_in,
    const float* __restrict__ w_ih, const float* __restrict__ w_hh,
    const float* __restrict__ b_ih, const float* __restrict__ b_hh,
    float* __restrict__ h_out, float* __restrict__ c_out)
{
  __shared__ float V[16][384];
  __shared__ float WT[16][516];
  const int tid = threadIdx.x;
  const int tx = tid & 63;
  const int ty = tid >> 6;
  const int n0 = blockIdx.x * 16;

  for (int idx = tid; idx < 16 * 256; idx += 256) {
    int nn = idx >> 8, j = idx & 255;
    V[nn][j] = x[(n0 + nn) * 256 + j];
  }
  for (int idx = tid; idx < 16 * 128; idx += 256) {
    int nn = idx >> 7, j = idx & 127;
    V[nn][256 + j] = h_in[(n0 + nn) * 128 + j];
  }

  float acc[8][4];
#pragma unroll
  for (int i = 0; i < 8; ++i) {
    float b = b_ih[i * 64 + tx] + b_hh[i * 64 + tx];
    acc[i][0] = acc[i][1] = acc[i][2] = acc[i][3] = b;
  }

  for (int t = 0; t < 16; ++t) {
    __syncthreads();
    {
      int c = tid >> 2, q = tid & 3;
#pragma unroll
      for (int p = 0; p < 8; ++p) {
        int cc = c + p * 64;
        const float4 w = *(const float4*)(w_ih + cc * 256 + t * 16 + q * 4);
        WT[q * 4 + 0][cc] = w.x; WT[q * 4 + 1][cc] = w.y;
        WT[q * 4 + 2][cc] = w.z; WT[q * 4 + 3][cc] = w.w;
      }
    }
    __syncthreads();
#pragma unroll
    for (int kk = 0; kk < 16; ++kk) {
      int k = t * 16 + kk;
      float a0 = V[ty * 4 + 0][k], a1 = V[ty * 4 + 1][k];
      float a2 = V[ty * 4 + 2][k], a3 = V[ty * 4 + 3][k];
#pragma unroll
      for (int i = 0; i < 8; ++i) {
        float w = WT[kk][i * 64 + tx];
        acc[i][0] = fmaf(w, a0, acc[i][0]);
        acc[i][1] = fmaf(w, a1, acc[i][1]);
        acc[i][2] = fmaf(w, a2, acc[i][2]);
        acc[i][3] = fmaf(w, a3, acc[i][3]);
      }
    }
  }

  for (int t = 0; t < 8; ++t) {
    __syncthreads();
    {
      int c = tid >> 2, q = tid & 3;
#pragma unroll
      for (int p = 0; p < 8; ++p) {
        int cc = c + p * 64;
        const float4 w = *(const float4*)(w_hh + cc * 128 + t * 16 + q * 4);
        WT[q * 4 + 0][cc] = w.x; WT[q * 4 + 1][cc] = w.y;
        WT[q * 4 + 2][cc] = w.z; WT[q * 4 + 3][cc] = w.w;
      }
    }
    __syncthreads();
#pragma unroll
    for (int kk = 0; kk < 16; ++kk) {
      int k = t * 16 + kk;
      float a0 = V[ty * 4 + 0][256 + k], a1 = V[ty * 4 + 1][256 + k];
      float a2 = V[ty * 4 + 2][256 + k], a3 = V[ty * 4 + 3][256 + k];
#pragma unroll
      for (int i = 0; i < 8; ++i) {
        float w = WT[kk][i * 64 + tx];
        acc[i][0] = fmaf(w, a0, acc[i][0]);
        acc[i][1] = fmaf(w, a1, acc[i][1]);
        acc[i][2] = fmaf(w, a2, acc[i][2]);
        acc[i][3] = fmaf(w, a3, acc[i][3]);
      }
    }
  }

#pragma unroll
  for (int nd = 0; nd < 4; ++nd) {
    int n = n0 + ty * 4 + nd;
#pragma unroll
    for (int half = 0; half < 2; ++half) {
      int j = half * 64 + tx;
      float ig = sig_(acc[0 + half][nd]);
      float fg = sig_(acc[2 + half][nd]);
      float gg = tanhf(acc[4 + half][nd]);
      float og = sig_(acc[6 + half][nd]);
      float cn = fmaf(fg, c_in[n * 128 + j], ig * gg);
      c_out[n * 128 + j] = cn;
      h_out[n * 128 + j] = og * tanhf(cn);
    }
  }
}

// ---------------- final projection ----------------
__global__ __launch_bounds__(256) void k_final(
    const float* __restrict__ yf, const float* __restrict__ yb,
    const float* __restrict__ W_out, const float* __restrict__ b_out,
    float* __restrict__ out)
{
  int tid = threadIdx.x;
  int g = blockIdx.x * 4 + (tid >> 6);
  int lane = tid & 63;
  float a0 = 0.f, a1 = 0.f;
  for (int k = lane; k < 128; k += 64) {
    float v = yf[g * 128 + k];
    a0 = fmaf(v, W_out[k * 2 + 0], a0);
    a1 = fmaf(v, W_out[k * 2 + 1], a1);
    float u = yb[g * 128 + k];
    a0 = fmaf(u, W_out[(128 + k) * 2 + 0], a0);
    a1 = fmaf(u, W_out[(128 + k) * 2 + 1], a1);
  }
#pragma unroll
  for (int o = 32; o > 0; o >>= 1) { a0 += __shfl_xor(a0, o); a1 += __shfl_xor(a1, o); }
  if (lane == 0) {
    out[g * 2 + 0] = a0 + b_out[0];
    out[g * 2 + 1] = a1 + b_out[1];
  }
}

extern "C" void kernel_launch(void* const* d_in, const int* in_sizes, int n_in,
                              void* d_out, int out_size, void* d_ws, size_t ws_size,
                              hipStream_t stream)
{
  (void)in_sizes; (void)n_in; (void)out_size; (void)ws_size;
  const float* feats   = (const float*)d_in[0];
  const int*   src     = (const int*)d_in[1];
  const int*   dst     = (const int*)d_in[2];
  const int*   n2g     = (const int*)d_in[3];
  const float* W_in    = (const float*)d_in[4];
  const float* b_in    = (const float*)d_in[5];
  const float* bng     = (const float*)d_in[6];
  const float* bnb     = (const float*)d_in[7];
  const float* bnm     = (const float*)d_in[8];
  const float* bnv     = (const float*)d_in[9];
  const float* gw_ih   = (const float*)d_in[10];
  const float* gw_hh   = (const float*)d_in[11];
  const float* gb_ih   = (const float*)d_in[12];
  const float* gb_hh   = (const float*)d_in[13];
  const float* w_aw    = (const float*)d_in[14];
  const float* b_aw    = (const float*)d_in[15];
  const float* lwih_f  = (const float*)d_in[16];
  const float* lwhh_f  = (const float*)d_in[17];
  const float* lbih_f  = (const float*)d_in[18];
  const float* lbhh_f  = (const float*)d_in[19];
  const float* lwih_b  = (const float*)d_in[20];
  const float* lwhh_b  = (const float*)d_in[21];
  const float* lbih_b  = (const float*)d_in[22];
  const float* lbhh_b  = (const float*)d_in[23];
  const float* W_out   = (const float*)d_in[24];
  const float* b_out   = (const float*)d_in[25];
  float* out = (float*)d_out;

  float* ws = (float*)d_ws;
  size_t off = 0;
  auto alloc = [&](size_t n) { float* p = ws + off; off += (n + 63) & ~(size_t)63; return p; };
  float* h      = alloc((size_t)NP * 128);
  unsigned short* xhi   = (unsigned short*)alloc((size_t)NP * 64);
  unsigned short* xlo   = (unsigned short*)alloc((size_t)NP * 64);
  unsigned short* agghi = (unsigned short*)alloc((size_t)NP * 64);
  unsigned short* agglo = (unsigned short*)alloc((size_t)NP * 64);
  unsigned short* Wp    = (unsigned short*)alloc(65536);
  float* bcat   = alloc(512);
  float* wnode  = alloc(NN);
  float* bnp    = alloc(256);
  float* reps   = alloc((size_t)NL * NG * 256);
  float* zz     = alloc((size_t)NG * 128);   // zeros for h0 and c0
  float* ha     = alloc((size_t)NG * 128);
  float* ca     = alloc((size_t)NG * 128);
  float* hb     = alloc((size_t)NG * 128);
  float* cb     = alloc((size_t)NG * 128);
  float* yf     = alloc((size_t)NG * 128);
  float* cf     = alloc((size_t)NG * 128);
  int* deg    = (int*)alloc(NN);
  int* rowptr = (int*)alloc(NN + 1);
  int* pos    = (int*)alloc(NN);
  int* colidx = (int*)alloc(NE);

  // ---- one-time: CSR build + GRU weight prepack ----
  hipMemsetAsync(deg, 0, (size_t)NN * sizeof(int), stream);
  k_hist<<<(NE + 255) / 256, 256, 0, stream>>>(dst, deg);
  k_scan<<<1, 1024, 0, stream>>>(deg, rowptr);
  hipMemcpyAsync(pos, rowptr, (size_t)NN * sizeof(int), hipMemcpyDeviceToDevice, stream);
  k_fill<<<(NE + 255) / 256, 256, 0, stream>>>(src, dst, pos, colidx);
  k_wpack<<<512, 256, 0, stream>>>(gw_ih, gw_hh, gb_ih, gb_hh, Wp, bcat);

  k_input_proj<<<NN, 128, 0, stream>>>(feats, W_in, b_in, h);

  for (int l = 0; l < NL; ++l) {
    k_bnprep<<<1, 128, 0, stream>>>(bng, bnb, bnm, bnv, l, bnp);
    k_prep<<<3125, 256, 0, stream>>>(h, bnp, w_aw, b_aw, xhi, xlo, wnode);
    k_gather<<<NN / 4, 256, 0, stream>>>(xhi, rowptr, colidx, agghi, agglo);
    k_readout<<<NG, 128, 0, stream>>>(h, wnode, n2g, reps, l);
    k_gru_mfma<<<GRUGRID, 256, 0, stream>>>(h, xhi, xlo, agghi, agglo, Wp, bcat, bnp);
  }

  hipMemsetAsync(zz, 0, (size_t)NG * 128 * sizeof(float), stream);

  // forward: only step 0 needed for y_f[0]
  k_lstm<<<NG / 16, 256, 0, stream>>>(reps, zz, zz, lwih_f, lwhh_f, lbih_f, lbhh_f, yf, cf);

  // backward: 5 steps over rep[4..0]
  k_lstm<<<NG / 16, 256, 0, stream>>>(reps + (size_t)4 * NG * 256, zz, zz, lwih_b, lwhh_b, lbih_b, lbhh_b, ha, ca);
  k_lstm<<<NG / 16, 256, 0, stream>>>(reps + (size_t)3 * NG * 256, ha, ca, lwih_b, lwhh_b, lbih_b, lbhh_b, hb, cb);
  k_lstm<<<NG / 16, 256, 0, stream>>>(reps + (size_t)2 * NG * 256, hb, cb, lwih_b, lwhh_b, lbih_b, lbhh_b, ha, ca);
  k_lstm<<<NG / 16, 256, 0, stream>>>(reps + (size_t)1 * NG * 256, ha, ca, lwih_b, lwhh_b, lbih_b, lbhh_b, hb, cb);
  k_lstm<<<NG / 16, 256, 0, stream>>>(reps + (size_t)0 * NG * 256, hb, cb, lwih_b, lwhh_b, lbih_b, lbhh_b, ha, ca);

  k_final<<<NG / 4, 256, 0, stream>>>(yf, ha, W_out, b_out, out);
}

// Round 5
// 1115.487 us; speedup vs baseline: 6.9552x; 1.2790x over previous
//
#include <hip/hip_runtime.h>
#include <math.h>

#define NN 50000
#define NP 50048   // padded rows (multiple of 64)
#define NE 600000
#define NG 1024
#define NL 5
#define NT (NP / 64)     // 782 M-tiles
#define GRUGRID 256      // persistent blocks (1 per CU)
// Hd = 128, Fin = 74, C = 2

typedef __attribute__((ext_vector_type(8))) short bfrag8;
typedef __attribute__((ext_vector_type(4))) float f32x4;

__device__ __forceinline__ float sig_(float x) { return 1.f / (1.f + expf(-x)); }

__device__ __forceinline__ unsigned short bf16r_(float x) {
  union { float f; unsigned u; } v; v.f = x;
  unsigned u = v.u;
  return (unsigned short)((u + 0x7FFFu + ((u >> 16) & 1u)) >> 16);
}
__device__ __forceinline__ float bf16tof_(unsigned short h) {
  union { float f; unsigned u; } v; v.u = ((unsigned)h) << 16;
  return v.f;
}

// async global->LDS, 16B per lane; lds dst = uniform base + lane*16
__device__ __forceinline__ void gl_lds16(const unsigned short* g, unsigned short* l) {
  __builtin_amdgcn_global_load_lds(
      (const __attribute__((address_space(1))) unsigned int*)g,
      (__attribute__((address_space(3))) unsigned int*)l, 16, 0, 0);
}

// ---------------- input projection: h = feats @ W_in + b_in ----------------
__global__ __launch_bounds__(128) void k_input_proj(
    const float* __restrict__ feats, const float* __restrict__ W_in,
    const float* __restrict__ b_in, float* __restrict__ h)
{
  __shared__ float fs[74];
  int n = blockIdx.x;
  int j = threadIdx.x;
  if (j < 74) fs[j] = feats[n * 74 + j];
  __syncthreads();
  float acc = b_in[j];
#pragma unroll
  for (int k = 0; k < 74; ++k) acc = fmaf(fs[k], W_in[k * 128 + j], acc);
  h[(size_t)n * 128 + j] = acc;
}

// ---------------- per-layer BN scale/shift precompute ----------------
__global__ void k_bnprep(const float* __restrict__ g, const float* __restrict__ b,
                         const float* __restrict__ m, const float* __restrict__ v,
                         int layer, float* __restrict__ bnp)
{
  int j = threadIdx.x;  // 128 threads
  float s = g[layer * 128 + j] * rsqrtf(v[layer * 128 + j] + 1e-5f);
  bnp[j] = s;
  bnp[128 + j] = b[layer * 128 + j] - m[layer * 128 + j] * s;
}

// ---------------- GRU weight prepack (once): Wp[kb][n][32k] bf16 + bcat ----------------
// Wcat[512][256]: n<128:r n<256:z n<384:inn n<512:hn. A = [x | agg], K=256.
__global__ __launch_bounds__(256) void k_wpack(
    const float* __restrict__ w_ih, const float* __restrict__ w_hh,
    const float* __restrict__ b_ih, const float* __restrict__ b_hh,
    unsigned short* __restrict__ Wp, float* __restrict__ bcat)
{
  int idx = blockIdx.x * 256 + threadIdx.x;  // 512*256 threads
  int n = idx >> 8, k = idx & 255;
  float val;
  if (n < 256) {
    val = (k < 128) ? fmaf(1.00001f, w_ih[n * 256 + k], w_hh[n * 128 + k])
                    : w_ih[n * 256 + k];
  } else if (n < 384) {
    val = (k < 128) ? 1.00001f * w_ih[n * 256 + k] : w_ih[n * 256 + k];
  } else {
    int g = n - 128;
    val = (k < 128) ? w_hh[g * 128 + k] : 0.f;
  }
  Wp[(size_t)(k >> 5) * 16384 + n * 32 + (k & 31)] = bf16r_(val);
  if (k == 0) {
    float bc;
    if (n < 256) bc = b_ih[n] + b_hh[n];
    else if (n < 384) bc = b_ih[n];
    else bc = b_hh[n - 128];
    bcat[n] = bc;
  }
}

// ---------------- prep: x = BN(h) -> swizzled bf16 hi/lo planes; + wnode ----------------
// thread t: row = t>>4, chunk c = t&15 (8 channels). Swizzle: chunk stored at c^(row&7).
__global__ __launch_bounds__(256) void k_prep(
    const float* __restrict__ h, const float* __restrict__ bnp,
    const float* __restrict__ w_aw, const float* __restrict__ b_aw,
    unsigned short* __restrict__ xhi, unsigned short* __restrict__ xlo,
    float* __restrict__ wnode)
{
  int t = blockIdx.x * 256 + threadIdx.x;
  int row = t >> 4, c = t & 15;
  const float* hp = h + (size_t)row * 128 + c * 8;
  float4 h0 = *(const float4*)(hp);
  float4 h1 = *(const float4*)(hp + 4);
  float4 s0 = *(const float4*)(bnp + c * 8);
  float4 s1 = *(const float4*)(bnp + c * 8 + 4);
  float4 t0 = *(const float4*)(bnp + 128 + c * 8);
  float4 t1 = *(const float4*)(bnp + 128 + c * 8 + 4);
  float x[8] = { fmaf(h0.x, s0.x, t0.x), fmaf(h0.y, s0.y, t0.y),
                 fmaf(h0.z, s0.z, t0.z), fmaf(h0.w, s0.w, t0.w),
                 fmaf(h1.x, s1.x, t1.x), fmaf(h1.y, s1.y, t1.y),
                 fmaf(h1.z, s1.z, t1.z), fmaf(h1.w, s1.w, t1.w) };
  unsigned hiw[4], low[4];
#pragma unroll
  for (int i = 0; i < 4; ++i) {
    unsigned short ha = bf16r_(x[2 * i]), hb = bf16r_(x[2 * i + 1]);
    unsigned short la = bf16r_(x[2 * i] - bf16tof_(ha));
    unsigned short lb = bf16r_(x[2 * i + 1] - bf16tof_(hb));
    hiw[i] = (unsigned)ha | ((unsigned)hb << 16);
    low[i] = (unsigned)la | ((unsigned)lb << 16);
  }
  size_t dst = (size_t)row * 16 + (c ^ (row & 7));
  ((uint4*)xhi)[dst] = make_uint4(hiw[0], hiw[1], hiw[2], hiw[3]);
  ((uint4*)xlo)[dst] = make_uint4(low[0], low[1], low[2], low[3]);
  // wnode = sigmoid(h . w_aw + b): reduce across 16 threads of this row
  const float4 wa0 = *(const float4*)(w_aw + c * 8);
  const float4 wa1 = *(const float4*)(w_aw + c * 8 + 4);
  float p = h0.x * wa0.x + h0.y * wa0.y + h0.z * wa0.z + h0.w * wa0.w +
            h1.x * wa1.x + h1.y * wa1.y + h1.z * wa1.z + h1.w * wa1.w;
#pragma unroll
  for (int o = 8; o > 0; o >>= 1) p += __shfl_xor(p, o);
  if (c == 0) wnode[row] = sig_(p + b_aw[0]);
}

// ---------------- CSR build: histogram -> scan -> fill ----------------
__global__ __launch_bounds__(256) void k_hist(const int* __restrict__ dst, int* __restrict__ deg)
{
  int t = blockIdx.x * 256 + threadIdx.x;
  if (t < NE) atomicAdd(&deg[dst[t]], 1);
}

__global__ __launch_bounds__(1024) void k_scan(const int* __restrict__ deg, int* __restrict__ rowptr)
{
  __shared__ int part[1024];
  const int t = threadIdx.x;
  const int CH = 49;
  int beg = t * CH, end = min(beg + CH, NN);
  int s = 0;
  for (int i = beg; i < end; ++i) s += deg[i];
  part[t] = s;
  __syncthreads();
  for (int o = 1; o < 1024; o <<= 1) {
    int v = (t >= o) ? part[t - o] : 0;
    __syncthreads();
    part[t] += v;
    __syncthreads();
  }
  int base = part[t] - s;
  for (int i = beg; i < end; ++i) { rowptr[i] = base; base += deg[i]; }
  if (t == 0) rowptr[NN] = NE;
}

__global__ __launch_bounds__(256) void k_fill(
    const int* __restrict__ src, const int* __restrict__ dst,
    int* __restrict__ pos, int* __restrict__ col)
{
  int t = blockIdx.x * 256 + threadIdx.x;
  if (t >= NE) return;
  int p = atomicAdd(&pos[dst[t]], 1);
  col[p] = src[t];
}

// ---------------- CSR gather from x_hi plane -> split-bf16 agg planes ----------------
// one wave per node; lane handles 2 channels; 4-deep ILP unroll
__global__ __launch_bounds__(256) void k_gather(
    const unsigned short* __restrict__ xhi, const int* __restrict__ rowptr,
    const int* __restrict__ col,
    unsigned short* __restrict__ agghi, unsigned short* __restrict__ agglo)
{
  int n = blockIdx.x * 4 + (threadIdx.x >> 6);
  int lane = threadIdx.x & 63;
  int c = lane >> 2, q = lane & 3;
  int lo = rowptr[n], hi = rowptr[n + 1];
  const unsigned* xp = (const unsigned*)xhi;
  float a0 = 0.f, a1 = 0.f, a2 = 0.f, a3 = 0.f;
  float b0 = 0.f, b1 = 0.f, b2 = 0.f, b3 = 0.f;
  int e = lo;
  for (; e + 3 < hi; e += 4) {
    int r0 = col[e], r1 = col[e + 1], r2 = col[e + 2], r3 = col[e + 3];
    unsigned u0 = xp[(size_t)r0 * 64 + ((c ^ (r0 & 7)) << 2) + q];
    unsigned u1 = xp[(size_t)r1 * 64 + ((c ^ (r1 & 7)) << 2) + q];
    unsigned u2 = xp[(size_t)r2 * 64 + ((c ^ (r2 & 7)) << 2) + q];
    unsigned u3 = xp[(size_t)r3 * 64 + ((c ^ (r3 & 7)) << 2) + q];
    a0 += bf16tof_((unsigned short)(u0 & 0xFFFF)); b0 += bf16tof_((unsigned short)(u0 >> 16));
    a1 += bf16tof_((unsigned short)(u1 & 0xFFFF)); b1 += bf16tof_((unsigned short)(u1 >> 16));
    a2 += bf16tof_((unsigned short)(u2 & 0xFFFF)); b2 += bf16tof_((unsigned short)(u2 >> 16));
    a3 += bf16tof_((unsigned short)(u3 & 0xFFFF)); b3 += bf16tof_((unsigned short)(u3 >> 16));
  }
  for (; e < hi; ++e) {
    int r0 = col[e];
    unsigned u0 = xp[(size_t)r0 * 64 + ((c ^ (r0 & 7)) << 2) + q];
    a0 += bf16tof_((unsigned short)(u0 & 0xFFFF));
    b0 += bf16tof_((unsigned short)(u0 >> 16));
  }
  float s0 = (a0 + a1) + (a2 + a3), s1 = (b0 + b1) + (b2 + b3);
  unsigned short h0 = bf16r_(s0), h1 = bf16r_(s1);
  unsigned short l0 = bf16r_(s0 - bf16tof_(h0)), l1 = bf16r_(s1 - bf16tof_(h1));
  size_t w = (size_t)n * 64 + ((c ^ (n & 7)) << 2) + q;
  ((unsigned*)agghi)[w] = (unsigned)h0 | ((unsigned)h1 << 16);
  ((unsigned*)agglo)[w] = (unsigned)l0 | ((unsigned)l1 << 16);
}

__device__ __forceinline__ int lbound_(const int* __restrict__ a, int n, int key)
{
  int lo = 0, hi = n;
  while (lo < hi) { int mid = (lo + hi) >> 1; if (a[mid] < key) lo = mid + 1; else hi = mid; }
  return lo;
}

// ---------------- graph readout: reps[l][g] = [sum w*h | max h] ----------------
__global__ __launch_bounds__(128) void k_readout(
    const float* __restrict__ h, const float* __restrict__ wnode,
    const int* __restrict__ n2g, float* __restrict__ reps, int layer)
{
  int g = blockIdx.x;
  int j = threadIdx.x;
  int lo = lbound_(n2g, NN, g);
  int hi = lbound_(n2g, NN, g + 1);
  float ws0 = 0.f, hm0 = -INFINITY, ws1 = 0.f, hm1 = -INFINITY;
  int n = lo;
  for (; n + 1 < hi; n += 2) {
    float hv0 = h[(size_t)n * 128 + j];
    float hv1 = h[(size_t)(n + 1) * 128 + j];
    ws0 = fmaf(wnode[n], hv0, ws0);     hm0 = fmaxf(hm0, hv0);
    ws1 = fmaf(wnode[n + 1], hv1, ws1); hm1 = fmaxf(hm1, hv1);
  }
  if (n < hi) {
    float hv0 = h[(size_t)n * 128 + j];
    ws0 = fmaf(wnode[n], hv0, ws0); hm0 = fmaxf(hm0, hv0);
  }
  float ws = ws0 + ws1, hm = fmaxf(hm0, hm1);
  if (hi == lo) hm = 0.f;
  float* r = reps + ((size_t)layer * NG + g) * 256;
  r[j] = ws;
  r[128 + j] = hm;
}

// ---------------- persistent MFMA GRU: W in registers, A double-buffered in LDS ----------------
// grid 256 (1 block/CU), 512 thr = 8 waves (2/SIMD); wave wv owns 16 channels x 4 gates.
// Epilogue reconstructs x (and hence old h) from the LDS planes -> no global h loads.
__global__ __launch_bounds__(512, 2) void k_gru_mfma(
    float* __restrict__ h,
    const unsigned short* __restrict__ xhi, const unsigned short* __restrict__ xlo,
    const unsigned short* __restrict__ agghi, const unsigned short* __restrict__ agglo,
    const unsigned short* __restrict__ Wp, const float* __restrict__ bcat,
    const float* __restrict__ bnp)
{
  __shared__ alignas(16) unsigned short A[2][32768];  // 2 x 64KB: [xhi|xlo|agghi|agglo] tiles
  const int tid = threadIdx.x;
  const int lane = tid & 63;
  const int wv = tid >> 6;      // 0..7
  const int mfr = lane & 15;    // A-row / D-col selector
  const int kq = lane >> 4;     // k-quad / D-row-quad

  // ---- this wave's W slice in registers: cols n = g*128 + wv*16 + mfr ----
  // hn gate (g=3) has zero weights for k>=128 (kb>=4) -> skip those.
  bfrag8 wreg[8][4];
#pragma unroll
  for (int kb = 0; kb < 8; ++kb) {
    int ng = (kb < 4) ? 4 : 3;
#pragma unroll
    for (int g = 0; g < 4; ++g) {
      if (g < ng) {
        int n = g * 128 + wv * 16 + mfr;
        wreg[kb][g] = *(const bfrag8*)(Wp + (size_t)kb * 16384 + n * 32 + kq * 8);
      }
    }
  }

  // ---- stage: 64KB tile via global_load_lds (8 waves x 2 rounds x 4 planes) ----
  auto stage = [&](int buf, int tile) {
    size_t goff = (size_t)tile * 64 * 128;  // shorts
    const unsigned short* srcs[4] = { xhi + goff, xlo + goff, agghi + goff, agglo + goff };
#pragma unroll
    for (int p = 0; p < 4; ++p) {
#pragma unroll
      for (int it = 0; it < 2; ++it) {
        int off = it * 4096 + wv * 512;  // shorts
        gl_lds16(srcs[p] + off + lane * 8, &A[buf][p * 8192 + off]);
      }
    }
  };

  int tile = blockIdx.x;
  stage(0, tile);
  __syncthreads();  // drains vmcnt + barrier
  int cur = 0;

  while (true) {
    int nxt = tile + GRUGRID;
    if (nxt < NT) stage(cur ^ 1, nxt);  // async prefetch overlaps compute

    f32x4 acc[4][4];  // [m-subtile][gate]
#pragma unroll
    for (int m = 0; m < 4; ++m)
#pragma unroll
      for (int g = 0; g < 4; ++g) acc[m][g] = (f32x4){0.f, 0.f, 0.f, 0.f};

    const char* Ab = (const char*)&A[cur][0];
#pragma unroll
    for (int kb = 0; kb < 8; ++kb) {
      int kp = kb & 3;
      int hoff = (kb < 4) ? 0 : 32768;  // x planes vs agg planes
      int ng = (kb < 4) ? 4 : 3;
      bfrag8 ah[4], al[4];
#pragma unroll
      for (int m = 0; m < 4; ++m) {
        int row = m * 16 + mfr;
        int cs = (((kp * 4 + kq) ^ (row & 7)) << 4);
        ah[m] = *(const bfrag8*)(Ab + hoff + row * 256 + cs);
        al[m] = *(const bfrag8*)(Ab + hoff + 16384 + row * 256 + cs);
      }
#pragma unroll
      for (int m = 0; m < 4; ++m)
#pragma unroll
        for (int g = 0; g < 4; ++g) {
          if (g < ng) {
            acc[m][g] = __builtin_amdgcn_mfma_f32_16x16x32_bf16(ah[m], wreg[kb][g], acc[m][g], 0, 0, 0);
            acc[m][g] = __builtin_amdgcn_mfma_f32_16x16x32_bf16(al[m], wreg[kb][g], acc[m][g], 0, 0, 0);
          }
        }
    }

    // ---- epilogue: node = m0 + m*16 + kq*4 + reg, channel j = wv*16 + mfr ----
    {
      int m0 = tile * 64;
      int j = wv * 16 + mfr;
      float sc = bnp[j], sh = bnp[128 + j];
      float isc = 1.f / sc;
      float br = bcat[j], bz = bcat[128 + j], bi = bcat[256 + j], bh = bcat[384 + j];
      int chunk = j >> 3;
      int jb = (j & 7) * 2;
#pragma unroll
      for (int m = 0; m < 4; ++m) {
#pragma unroll
        for (int reg = 0; reg < 4; ++reg) {
          int rr = m * 16 + kq * 4 + reg;
          int node = m0 + rr;
          int byte = rr * 256 + ((chunk ^ (rr & 7)) << 4) + jb;
          unsigned short xh = *(const unsigned short*)(Ab + byte);
          unsigned short xl = *(const unsigned short*)(Ab + 16384 + byte);
          float x = bf16tof_(xh) + bf16tof_(xl);
          float hv = (x - sh) * isc;  // old h (sc well-conditioned: var in [0.5,1.5], gamma=1)
          float r = sig_(acc[m][0][reg] + br);
          float z = sig_(acc[m][1][reg] + bz);
          float ng2 = tanhf(fmaf(r, acc[m][3][reg] + bh, acc[m][2][reg] + bi));
          float o = (1.f - z) * ng2 + z * x;
          float hc = (o > 0.f) ? o : expm1f(o);
          if (node < NN) h[(size_t)node * 128 + j] = hv + hc;
        }
      }
    }

    if (nxt >= NT) break;
    __syncthreads();  // drain prefetch (vmcnt 0) + sync before swapping buffers
    cur ^= 1;
    tile = nxt;
  }
}

// ---------------- fused LSTM step (fp32) ----------------
__global__ __launch_bounds__(256) void k_lstm(
    const float* __restrict__ x, const float* __restrict__ h_in, const float* __restrict__ c_in,
    const float* __restrict__ w_ih, const float* __restrict__ w_hh,
    const float* __restrict__ b_ih, const float* __restrict__ b_hh,
    float* __restrict__ h_out, float* __restrict__ c_out)
{
  __shared__ float V[16][384];
  __shared__ float WT[16][516];
  const int tid = threadIdx.x;
  const int tx = tid & 63;
  const int ty = tid >> 6;
  const int n0 = blockIdx.x * 16;

  for (int idx = tid; idx < 16 * 256; idx += 256) {
    int nn = idx >> 8, j = idx & 255;
    V[nn][j] = x[(n0 + nn) * 256 + j];
  }
  for (int idx = tid; idx < 16 * 128; idx += 256) {
    int nn = idx >> 7, j = idx & 127;
    V[nn][256 + j] = h_in[(n0 + nn) * 128 + j];
  }

  float acc[8][4];
#pragma unroll
  for (int i = 0; i < 8; ++i) {
    float b = b_ih[i * 64 + tx] + b_hh[i * 64 + tx];
    acc[i][0] = acc[i][1] = acc[i][2] = acc[i][3] = b;
  }

  for (int t = 0; t < 16; ++t) {
    __syncthreads();
    {
      int c = tid >> 2, q = tid & 3;
#pragma unroll
      for (int p = 0; p < 8; ++p) {
        int cc = c + p * 64;
        const float4 w = *(const float4*)(w_ih + cc * 256 + t * 16 + q * 4);
        WT[q * 4 + 0][cc] = w.x; WT[q * 4 + 1][cc] = w.y;
        WT[q * 4 + 2][cc] = w.z; WT[q * 4 + 3][cc] = w.w;
      }
    }
    __syncthreads();
#pragma unroll
    for (int kk = 0; kk < 16; ++kk) {
      int k = t * 16 + kk;
      float a0 = V[ty * 4 + 0][k], a1 = V[ty * 4 + 1][k];
      float a2 = V[ty * 4 + 2][k], a3 = V[ty * 4 + 3][k];
#pragma unroll
      for (int i = 0; i < 8; ++i) {
        float w = WT[kk][i * 64 + tx];
        acc[i][0] = fmaf(w, a0, acc[i][0]);
        acc[i][1] = fmaf(w, a1, acc[i][1]);
        acc[i][2] = fmaf(w, a2, acc[i][2]);
        acc[i][3] = fmaf(w, a3, acc[i][3]);
      }
    }
  }

  for (int t = 0; t < 8; ++t) {
    __syncthreads();
    {
      int c = tid >> 2, q = tid & 3;
#pragma unroll
      for (int p = 0; p < 8; ++p) {
        int cc = c + p * 64;
        const float4 w = *(const float4*)(w_hh + cc * 128 + t * 16 + q * 4);
        WT[q * 4 + 0][cc] = w.x; WT[q * 4 + 1][cc] = w.y;
        WT[q * 4 + 2][cc] = w.z; WT[q * 4 + 3][cc] = w.w;
      }
    }
    __syncthreads();
#pragma unroll
    for (int kk = 0; kk < 16; ++kk) {
      int k = t * 16 + kk;
      float a0 = V[ty * 4 + 0][256 + k], a1 = V[ty * 4 + 1][256 + k];
      float a2 = V[ty * 4 + 2][256 + k], a3 = V[ty * 4 + 3][256 + k];
#pragma unroll
      for (int i = 0; i < 8; ++i) {
        float w = WT[kk][i * 64 + tx];
        acc[i][0] = fmaf(w, a0, acc[i][0]);
        acc[i][1] = fmaf(w, a1, acc[i][1]);
        acc[i][2] = fmaf(w, a2, acc[i][2]);
        acc[i][3] = fmaf(w, a3, acc[i][3]);
      }
    }
  }

#pragma unroll
  for (int nd = 0; nd < 4; ++nd) {
    int n = n0 + ty * 4 + nd;
#pragma unroll
    for (int half = 0; half < 2; ++half) {
      int j = half * 64 + tx;
      float ig = sig_(acc[0 + half][nd]);
      float fg = sig_(acc[2 + half][nd]);
      float gg = tanhf(acc[4 + half][nd]);
      float og = sig_(acc[6 + half][nd]);
      float cn = fmaf(fg, c_in[n * 128 + j], ig * gg);
      c_out[n * 128 + j] = cn;
      h_out[n * 128 + j] = og * tanhf(cn);
    }
  }
}

// ---------------- final projection ----------------
__global__ __launch_bounds__(256) void k_final(
    const float* __restrict__ yf, const float* __restrict__ yb,
    const float* __restrict__ W_out, const float* __restrict__ b_out,
    float* __restrict__ out)
{
  int tid = threadIdx.x;
  int g = blockIdx.x * 4 + (tid >> 6);
  int lane = tid & 63;
  float a0 = 0.f, a1 = 0.f;
  for (int k = lane; k < 128; k += 64) {
    float v = yf[g * 128 + k];
    a0 = fmaf(v, W_out[k * 2 + 0], a0);
    a1 = fmaf(v, W_out[k * 2 + 1], a1);
    float u = yb[g * 128 + k];
    a0 = fmaf(u, W_out[(128 + k) * 2 + 0], a0);
    a1 = fmaf(u, W_out[(128 + k) * 2 + 1], a1);
  }
#pragma unroll
  for (int o = 32; o > 0; o >>= 1) { a0 += __shfl_xor(a0, o); a1 += __shfl_xor(a1, o); }
  if (lane == 0) {
    out[g * 2 + 0] = a0 + b_out[0];
    out[g * 2 + 1] = a1 + b_out[1];
  }
}

extern "C" void kernel_launch(void* const* d_in, const int* in_sizes, int n_in,
                              void* d_out, int out_size, void* d_ws, size_t ws_size,
                              hipStream_t stream)
{
  (void)in_sizes; (void)n_in; (void)out_size; (void)ws_size;
  const float* feats   = (const float*)d_in[0];
  const int*   src     = (const int*)d_in[1];
  const int*   dst     = (const int*)d_in[2];
  const int*   n2g     = (const int*)d_in[3];
  const float* W_in    = (const float*)d_in[4];
  const float* b_in    = (const float*)d_in[5];
  const float* bng     = (const float*)d_in[6];
  const float* bnb     = (const float*)d_in[7];
  const float* bnm     = (const float*)d_in[8];
  const float* bnv     = (const float*)d_in[9];
  const float* gw_ih   = (const float*)d_in[10];
  const float* gw_hh   = (const float*)d_in[11];
  const float* gb_ih   = (const float*)d_in[12];
  const float* gb_hh   = (const float*)d_in[13];
  const float* w_aw    = (const float*)d_in[14];
  const float* b_aw    = (const float*)d_in[15];
  const float* lwih_f  = (const float*)d_in[16];
  const float* lwhh_f  = (const float*)d_in[17];
  const float* lbih_f  = (const float*)d_in[18];
  const float* lbhh_f  = (const float*)d_in[19];
  const float* lwih_b  = (const float*)d_in[20];
  const float* lwhh_b  = (const float*)d_in[21];
  const float* lbih_b  = (const float*)d_in[22];
  const float* lbhh_b  = (const float*)d_in[23];
  const float* W_out   = (const float*)d_in[24];
  const float* b_out   = (const float*)d_in[25];
  float* out = (float*)d_out;

  float* ws = (float*)d_ws;
  size_t off = 0;
  auto alloc = [&](size_t n) { float* p = ws + off; off += (n + 63) & ~(size_t)63; return p; };
  float* h      = alloc((size_t)NP * 128);
  unsigned short* xhi   = (unsigned short*)alloc((size_t)NP * 64);
  unsigned short* xlo   = (unsigned short*)alloc((size_t)NP * 64);
  unsigned short* agghi = (unsigned short*)alloc((size_t)NP * 64);
  unsigned short* agglo = (unsigned short*)alloc((size_t)NP * 64);
  unsigned short* Wp    = (unsigned short*)alloc(65536);
  float* bcat   = alloc(512);
  float* wnode  = alloc(NN);
  float* bnp    = alloc(256);
  float* reps   = alloc((size_t)NL * NG * 256);
  float* zz     = alloc((size_t)NG * 128);   // zeros for h0 and c0
  float* ha     = alloc((size_t)NG * 128);
  float* ca     = alloc((size_t)NG * 128);
  float* hb     = alloc((size_t)NG * 128);
  float* cb     = alloc((size_t)NG * 128);
  float* yf     = alloc((size_t)NG * 128);
  float* cf     = alloc((size_t)NG * 128);
  int* deg    = (int*)alloc(NN);
  int* rowptr = (int*)alloc(NN + 1);
  int* pos    = (int*)alloc(NN);
  int* colidx = (int*)alloc(NE);

  // ---- one-time: CSR build + GRU weight prepack ----
  hipMemsetAsync(deg, 0, (size_t)NN * sizeof(int), stream);
  k_hist<<<(NE + 255) / 256, 256, 0, stream>>>(dst, deg);
  k_scan<<<1, 1024, 0, stream>>>(deg, rowptr);
  hipMemcpyAsync(pos, rowptr, (size_t)NN * sizeof(int), hipMemcpyDeviceToDevice, stream);
  k_fill<<<(NE + 255) / 256, 256, 0, stream>>>(src, dst, pos, colidx);
  k_wpack<<<512, 256, 0, stream>>>(gw_ih, gw_hh, gb_ih, gb_hh, Wp, bcat);

  k_input_proj<<<NN, 128, 0, stream>>>(feats, W_in, b_in, h);

  for (int l = 0; l < NL; ++l) {
    k_bnprep<<<1, 128, 0, stream>>>(bng, bnb, bnm, bnv, l, bnp);
    k_prep<<<3125, 256, 0, stream>>>(h, bnp, w_aw, b_aw, xhi, xlo, wnode);
    k_gather<<<NN / 4, 256, 0, stream>>>(xhi, rowptr, colidx, agghi, agglo);
    k_readout<<<NG, 128, 0, stream>>>(h, wnode, n2g, reps, l);
    k_gru_mfma<<<GRUGRID, 512, 0, stream>>>(h, xhi, xlo, agghi, agglo, Wp, bcat, bnp);
  }

  hipMemsetAsync(zz, 0, (size_t)NG * 128 * sizeof(float), stream);

  // forward: only step 0 needed for y_f[0]
  k_lstm<<<NG / 16, 256, 0, stream>>>(reps, zz, zz, lwih_f, lwhh_f, lbih_f, lbhh_f, yf, cf);

  // backward: 5 steps over rep[4..0]
  k_lstm<<<NG / 16, 256, 0, stream>>>(reps + (size_t)4 * NG * 256, zz, zz, lwih_b, lwhh_b, lbih_b, lbhh_b, ha, ca);
  k_lstm<<<NG / 16, 256, 0, stream>>>(reps + (size_t)3 * NG * 256, ha, ca, lwih_b, lwhh_b, lbih_b, lbhh_b, hb, cb);
  k_lstm<<<NG / 16, 256, 0, stream>>>(reps + (size_t)2 * NG * 256, hb, cb, lwih_b, lwhh_b, lbih_b, lbhh_b, ha, ca);
  k_lstm<<<NG / 16, 256, 0, stream>>>(reps + (size_t)1 * NG * 256, ha, ca, lwih_b, lwhh_b, lbih_b, lbhh_b, hb, cb);
  k_lstm<<<NG / 16, 256, 0, stream>>>(reps + (size_t)0 * NG * 256, hb, cb, lwih_b, lwhh_b, lbih_b, lbhh_b, ha, ca);

  k_final<<<NG / 4, 256, 0, stream>>>(yf, ha, W_out, b_out, out);
}

// Round 6
// 733.294 us; speedup vs baseline: 10.5802x; 1.5212x over previous
//
#include <hip/hip_runtime.h>
#include <math.h>

#define NN 50000
#define NP 50048   // padded rows (multiple of 64)
#define NE 600000
#define NG 1024
#define NL 5
#define NT (NP / 64)     // 782 M-tiles
#define GRUGRID 256      // persistent blocks (1 per CU)
// Hd = 128, Fin = 74, C = 2

typedef __attribute__((ext_vector_type(8))) short bfrag8;
typedef __attribute__((ext_vector_type(4))) float f32x4;

__device__ __forceinline__ float sig_(float x) { return 1.f / (1.f + expf(-x)); }

__device__ __forceinline__ unsigned short bf16r_(float x) {
  union { float f; unsigned u; } v; v.f = x;
  unsigned u = v.u;
  return (unsigned short)((u + 0x7FFFu + ((u >> 16) & 1u)) >> 16);
}
__device__ __forceinline__ float bf16tof_(unsigned short h) {
  union { float f; unsigned u; } v; v.u = ((unsigned)h) << 16;
  return v.f;
}

// async global->LDS, 16B per lane; lds dst = uniform base + lane*16
__device__ __forceinline__ void gl_lds16(const unsigned short* g, unsigned short* l) {
  __builtin_amdgcn_global_load_lds(
      (const __attribute__((address_space(1))) unsigned int*)g,
      (__attribute__((address_space(3))) unsigned int*)l, 16, 0, 0);
}

// ---------------- input projection: h = feats @ W_in + b_in ----------------
__global__ __launch_bounds__(128) void k_input_proj(
    const float* __restrict__ feats, const float* __restrict__ W_in,
    const float* __restrict__ b_in, float* __restrict__ h)
{
  __shared__ float fs[74];
  int n = blockIdx.x;
  int j = threadIdx.x;
  if (j < 74) fs[j] = feats[n * 74 + j];
  __syncthreads();
  float acc = b_in[j];
#pragma unroll
  for (int k = 0; k < 74; ++k) acc = fmaf(fs[k], W_in[k * 128 + j], acc);
  h[(size_t)n * 128 + j] = acc;
}

// ---------------- per-layer BN scale/shift precompute ----------------
__global__ void k_bnprep(const float* __restrict__ g, const float* __restrict__ b,
                         const float* __restrict__ m, const float* __restrict__ v,
                         int layer, float* __restrict__ bnp)
{
  int j = threadIdx.x;  // 128 threads
  float s = g[layer * 128 + j] * rsqrtf(v[layer * 128 + j] + 1e-5f);
  bnp[j] = s;
  bnp[128 + j] = b[layer * 128 + j] - m[layer * 128 + j] * s;
}

// ---------------- GRU weight prepack (once): Wp[kb][n][32k] bf16 + bcat ----------------
__global__ __launch_bounds__(256) void k_wpack(
    const float* __restrict__ w_ih, const float* __restrict__ w_hh,
    const float* __restrict__ b_ih, const float* __restrict__ b_hh,
    unsigned short* __restrict__ Wp, float* __restrict__ bcat)
{
  int idx = blockIdx.x * 256 + threadIdx.x;  // 512*256 threads
  int n = idx >> 8, k = idx & 255;
  float val;
  if (n < 256) {
    val = (k < 128) ? fmaf(1.00001f, w_ih[n * 256 + k], w_hh[n * 128 + k])
                    : w_ih[n * 256 + k];
  } else if (n < 384) {
    val = (k < 128) ? 1.00001f * w_ih[n * 256 + k] : w_ih[n * 256 + k];
  } else {
    int g = n - 128;
    val = (k < 128) ? w_hh[g * 128 + k] : 0.f;
  }
  Wp[(size_t)(k >> 5) * 16384 + n * 32 + (k & 31)] = bf16r_(val);
  if (k == 0) {
    float bc;
    if (n < 256) bc = b_ih[n] + b_hh[n];
    else if (n < 384) bc = b_ih[n];
    else bc = b_hh[n - 128];
    bcat[n] = bc;
  }
}

// ---------------- LSTM weight prepack (once): ih fwd/bwd + hh bwd + biases ----------------
__global__ __launch_bounds__(256) void k_wpack_lstm(
    const float* __restrict__ lwih_f, const float* __restrict__ lwih_b,
    const float* __restrict__ lwhh_b,
    const float* __restrict__ lbih_f, const float* __restrict__ lbhh_f,
    const float* __restrict__ lbih_b, const float* __restrict__ lbhh_b,
    unsigned short* __restrict__ Wihf, unsigned short* __restrict__ Wihb,
    unsigned short* __restrict__ Whhb, float* __restrict__ bcf, float* __restrict__ bcb)
{
  int idx = blockIdx.x * 256 + threadIdx.x;
  if (idx < 131072) {
    int n = idx >> 8, k = idx & 255;
    Wihf[(size_t)(k >> 5) * 16384 + n * 32 + (k & 31)] = bf16r_(lwih_f[n * 256 + k]);
  } else if (idx < 262144) {
    int i2 = idx - 131072; int n = i2 >> 8, k = i2 & 255;
    Wihb[(size_t)(k >> 5) * 16384 + n * 32 + (k & 31)] = bf16r_(lwih_b[n * 256 + k]);
  } else if (idx < 327680) {
    int i2 = idx - 262144; int n = i2 >> 7, k = i2 & 127;
    Whhb[(size_t)(k >> 5) * 16384 + n * 32 + (k & 31)] = bf16r_(lwhh_b[n * 128 + k]);
  }
  if (idx < 512) {
    bcf[idx] = lbih_f[idx] + lbhh_f[idx];
    bcb[idx] = lbih_b[idx] + lbhh_b[idx];
  }
}

// ---------------- prep: x = BN(h) -> swizzled bf16 hi/lo planes; + wnode ----------------
__global__ __launch_bounds__(256) void k_prep(
    const float* __restrict__ h, const float* __restrict__ bnp,
    const float* __restrict__ w_aw, const float* __restrict__ b_aw,
    unsigned short* __restrict__ xhi, unsigned short* __restrict__ xlo,
    float* __restrict__ wnode)
{
  int t = blockIdx.x * 256 + threadIdx.x;
  int row = t >> 4, c = t & 15;
  const float* hp = h + (size_t)row * 128 + c * 8;
  float4 h0 = *(const float4*)(hp);
  float4 h1 = *(const float4*)(hp + 4);
  float4 s0 = *(const float4*)(bnp + c * 8);
  float4 s1 = *(const float4*)(bnp + c * 8 + 4);
  float4 t0 = *(const float4*)(bnp + 128 + c * 8);
  float4 t1 = *(const float4*)(bnp + 128 + c * 8 + 4);
  float x[8] = { fmaf(h0.x, s0.x, t0.x), fmaf(h0.y, s0.y, t0.y),
                 fmaf(h0.z, s0.z, t0.z), fmaf(h0.w, s0.w, t0.w),
                 fmaf(h1.x, s1.x, t1.x), fmaf(h1.y, s1.y, t1.y),
                 fmaf(h1.z, s1.z, t1.z), fmaf(h1.w, s1.w, t1.w) };
  unsigned hiw[4], low[4];
#pragma unroll
  for (int i = 0; i < 4; ++i) {
    unsigned short ha = bf16r_(x[2 * i]), hb = bf16r_(x[2 * i + 1]);
    unsigned short la = bf16r_(x[2 * i] - bf16tof_(ha));
    unsigned short lb = bf16r_(x[2 * i + 1] - bf16tof_(hb));
    hiw[i] = (unsigned)ha | ((unsigned)hb << 16);
    low[i] = (unsigned)la | ((unsigned)lb << 16);
  }
  size_t dst = (size_t)row * 16 + (c ^ (row & 7));
  ((uint4*)xhi)[dst] = make_uint4(hiw[0], hiw[1], hiw[2], hiw[3]);
  ((uint4*)xlo)[dst] = make_uint4(low[0], low[1], low[2], low[3]);
  const float4 wa0 = *(const float4*)(w_aw + c * 8);
  const float4 wa1 = *(const float4*)(w_aw + c * 8 + 4);
  float p = h0.x * wa0.x + h0.y * wa0.y + h0.z * wa0.z + h0.w * wa0.w +
            h1.x * wa1.x + h1.y * wa1.y + h1.z * wa1.z + h1.w * wa1.w;
#pragma unroll
  for (int o = 8; o > 0; o >>= 1) p += __shfl_xor(p, o);
  if (c == 0) wnode[row] = sig_(p + b_aw[0]);
}

// ---------------- CSR build: histogram -> hierarchical scan -> fill ----------------
__global__ __launch_bounds__(256) void k_hist(const int* __restrict__ dst, int* __restrict__ deg)
{
  int t = blockIdx.x * 256 + threadIdx.x;
  if (t < NE) atomicAdd(&deg[dst[t]], 1);
}

// phase 1: per-block sums (196 blocks x 256)
__global__ __launch_bounds__(256) void k_scan1(const int* __restrict__ deg, int* __restrict__ bsum)
{
  __shared__ int red[4];
  int i = blockIdx.x * 256 + threadIdx.x;
  int d = (i < NN) ? deg[i] : 0;
  int s = d;
#pragma unroll
  for (int o = 32; o > 0; o >>= 1) s += __shfl_xor(s, o);
  if ((threadIdx.x & 63) == 0) red[threadIdx.x >> 6] = s;
  __syncthreads();
  if (threadIdx.x == 0) bsum[blockIdx.x] = red[0] + red[1] + red[2] + red[3];
}

// phase 2: scan 196 partials (1 block x 256)
__global__ __launch_bounds__(256) void k_scan2(const int* __restrict__ bsum, int* __restrict__ boff,
                                               int* __restrict__ rowptr)
{
  __shared__ int part[256];
  int t = threadIdx.x;
  int v = (t < 196) ? bsum[t] : 0;
  part[t] = v;
  __syncthreads();
  for (int o = 1; o < 256; o <<= 1) {
    int u = (t >= o) ? part[t - o] : 0;
    __syncthreads();
    part[t] += u;
    __syncthreads();
  }
  if (t < 196) boff[t] = part[t] - v;  // exclusive
  if (t == 0) rowptr[NN] = NE;
}

// phase 3: block-local scan + add-back
__global__ __launch_bounds__(256) void k_scan3(const int* __restrict__ deg, const int* __restrict__ boff,
                                               int* __restrict__ rowptr)
{
  __shared__ int part[256];
  int t = threadIdx.x;
  int i = blockIdx.x * 256 + t;
  int d = (i < NN) ? deg[i] : 0;
  part[t] = d;
  __syncthreads();
  for (int o = 1; o < 256; o <<= 1) {
    int u = (t >= o) ? part[t - o] : 0;
    __syncthreads();
    part[t] += u;
    __syncthreads();
  }
  if (i < NN) rowptr[i] = boff[blockIdx.x] + part[t] - d;
}

__global__ __launch_bounds__(256) void k_fill(
    const int* __restrict__ src, const int* __restrict__ dst,
    int* __restrict__ pos, int* __restrict__ col)
{
  int t = blockIdx.x * 256 + threadIdx.x;
  if (t >= NE) return;
  int p = atomicAdd(&pos[dst[t]], 1);
  col[p] = src[t];
}

// ---------------- CSR gather from x_hi plane -> split-bf16 agg planes ----------------
__global__ __launch_bounds__(256) void k_gather(
    const unsigned short* __restrict__ xhi, const int* __restrict__ rowptr,
    const int* __restrict__ col,
    unsigned short* __restrict__ agghi, unsigned short* __restrict__ agglo)
{
  int n = blockIdx.x * 4 + (threadIdx.x >> 6);
  int lane = threadIdx.x & 63;
  int c = lane >> 2, q = lane & 3;
  int lo = rowptr[n], hi = rowptr[n + 1];
  const unsigned* xp = (const unsigned*)xhi;
  float a0 = 0.f, a1 = 0.f, a2 = 0.f, a3 = 0.f;
  float b0 = 0.f, b1 = 0.f, b2 = 0.f, b3 = 0.f;
  int e = lo;
  for (; e + 3 < hi; e += 4) {
    int r0 = col[e], r1 = col[e + 1], r2 = col[e + 2], r3 = col[e + 3];
    unsigned u0 = xp[(size_t)r0 * 64 + ((c ^ (r0 & 7)) << 2) + q];
    unsigned u1 = xp[(size_t)r1 * 64 + ((c ^ (r1 & 7)) << 2) + q];
    unsigned u2 = xp[(size_t)r2 * 64 + ((c ^ (r2 & 7)) << 2) + q];
    unsigned u3 = xp[(size_t)r3 * 64 + ((c ^ (r3 & 7)) << 2) + q];
    a0 += bf16tof_((unsigned short)(u0 & 0xFFFF)); b0 += bf16tof_((unsigned short)(u0 >> 16));
    a1 += bf16tof_((unsigned short)(u1 & 0xFFFF)); b1 += bf16tof_((unsigned short)(u1 >> 16));
    a2 += bf16tof_((unsigned short)(u2 & 0xFFFF)); b2 += bf16tof_((unsigned short)(u2 >> 16));
    a3 += bf16tof_((unsigned short)(u3 & 0xFFFF)); b3 += bf16tof_((unsigned short)(u3 >> 16));
  }
  for (; e < hi; ++e) {
    int r0 = col[e];
    unsigned u0 = xp[(size_t)r0 * 64 + ((c ^ (r0 & 7)) << 2) + q];
    a0 += bf16tof_((unsigned short)(u0 & 0xFFFF));
    b0 += bf16tof_((unsigned short)(u0 >> 16));
  }
  float s0 = (a0 + a1) + (a2 + a3), s1 = (b0 + b1) + (b2 + b3);
  unsigned short h0 = bf16r_(s0), h1 = bf16r_(s1);
  unsigned short l0 = bf16r_(s0 - bf16tof_(h0)), l1 = bf16r_(s1 - bf16tof_(h1));
  size_t w = (size_t)n * 64 + ((c ^ (n & 7)) << 2) + q;
  ((unsigned*)agghi)[w] = (unsigned)h0 | ((unsigned)h1 << 16);
  ((unsigned*)agglo)[w] = (unsigned)l0 | ((unsigned)l1 << 16);
}

__device__ __forceinline__ int lbound_(const int* __restrict__ a, int n, int key)
{
  int lo = 0, hi = n;
  while (lo < hi) { int mid = (lo + hi) >> 1; if (a[mid] < key) lo = mid + 1; else hi = mid; }
  return lo;
}

// ---------------- graph readout -> reps split-bf16 planes [NL*NG rows][256 ch] ----------------
__global__ __launch_bounds__(128) void k_readout(
    const float* __restrict__ h, const float* __restrict__ wnode,
    const int* __restrict__ n2g, unsigned short* __restrict__ xplh,
    unsigned short* __restrict__ xpll, int layer)
{
  int g = blockIdx.x;
  int j = threadIdx.x;
  int lo = lbound_(n2g, NN, g);
  int hi = lbound_(n2g, NN, g + 1);
  float ws0 = 0.f, hm0 = -INFINITY, ws1 = 0.f, hm1 = -INFINITY;
  int n = lo;
  for (; n + 1 < hi; n += 2) {
    float hv0 = h[(size_t)n * 128 + j];
    float hv1 = h[(size_t)(n + 1) * 128 + j];
    ws0 = fmaf(wnode[n], hv0, ws0);     hm0 = fmaxf(hm0, hv0);
    ws1 = fmaf(wnode[n + 1], hv1, ws1); hm1 = fmaxf(hm1, hv1);
  }
  if (n < hi) {
    float hv0 = h[(size_t)n * 128 + j];
    ws0 = fmaf(wnode[n], hv0, ws0); hm0 = fmaxf(hm0, hv0);
  }
  float ws = ws0 + ws1, hm = fmaxf(hm0, hm1);
  if (hi == lo) hm = 0.f;
  int r = layer * NG + g;
  {
    unsigned short hi16 = bf16r_(ws);
    unsigned short lo16 = bf16r_(ws - bf16tof_(hi16));
    size_t si = (size_t)r * 256 + (((j >> 3) ^ (r & 7)) << 3) + (j & 7);
    xplh[si] = hi16; xpll[si] = lo16;
  }
  {
    int ch = 128 + j;
    unsigned short hi16 = bf16r_(hm);
    unsigned short lo16 = bf16r_(hm - bf16tof_(hi16));
    size_t si = (size_t)r * 256 + (((ch >> 3) ^ (r & 7)) << 3) + (ch & 7);
    xplh[si] = hi16; xpll[si] = lo16;
  }
}

// ---------------- persistent MFMA GRU (unchanged from R5) ----------------
__global__ __launch_bounds__(512, 2) void k_gru_mfma(
    float* __restrict__ h,
    const unsigned short* __restrict__ xhi, const unsigned short* __restrict__ xlo,
    const unsigned short* __restrict__ agghi, const unsigned short* __restrict__ agglo,
    const unsigned short* __restrict__ Wp, const float* __restrict__ bcat,
    const float* __restrict__ bnp)
{
  __shared__ alignas(16) unsigned short A[2][32768];
  const int tid = threadIdx.x;
  const int lane = tid & 63;
  const int wv = tid >> 6;
  const int mfr = lane & 15;
  const int kq = lane >> 4;

  bfrag8 wreg[8][4];
#pragma unroll
  for (int kb = 0; kb < 8; ++kb) {
    int ng = (kb < 4) ? 4 : 3;
#pragma unroll
    for (int g = 0; g < 4; ++g) {
      if (g < ng) {
        int n = g * 128 + wv * 16 + mfr;
        wreg[kb][g] = *(const bfrag8*)(Wp + (size_t)kb * 16384 + n * 32 + kq * 8);
      }
    }
  }

  auto stage = [&](int buf, int tile) {
    size_t goff = (size_t)tile * 64 * 128;
    const unsigned short* srcs[4] = { xhi + goff, xlo + goff, agghi + goff, agglo + goff };
#pragma unroll
    for (int p = 0; p < 4; ++p) {
#pragma unroll
      for (int it = 0; it < 2; ++it) {
        int off = it * 4096 + wv * 512;
        gl_lds16(srcs[p] + off + lane * 8, &A[buf][p * 8192 + off]);
      }
    }
  };

  int tile = blockIdx.x;
  stage(0, tile);
  __syncthreads();
  int cur = 0;

  while (true) {
    int nxt = tile + GRUGRID;
    if (nxt < NT) stage(cur ^ 1, nxt);

    f32x4 acc[4][4];
#pragma unroll
    for (int m = 0; m < 4; ++m)
#pragma unroll
      for (int g = 0; g < 4; ++g) acc[m][g] = (f32x4){0.f, 0.f, 0.f, 0.f};

    const char* Ab = (const char*)&A[cur][0];
#pragma unroll
    for (int kb = 0; kb < 8; ++kb) {
      int kp = kb & 3;
      int hoff = (kb < 4) ? 0 : 32768;
      int ng = (kb < 4) ? 4 : 3;
      bfrag8 ah[4], al[4];
#pragma unroll
      for (int m = 0; m < 4; ++m) {
        int row = m * 16 + mfr;
        int cs = (((kp * 4 + kq) ^ (row & 7)) << 4);
        ah[m] = *(const bfrag8*)(Ab + hoff + row * 256 + cs);
        al[m] = *(const bfrag8*)(Ab + hoff + 16384 + row * 256 + cs);
      }
#pragma unroll
      for (int m = 0; m < 4; ++m)
#pragma unroll
        for (int g = 0; g < 4; ++g) {
          if (g < ng) {
            acc[m][g] = __builtin_amdgcn_mfma_f32_16x16x32_bf16(ah[m], wreg[kb][g], acc[m][g], 0, 0, 0);
            acc[m][g] = __builtin_amdgcn_mfma_f32_16x16x32_bf16(al[m], wreg[kb][g], acc[m][g], 0, 0, 0);
          }
        }
    }

    {
      int m0 = tile * 64;
      int j = wv * 16 + mfr;
      float sc = bnp[j], sh = bnp[128 + j];
      float isc = 1.f / sc;
      float br = bcat[j], bz = bcat[128 + j], bi = bcat[256 + j], bh = bcat[384 + j];
      int chunk = j >> 3;
      int jb = (j & 7) * 2;
#pragma unroll
      for (int m = 0; m < 4; ++m) {
#pragma unroll
        for (int reg = 0; reg < 4; ++reg) {
          int rr = m * 16 + kq * 4 + reg;
          int node = m0 + rr;
          int byte = rr * 256 + ((chunk ^ (rr & 7)) << 4) + jb;
          unsigned short xh = *(const unsigned short*)(Ab + byte);
          unsigned short xl = *(const unsigned short*)(Ab + 16384 + byte);
          float x = bf16tof_(xh) + bf16tof_(xl);
          float hv = (x - sh) * isc;
          float r = sig_(acc[m][0][reg] + br);
          float z = sig_(acc[m][1][reg] + bz);
          float ng2 = tanhf(fmaf(r, acc[m][3][reg] + bh, acc[m][2][reg] + bi));
          float o = (1.f - z) * ng2 + z * x;
          float hc = (o > 0.f) ? o : expm1f(o);
          if (node < NN) h[(size_t)node * 128 + j] = hv + hc;
        }
      }
    }

    if (nxt >= NT) break;
    __syncthreads();
    cur ^= 1;
    tile = nxt;
  }
}

// ---------------- x-gates precompute: gx = reps @ W_ih^T + bias (all steps, fwd+bwd) ----------------
// grid 96 x 512: bid<80 -> bwd tiles (rows 0..5120 of planes), else fwd tiles (rows 0..1024)
__global__ __launch_bounds__(512) void k_xgates(
    const unsigned short* __restrict__ xplh, const unsigned short* __restrict__ xpll,
    const unsigned short* __restrict__ Wihb, const unsigned short* __restrict__ Wihf,
    const float* __restrict__ bcb, const float* __restrict__ bcf,
    float* __restrict__ gxb, float* __restrict__ gxf)
{
  __shared__ alignas(16) unsigned short Ah[16384], Al[16384];  // 64 rows x 256 ch
  int bid = blockIdx.x;
  const unsigned short* Wp; const float* bc; float* gx; int r0;
  if (bid < 80) { Wp = Wihb; bc = bcb; gx = gxb; r0 = bid * 64; }
  else          { Wp = Wihf; bc = bcf; gx = gxf; r0 = (bid - 80) * 64; }
  const int tid = threadIdx.x;
  const int lane = tid & 63;
  const int wv = tid >> 6;
  const int mfr = lane & 15;
  const int kq = lane >> 4;
  const int j = wv * 16 + mfr;

#pragma unroll
  for (int q = 0; q < 4; ++q) {
    int off = (q * 512 + wv * 64) * 8;
    gl_lds16(xplh + (size_t)r0 * 256 + off + lane * 8, &Ah[off]);
    gl_lds16(xpll + (size_t)r0 * 256 + off + lane * 8, &Al[off]);
  }

  bfrag8 wr[8][4];
#pragma unroll
  for (int kb = 0; kb < 8; ++kb)
#pragma unroll
    for (int g = 0; g < 4; ++g) {
      int n = g * 128 + j;
      wr[kb][g] = *(const bfrag8*)(Wp + (size_t)kb * 16384 + n * 32 + kq * 8);
    }

  __syncthreads();

  f32x4 acc[4][4];
#pragma unroll
  for (int m = 0; m < 4; ++m)
#pragma unroll
    for (int g = 0; g < 4; ++g) acc[m][g] = (f32x4){0.f, 0.f, 0.f, 0.f};

  const char* Ab = (const char*)Ah;
  const char* Al8 = (const char*)Al;
#pragma unroll
  for (int kb = 0; kb < 8; ++kb) {
    bfrag8 ah[4], al[4];
#pragma unroll
    for (int m = 0; m < 4; ++m) {
      int rr = m * 16 + mfr;
      int cs = ((((kb * 4 + kq)) ^ (rr & 7)) << 4);
      ah[m] = *(const bfrag8*)(Ab + rr * 512 + cs);
      al[m] = *(const bfrag8*)(Al8 + rr * 512 + cs);
    }
#pragma unroll
    for (int m = 0; m < 4; ++m)
#pragma unroll
      for (int g = 0; g < 4; ++g) {
        acc[m][g] = __builtin_amdgcn_mfma_f32_16x16x32_bf16(ah[m], wr[kb][g], acc[m][g], 0, 0, 0);
        acc[m][g] = __builtin_amdgcn_mfma_f32_16x16x32_bf16(al[m], wr[kb][g], acc[m][g], 0, 0, 0);
      }
  }

#pragma unroll
  for (int g = 0; g < 4; ++g) {
    float b = bc[g * 128 + j];
#pragma unroll
    for (int m = 0; m < 4; ++m)
#pragma unroll
      for (int reg = 0; reg < 4; ++reg) {
        int rr = m * 16 + kq * 4 + reg;
        gx[((size_t)(r0 + rr)) * 512 + g * 128 + j] = acc[m][g][reg] + b;
      }
  }
}

// ---------------- fwd LSTM step 0 (h0=c0=0): pure pointwise ----------------
__global__ __launch_bounds__(256) void k_lstm0(const float* __restrict__ gxf, float* __restrict__ yf)
{
  int i = blockIdx.x * 256 + threadIdx.x;  // 131072
  int row = i >> 7, j = i & 127;
  const float* gp = gxf + (size_t)row * 512;
  float cn = sig_(gp[j]) * tanhf(gp[256 + j]);
  yf[i] = sig_(gp[384 + j]) * tanhf(cn);
}

// ---------------- bwd LSTM recurrence: 5 steps in one kernel, W_hh in regs, h in LDS planes ----------------
// grid 32 x 512; block owns 32 graphs. Gate order i,f,g,o.
__global__ __launch_bounds__(512) void k_lstm_rec(
    const float* __restrict__ gxb, const unsigned short* __restrict__ Whh,
    float* __restrict__ yb)
{
  __shared__ alignas(16) unsigned short Hh[4096], Hl[4096];  // 32 rows x 128 ch
  const int tid = threadIdx.x;
  const int lane = tid & 63;
  const int wv = tid >> 6;
  const int mfr = lane & 15;
  const int kq = lane >> 4;
  const int r0 = blockIdx.x * 32;
  const int j = wv * 16 + mfr;

  bfrag8 whh[4][4];
#pragma unroll
  for (int kb = 0; kb < 4; ++kb)
#pragma unroll
    for (int g = 0; g < 4; ++g) {
      int n = g * 128 + j;
      whh[kb][g] = *(const bfrag8*)(Whh + (size_t)kb * 16384 + n * 32 + kq * 8);
    }

  float cc[2][4];
  // t = 4: h=c=0 -> pointwise from gxb
#pragma unroll
  for (int m = 0; m < 2; ++m)
#pragma unroll
    for (int reg = 0; reg < 4; ++reg) {
      int rr = m * 16 + kq * 4 + reg;
      const float* gp = gxb + ((size_t)(4 * NG) + r0 + rr) * 512;
      float cn = sig_(gp[j]) * tanhf(gp[256 + j]);
      cc[m][reg] = cn;
      float hh = sig_(gp[384 + j]) * tanhf(cn);
      unsigned short hb16 = bf16r_(hh);
      unsigned short lb16 = bf16r_(hh - bf16tof_(hb16));
      int si = rr * 128 + (((j >> 3) ^ (rr & 7)) << 3) + (j & 7);
      Hh[si] = hb16; Hl[si] = lb16;
    }
  __syncthreads();

  for (int t = 3; t >= 0; --t) {
    f32x4 acc[2][4];
#pragma unroll
    for (int m = 0; m < 2; ++m)
#pragma unroll
      for (int g = 0; g < 4; ++g) acc[m][g] = (f32x4){0.f, 0.f, 0.f, 0.f};
    const char* Bh = (const char*)Hh;
    const char* Bl = (const char*)Hl;
#pragma unroll
    for (int kb = 0; kb < 4; ++kb) {
      bfrag8 ah[2], al[2];
#pragma unroll
      for (int m = 0; m < 2; ++m) {
        int rr = m * 16 + mfr;
        int cs = (((kb * 4 + kq) ^ (rr & 7)) << 4);
        ah[m] = *(const bfrag8*)(Bh + rr * 256 + cs);
        al[m] = *(const bfrag8*)(Bl + rr * 256 + cs);
      }
#pragma unroll
      for (int m = 0; m < 2; ++m)
#pragma unroll
        for (int g = 0; g < 4; ++g) {
          acc[m][g] = __builtin_amdgcn_mfma_f32_16x16x32_bf16(ah[m], whh[kb][g], acc[m][g], 0, 0, 0);
          acc[m][g] = __builtin_amdgcn_mfma_f32_16x16x32_bf16(al[m], whh[kb][g], acc[m][g], 0, 0, 0);
        }
    }
    __syncthreads();  // all reads of H done before overwriting
#pragma unroll
    for (int m = 0; m < 2; ++m)
#pragma unroll
      for (int reg = 0; reg < 4; ++reg) {
        int rr = m * 16 + kq * 4 + reg;
        const float* gp = gxb + ((size_t)(t * NG) + r0 + rr) * 512;
        float g0 = acc[m][0][reg] + gp[j];
        float g1 = acc[m][1][reg] + gp[128 + j];
        float g2 = acc[m][2][reg] + gp[256 + j];
        float g3 = acc[m][3][reg] + gp[384 + j];
        float cn = fmaf(sig_(g1), cc[m][reg], sig_(g0) * tanhf(g2));
        cc[m][reg] = cn;
        float hh = sig_(g3) * tanhf(cn);
        if (t > 0) {
          unsigned short hb16 = bf16r_(hh);
          unsigned short lb16 = bf16r_(hh - bf16tof_(hb16));
          int si = rr * 128 + (((j >> 3) ^ (rr & 7)) << 3) + (j & 7);
          Hh[si] = hb16; Hl[si] = lb16;
        } else {
          yb[(size_t)(r0 + rr) * 128 + j] = hh;
        }
      }
    if (t > 0) __syncthreads();
  }
}

// ---------------- final projection ----------------
__global__ __launch_bounds__(256) void k_final(
    const float* __restrict__ yf, const float* __restrict__ yb,
    const float* __restrict__ W_out, const float* __restrict__ b_out,
    float* __restrict__ out)
{
  int tid = threadIdx.x;
  int g = blockIdx.x * 4 + (tid >> 6);
  int lane = tid & 63;
  float a0 = 0.f, a1 = 0.f;
  for (int k = lane; k < 128; k += 64) {
    float v = yf[g * 128 + k];
    a0 = fmaf(v, W_out[k * 2 + 0], a0);
    a1 = fmaf(v, W_out[k * 2 + 1], a1);
    float u = yb[g * 128 + k];
    a0 = fmaf(u, W_out[(128 + k) * 2 + 0], a0);
    a1 = fmaf(u, W_out[(128 + k) * 2 + 1], a1);
  }
#pragma unroll
  for (int o = 32; o > 0; o >>= 1) { a0 += __shfl_xor(a0, o); a1 += __shfl_xor(a1, o); }
  if (lane == 0) {
    out[g * 2 + 0] = a0 + b_out[0];
    out[g * 2 + 1] = a1 + b_out[1];
  }
}

extern "C" void kernel_launch(void* const* d_in, const int* in_sizes, int n_in,
                              void* d_out, int out_size, void* d_ws, size_t ws_size,
                              hipStream_t stream)
{
  (void)in_sizes; (void)n_in; (void)out_size; (void)ws_size;
  const float* feats   = (const float*)d_in[0];
  const int*   src     = (const int*)d_in[1];
  const int*   dst     = (const int*)d_in[2];
  const int*   n2g     = (const int*)d_in[3];
  const float* W_in    = (const float*)d_in[4];
  const float* b_in    = (const float*)d_in[5];
  const float* bng     = (const float*)d_in[6];
  const float* bnb     = (const float*)d_in[7];
  const float* bnm     = (const float*)d_in[8];
  const float* bnv     = (const float*)d_in[9];
  const float* gw_ih   = (const float*)d_in[10];
  const float* gw_hh   = (const float*)d_in[11];
  const float* gb_ih   = (const float*)d_in[12];
  const float* gb_hh   = (const float*)d_in[13];
  const float* w_aw    = (const float*)d_in[14];
  const float* b_aw    = (const float*)d_in[15];
  const float* lwih_f  = (const float*)d_in[16];
  const float* lwhh_f  = (const float*)d_in[17];
  const float* lbih_f  = (const float*)d_in[18];
  const float* lbhh_f  = (const float*)d_in[19];
  const float* lwih_b  = (const float*)d_in[20];
  const float* lwhh_b  = (const float*)d_in[21];
  const float* lbih_b  = (const float*)d_in[22];
  const float* lbhh_b  = (const float*)d_in[23];
  const float* W_out   = (const float*)d_in[24];
  const float* b_out   = (const float*)d_in[25];
  float* out = (float*)d_out;
  (void)lwhh_f;  // fwd w_hh unused: h0 = 0 and only step 0 of fwd LSTM is needed

  float* ws = (float*)d_ws;
  size_t off = 0;
  auto alloc = [&](size_t n) { float* p = ws + off; off += (n + 63) & ~(size_t)63; return p; };
  float* h      = alloc((size_t)NP * 128);
  unsigned short* xhi   = (unsigned short*)alloc((size_t)NP * 64);
  unsigned short* xlo   = (unsigned short*)alloc((size_t)NP * 64);
  unsigned short* agghi = (unsigned short*)alloc((size_t)NP * 64);
  unsigned short* agglo = (unsigned short*)alloc((size_t)NP * 64);
  unsigned short* Wp    = (unsigned short*)alloc(65536);
  float* bcat   = alloc(512);
  float* wnode  = alloc(NN);
  float* bnp    = alloc(256);
  unsigned short* xplh = (unsigned short*)alloc((size_t)NL * NG * 128);  // NL*NG*256 shorts
  unsigned short* xpll = (unsigned short*)alloc((size_t)NL * NG * 128);
  unsigned short* Wihf = (unsigned short*)alloc(65536);   // 131072 shorts
  unsigned short* Wihb = (unsigned short*)alloc(65536);
  unsigned short* Whhb = (unsigned short*)alloc(32768);   // 65536 shorts
  float* bcf    = alloc(512);
  float* bcb    = alloc(512);
  float* gxb    = alloc((size_t)NL * NG * 512);
  float* gxf    = alloc((size_t)NG * 512);
  float* yf     = alloc((size_t)NG * 128);
  float* yb     = alloc((size_t)NG * 128);
  int* deg    = (int*)alloc(NN);
  int* rowptr = (int*)alloc(NN + 1);
  int* pos    = (int*)alloc(NN);
  int* colidx = (int*)alloc(NE);
  int* bsum   = (int*)alloc(256);
  int* boff   = (int*)alloc(256);

  // ---- one-time: CSR build + weight prepacks ----
  hipMemsetAsync(deg, 0, (size_t)NN * sizeof(int), stream);
  k_hist<<<(NE + 255) / 256, 256, 0, stream>>>(dst, deg);
  k_scan1<<<196, 256, 0, stream>>>(deg, bsum);
  k_scan2<<<1, 256, 0, stream>>>(bsum, boff, rowptr);
  k_scan3<<<196, 256, 0, stream>>>(deg, boff, rowptr);
  hipMemcpyAsync(pos, rowptr, (size_t)NN * sizeof(int), hipMemcpyDeviceToDevice, stream);
  k_fill<<<(NE + 255) / 256, 256, 0, stream>>>(src, dst, pos, colidx);
  k_wpack<<<512, 256, 0, stream>>>(gw_ih, gw_hh, gb_ih, gb_hh, Wp, bcat);
  k_wpack_lstm<<<1280, 256, 0, stream>>>(lwih_f, lwih_b, lwhh_b, lbih_f, lbhh_f, lbih_b, lbhh_b,
                                         Wihf, Wihb, Whhb, bcf, bcb);

  k_input_proj<<<NN, 128, 0, stream>>>(feats, W_in, b_in, h);

  for (int l = 0; l < NL; ++l) {
    k_bnprep<<<1, 128, 0, stream>>>(bng, bnb, bnm, bnv, l, bnp);
    k_prep<<<3125, 256, 0, stream>>>(h, bnp, w_aw, b_aw, xhi, xlo, wnode);
    k_gather<<<NN / 4, 256, 0, stream>>>(xhi, rowptr, colidx, agghi, agglo);
    k_readout<<<NG, 128, 0, stream>>>(h, wnode, n2g, xplh, xpll, l);
    k_gru_mfma<<<GRUGRID, 512, 0, stream>>>(h, xhi, xlo, agghi, agglo, Wp, bcat, bnp);
  }

  // ---- LSTM: x-gates for all steps (fwd step0 + bwd 5 steps), then recurrence ----
  k_xgates<<<96, 512, 0, stream>>>(xplh, xpll, Wihb, Wihf, bcb, bcf, gxb, gxf);
  k_lstm0<<<512, 256, 0, stream>>>(gxf, yf);
  k_lstm_rec<<<32, 512, 0, stream>>>(gxb, Whhb, yb);

  k_final<<<NG / 4, 256, 0, stream>>>(yf, yb, W_out, b_out, out);
}

// Round 7
// 669.334 us; speedup vs baseline: 11.5913x; 1.0956x over previous
//
#include <hip/hip_runtime.h>
#include <math.h>

#define NN 50000
#define NP 50048   // padded rows (multiple of 64)
#define NE 600000
#define NG 1024
#define NL 5
#define NT (NP / 64)     // 782 M-tiles
#define GRUGRID 256      // persistent blocks (1 per CU)
// Hd = 128, Fin = 74, C = 2

typedef __attribute__((ext_vector_type(8))) short bfrag8;
typedef __attribute__((ext_vector_type(4))) float f32x4;

__device__ __forceinline__ float sig_(float x) { return 1.f / (1.f + expf(-x)); }

__device__ __forceinline__ unsigned short bf16r_(float x) {
  union { float f; unsigned u; } v; v.f = x;
  unsigned u = v.u;
  return (unsigned short)((u + 0x7FFFu + ((u >> 16) & 1u)) >> 16);
}
__device__ __forceinline__ float bf16tof_(unsigned short h) {
  union { float f; unsigned u; } v; v.u = ((unsigned)h) << 16;
  return v.f;
}

// async global->LDS, 16B per lane; lds dst = uniform base + lane*16
__device__ __forceinline__ void gl_lds16(const unsigned short* g, unsigned short* l) {
  __builtin_amdgcn_global_load_lds(
      (const __attribute__((address_space(1))) unsigned int*)g,
      (__attribute__((address_space(3))) unsigned int*)l, 16, 0, 0);
}

// ---------------- input projection: h = feats @ W_in + b_in ----------------
// persistent: thread owns channel j, W column in VGPRs; feats row via scalar loads
__global__ __launch_bounds__(256) void k_input_proj(
    const float* __restrict__ feats, const float* __restrict__ W_in,
    const float* __restrict__ b_in, float* __restrict__ h)
{
  const int j = threadIdx.x & 127;
  const int half = threadIdx.x >> 7;   // wave-uniform (waves 0-1: 0, waves 2-3: 1)
  float wcol[74];
#pragma unroll
  for (int k = 0; k < 74; ++k) wcol[k] = W_in[k * 128 + j];
  const float bj = b_in[j];
  for (int p = blockIdx.x; p < NN / 2; p += gridDim.x) {
    int node = __builtin_amdgcn_readfirstlane(p * 2 + half);
    const float* fr = feats + (size_t)node * 74;
    float acc = bj;
#pragma unroll
    for (int k = 0; k < 74; ++k) acc = fmaf(fr[k], wcol[k], acc);
    h[(size_t)node * 128 + j] = acc;
  }
}

// ---------------- per-layer BN scale/shift precompute (all layers at once) ----------------
__global__ void k_bnprep_all(const float* __restrict__ g, const float* __restrict__ b,
                             const float* __restrict__ m, const float* __restrict__ v,
                             float* __restrict__ bnp)
{
  int l = blockIdx.x;   // NL blocks
  int j = threadIdx.x;  // 128 threads
  float s = g[l * 128 + j] * rsqrtf(v[l * 128 + j] + 1e-5f);
  bnp[l * 256 + j] = s;
  bnp[l * 256 + 128 + j] = b[l * 128 + j] - m[l * 128 + j] * s;
}

// ---------------- GRU weight prepack (once): Wp[kb][n][32k] bf16 + bcat ----------------
__global__ __launch_bounds__(256) void k_wpack(
    const float* __restrict__ w_ih, const float* __restrict__ w_hh,
    const float* __restrict__ b_ih, const float* __restrict__ b_hh,
    unsigned short* __restrict__ Wp, float* __restrict__ bcat)
{
  int idx = blockIdx.x * 256 + threadIdx.x;  // 512*256 threads
  int n = idx >> 8, k = idx & 255;
  float val;
  if (n < 256) {
    val = (k < 128) ? fmaf(1.00001f, w_ih[n * 256 + k], w_hh[n * 128 + k])
                    : w_ih[n * 256 + k];
  } else if (n < 384) {
    val = (k < 128) ? 1.00001f * w_ih[n * 256 + k] : w_ih[n * 256 + k];
  } else {
    int g = n - 128;
    val = (k < 128) ? w_hh[g * 128 + k] : 0.f;
  }
  Wp[(size_t)(k >> 5) * 16384 + n * 32 + (k & 31)] = bf16r_(val);
  if (k == 0) {
    float bc;
    if (n < 256) bc = b_ih[n] + b_hh[n];
    else if (n < 384) bc = b_ih[n];
    else bc = b_hh[n - 128];
    bcat[n] = bc;
  }
}

// ---------------- LSTM weight prepack (once): ih fwd/bwd + hh bwd + biases ----------------
__global__ __launch_bounds__(256) void k_wpack_lstm(
    const float* __restrict__ lwih_f, const float* __restrict__ lwih_b,
    const float* __restrict__ lwhh_b,
    const float* __restrict__ lbih_f, const float* __restrict__ lbhh_f,
    const float* __restrict__ lbih_b, const float* __restrict__ lbhh_b,
    unsigned short* __restrict__ Wihf, unsigned short* __restrict__ Wihb,
    unsigned short* __restrict__ Whhb, float* __restrict__ bcf, float* __restrict__ bcb)
{
  int idx = blockIdx.x * 256 + threadIdx.x;
  if (idx < 131072) {
    int n = idx >> 8, k = idx & 255;
    Wihf[(size_t)(k >> 5) * 16384 + n * 32 + (k & 31)] = bf16r_(lwih_f[n * 256 + k]);
  } else if (idx < 262144) {
    int i2 = idx - 131072; int n = i2 >> 8, k = i2 & 255;
    Wihb[(size_t)(k >> 5) * 16384 + n * 32 + (k & 31)] = bf16r_(lwih_b[n * 256 + k]);
  } else if (idx < 327680) {
    int i2 = idx - 262144; int n = i2 >> 7, k = i2 & 127;
    Whhb[(size_t)(k >> 5) * 16384 + n * 32 + (k & 31)] = bf16r_(lwhh_b[n * 128 + k]);
  }
  if (idx < 512) {
    bcf[idx] = lbih_f[idx] + lbhh_f[idx];
    bcb[idx] = lbih_b[idx] + lbhh_b[idx];
  }
}

// ---------------- prep: x = BN(h) -> swizzled bf16 hi/lo planes; + wnode ----------------
__global__ __launch_bounds__(256) void k_prep(
    const float* __restrict__ h, const float* __restrict__ bnp,
    const float* __restrict__ w_aw, const float* __restrict__ b_aw,
    unsigned short* __restrict__ xhi, unsigned short* __restrict__ xlo,
    float* __restrict__ wnode)
{
  int t = blockIdx.x * 256 + threadIdx.x;
  int row = t >> 4, c = t & 15;
  const float* hp = h + (size_t)row * 128 + c * 8;
  float4 h0 = *(const float4*)(hp);
  float4 h1 = *(const float4*)(hp + 4);
  float4 s0 = *(const float4*)(bnp + c * 8);
  float4 s1 = *(const float4*)(bnp + c * 8 + 4);
  float4 t0 = *(const float4*)(bnp + 128 + c * 8);
  float4 t1 = *(const float4*)(bnp + 128 + c * 8 + 4);
  float x[8] = { fmaf(h0.x, s0.x, t0.x), fmaf(h0.y, s0.y, t0.y),
                 fmaf(h0.z, s0.z, t0.z), fmaf(h0.w, s0.w, t0.w),
                 fmaf(h1.x, s1.x, t1.x), fmaf(h1.y, s1.y, t1.y),
                 fmaf(h1.z, s1.z, t1.z), fmaf(h1.w, s1.w, t1.w) };
  unsigned hiw[4], low[4];
#pragma unroll
  for (int i = 0; i < 4; ++i) {
    unsigned short ha = bf16r_(x[2 * i]), hb = bf16r_(x[2 * i + 1]);
    unsigned short la = bf16r_(x[2 * i] - bf16tof_(ha));
    unsigned short lb = bf16r_(x[2 * i + 1] - bf16tof_(hb));
    hiw[i] = (unsigned)ha | ((unsigned)hb << 16);
    low[i] = (unsigned)la | ((unsigned)lb << 16);
  }
  size_t dst = (size_t)row * 16 + (c ^ (row & 7));
  ((uint4*)xhi)[dst] = make_uint4(hiw[0], hiw[1], hiw[2], hiw[3]);
  ((uint4*)xlo)[dst] = make_uint4(low[0], low[1], low[2], low[3]);
  const float4 wa0 = *(const float4*)(w_aw + c * 8);
  const float4 wa1 = *(const float4*)(w_aw + c * 8 + 4);
  float p = h0.x * wa0.x + h0.y * wa0.y + h0.z * wa0.z + h0.w * wa0.w +
            h1.x * wa1.x + h1.y * wa1.y + h1.z * wa1.z + h1.w * wa1.w;
#pragma unroll
  for (int o = 8; o > 0; o >>= 1) p += __shfl_xor(p, o);
  if (c == 0) wnode[row] = sig_(p + b_aw[0]);
}

// ---------------- CSR build: histogram -> hierarchical scan -> fill ----------------
__global__ __launch_bounds__(256) void k_hist(const int* __restrict__ dst, int* __restrict__ deg)
{
  int t = blockIdx.x * 256 + threadIdx.x;
  if (t < NE) atomicAdd(&deg[dst[t]], 1);
}

__global__ __launch_bounds__(256) void k_scan1(const int* __restrict__ deg, int* __restrict__ bsum)
{
  __shared__ int red[4];
  int i = blockIdx.x * 256 + threadIdx.x;
  int d = (i < NN) ? deg[i] : 0;
  int s = d;
#pragma unroll
  for (int o = 32; o > 0; o >>= 1) s += __shfl_xor(s, o);
  if ((threadIdx.x & 63) == 0) red[threadIdx.x >> 6] = s;
  __syncthreads();
  if (threadIdx.x == 0) bsum[blockIdx.x] = red[0] + red[1] + red[2] + red[3];
}

__global__ __launch_bounds__(256) void k_scan2(const int* __restrict__ bsum, int* __restrict__ boff,
                                               int* __restrict__ rowptr)
{
  __shared__ int part[256];
  int t = threadIdx.x;
  int v = (t < 196) ? bsum[t] : 0;
  part[t] = v;
  __syncthreads();
  for (int o = 1; o < 256; o <<= 1) {
    int u = (t >= o) ? part[t - o] : 0;
    __syncthreads();
    part[t] += u;
    __syncthreads();
  }
  if (t < 196) boff[t] = part[t] - v;  // exclusive
  if (t == 0) rowptr[NN] = NE;
}

__global__ __launch_bounds__(256) void k_scan3(const int* __restrict__ deg, const int* __restrict__ boff,
                                               int* __restrict__ rowptr)
{
  __shared__ int part[256];
  int t = threadIdx.x;
  int i = blockIdx.x * 256 + t;
  int d = (i < NN) ? deg[i] : 0;
  part[t] = d;
  __syncthreads();
  for (int o = 1; o < 256; o <<= 1) {
    int u = (t >= o) ? part[t - o] : 0;
    __syncthreads();
    part[t] += u;
    __syncthreads();
  }
  if (i < NN) rowptr[i] = boff[blockIdx.x] + part[t] - d;
}

__global__ __launch_bounds__(256) void k_fill(
    const int* __restrict__ src, const int* __restrict__ dst,
    int* __restrict__ pos, int* __restrict__ col)
{
  int t = blockIdx.x * 256 + threadIdx.x;
  if (t >= NE) return;
  int p = atomicAdd(&pos[dst[t]], 1);
  col[p] = src[t];
}

// ---------------- CSR gather from x_hi plane -> split-bf16 agg planes ----------------
__global__ __launch_bounds__(256) void k_gather(
    const unsigned short* __restrict__ xhi, const int* __restrict__ rowptr,
    const int* __restrict__ col,
    unsigned short* __restrict__ agghi, unsigned short* __restrict__ agglo)
{
  int n = blockIdx.x * 4 + (threadIdx.x >> 6);
  int lane = threadIdx.x & 63;
  int c = lane >> 2, q = lane & 3;
  int lo = rowptr[n], hi = rowptr[n + 1];
  const unsigned* xp = (const unsigned*)xhi;
  float a0 = 0.f, a1 = 0.f, a2 = 0.f, a3 = 0.f;
  float b0 = 0.f, b1 = 0.f, b2 = 0.f, b3 = 0.f;
  int e = lo;
  for (; e + 3 < hi; e += 4) {
    int r0 = col[e], r1 = col[e + 1], r2 = col[e + 2], r3 = col[e + 3];
    unsigned u0 = xp[(size_t)r0 * 64 + ((c ^ (r0 & 7)) << 2) + q];
    unsigned u1 = xp[(size_t)r1 * 64 + ((c ^ (r1 & 7)) << 2) + q];
    unsigned u2 = xp[(size_t)r2 * 64 + ((c ^ (r2 & 7)) << 2) + q];
    unsigned u3 = xp[(size_t)r3 * 64 + ((c ^ (r3 & 7)) << 2) + q];
    a0 += bf16tof_((unsigned short)(u0 & 0xFFFF)); b0 += bf16tof_((unsigned short)(u0 >> 16));
    a1 += bf16tof_((unsigned short)(u1 & 0xFFFF)); b1 += bf16tof_((unsigned short)(u1 >> 16));
    a2 += bf16tof_((unsigned short)(u2 & 0xFFFF)); b2 += bf16tof_((unsigned short)(u2 >> 16));
    a3 += bf16tof_((unsigned short)(u3 & 0xFFFF)); b3 += bf16tof_((unsigned short)(u3 >> 16));
  }
  for (; e < hi; ++e) {
    int r0 = col[e];
    unsigned u0 = xp[(size_t)r0 * 64 + ((c ^ (r0 & 7)) << 2) + q];
    a0 += bf16tof_((unsigned short)(u0 & 0xFFFF));
    b0 += bf16tof_((unsigned short)(u0 >> 16));
  }
  float s0 = (a0 + a1) + (a2 + a3), s1 = (b0 + b1) + (b2 + b3);
  unsigned short h0 = bf16r_(s0), h1 = bf16r_(s1);
  unsigned short l0 = bf16r_(s0 - bf16tof_(h0)), l1 = bf16r_(s1 - bf16tof_(h1));
  size_t w = (size_t)n * 64 + ((c ^ (n & 7)) << 2) + q;
  ((unsigned*)agghi)[w] = (unsigned)h0 | ((unsigned)h1 << 16);
  ((unsigned*)agglo)[w] = (unsigned)l0 | ((unsigned)l1 << 16);
}

__device__ __forceinline__ int lbound_(const int* __restrict__ a, int n, int key)
{
  int lo = 0, hi = n;
  while (lo < hi) { int mid = (lo + hi) >> 1; if (a[mid] < key) lo = mid + 1; else hi = mid; }
  return lo;
}

// ---------------- graph readout -> reps split-bf16 planes [NL*NG rows][256 ch] ----------------
// 256 threads: ty = tid>>7 splits the node range 2-way; LDS combine.
__global__ __launch_bounds__(256) void k_readout(
    const float* __restrict__ h, const float* __restrict__ wnode,
    const int* __restrict__ n2g, unsigned short* __restrict__ xplh,
    unsigned short* __restrict__ xpll, int layer)
{
  __shared__ float WS[128], HM[128];
  int g = blockIdx.x;
  int tid = threadIdx.x;
  int j = tid & 127, ty = tid >> 7;
  int lo = lbound_(n2g, NN, g);
  int hi = lbound_(n2g, NN, g + 1);
  float ws0 = 0.f, hm0 = -INFINITY, ws1 = 0.f, hm1 = -INFINITY;
  int n = lo + ty;
  for (; n + 2 < hi; n += 4) {
    float hv0 = h[(size_t)n * 128 + j];
    float hv1 = h[(size_t)(n + 2) * 128 + j];
    ws0 = fmaf(wnode[n], hv0, ws0);     hm0 = fmaxf(hm0, hv0);
    ws1 = fmaf(wnode[n + 2], hv1, ws1); hm1 = fmaxf(hm1, hv1);
  }
  if (n < hi) {
    float hv0 = h[(size_t)n * 128 + j];
    ws0 = fmaf(wnode[n], hv0, ws0); hm0 = fmaxf(hm0, hv0);
  }
  float ws = ws0 + ws1, hm = fmaxf(hm0, hm1);
  if (ty == 1) { WS[j] = ws; HM[j] = hm; }
  __syncthreads();
  if (ty == 0) {
    ws += WS[j];
    hm = fmaxf(hm, HM[j]);
    if (hi == lo) hm = 0.f;
    int r = layer * NG + g;
    {
      unsigned short hi16 = bf16r_(ws);
      unsigned short lo16 = bf16r_(ws - bf16tof_(hi16));
      size_t si = (size_t)r * 256 + (((j >> 3) ^ (r & 7)) << 3) + (j & 7);
      xplh[si] = hi16; xpll[si] = lo16;
    }
    {
      int ch = 128 + j;
      unsigned short hi16 = bf16r_(hm);
      unsigned short lo16 = bf16r_(hm - bf16tof_(hi16));
      size_t si = (size_t)r * 256 + (((ch >> 3) ^ (r & 7)) << 3) + (ch & 7);
      xplh[si] = hi16; xpll[si] = lo16;
    }
  }
}

// ---------------- persistent MFMA GRU (unchanged structure) ----------------
__global__ __launch_bounds__(512, 2) void k_gru_mfma(
    float* __restrict__ h,
    const unsigned short* __restrict__ xhi, const unsigned short* __restrict__ xlo,
    const unsigned short* __restrict__ agghi, const unsigned short* __restrict__ agglo,
    const unsigned short* __restrict__ Wp, const float* __restrict__ bcat,
    const float* __restrict__ bnp)
{
  __shared__ alignas(16) unsigned short A[2][32768];
  const int tid = threadIdx.x;
  const int lane = tid & 63;
  const int wv = tid >> 6;
  const int mfr = lane & 15;
  const int kq = lane >> 4;

  bfrag8 wreg[8][4];
#pragma unroll
  for (int kb = 0; kb < 8; ++kb) {
    int ng = (kb < 4) ? 4 : 3;
#pragma unroll
    for (int g = 0; g < 4; ++g) {
      if (g < ng) {
        int n = g * 128 + wv * 16 + mfr;
        wreg[kb][g] = *(const bfrag8*)(Wp + (size_t)kb * 16384 + n * 32 + kq * 8);
      }
    }
  }

  auto stage = [&](int buf, int tile) {
    size_t goff = (size_t)tile * 64 * 128;
    const unsigned short* srcs[4] = { xhi + goff, xlo + goff, agghi + goff, agglo + goff };
#pragma unroll
    for (int p = 0; p < 4; ++p) {
#pragma unroll
      for (int it = 0; it < 2; ++it) {
        int off = it * 4096 + wv * 512;
        gl_lds16(srcs[p] + off + lane * 8, &A[buf][p * 8192 + off]);
      }
    }
  };

  int tile = blockIdx.x;
  stage(0, tile);
  __syncthreads();
  int cur = 0;

  while (true) {
    int nxt = tile + GRUGRID;
    if (nxt < NT) stage(cur ^ 1, nxt);

    f32x4 acc[4][4];
#pragma unroll
    for (int m = 0; m < 4; ++m)
#pragma unroll
      for (int g = 0; g < 4; ++g) acc[m][g] = (f32x4){0.f, 0.f, 0.f, 0.f};

    const char* Ab = (const char*)&A[cur][0];
#pragma unroll
    for (int kb = 0; kb < 8; ++kb) {
      int kp = kb & 3;
      int hoff = (kb < 4) ? 0 : 32768;
      int ng = (kb < 4) ? 4 : 3;
      bfrag8 ah[4], al[4];
#pragma unroll
      for (int m = 0; m < 4; ++m) {
        int row = m * 16 + mfr;
        int cs = (((kp * 4 + kq) ^ (row & 7)) << 4);
        ah[m] = *(const bfrag8*)(Ab + hoff + row * 256 + cs);
        al[m] = *(const bfrag8*)(Ab + hoff + 16384 + row * 256 + cs);
      }
#pragma unroll
      for (int m = 0; m < 4; ++m)
#pragma unroll
        for (int g = 0; g < 4; ++g) {
          if (g < ng) {
            acc[m][g] = __builtin_amdgcn_mfma_f32_16x16x32_bf16(ah[m], wreg[kb][g], acc[m][g], 0, 0, 0);
            acc[m][g] = __builtin_amdgcn_mfma_f32_16x16x32_bf16(al[m], wreg[kb][g], acc[m][g], 0, 0, 0);
          }
        }
    }

    {
      int m0 = tile * 64;
      int j = wv * 16 + mfr;
      float sc = bnp[j], sh = bnp[128 + j];
      float isc = 1.f / sc;
      float br = bcat[j], bz = bcat[128 + j], bi = bcat[256 + j], bh = bcat[384 + j];
      int chunk = j >> 3;
      int jb = (j & 7) * 2;
#pragma unroll
      for (int m = 0; m < 4; ++m) {
#pragma unroll
        for (int reg = 0; reg < 4; ++reg) {
          int rr = m * 16 + kq * 4 + reg;
          int node = m0 + rr;
          int byte = rr * 256 + ((chunk ^ (rr & 7)) << 4) + jb;
          unsigned short xh = *(const unsigned short*)(Ab + byte);
          unsigned short xl = *(const unsigned short*)(Ab + 16384 + byte);
          float x = bf16tof_(xh) + bf16tof_(xl);
          float hv = (x - sh) * isc;
          float r = sig_(acc[m][0][reg] + br);
          float z = sig_(acc[m][1][reg] + bz);
          float ng2 = tanhf(fmaf(r, acc[m][3][reg] + bh, acc[m][2][reg] + bi));
          float o = (1.f - z) * ng2 + z * x;
          float hc = (o > 0.f) ? o : expm1f(o);
          if (node < NN) h[(size_t)node * 128 + j] = hv + hc;
        }
      }
    }

    if (nxt >= NT) break;
    __syncthreads();
    cur ^= 1;
    tile = nxt;
  }
}

// ---------------- x-gates precompute: gx = reps @ W_ih^T + bias (all steps, fwd+bwd) ----------------
__global__ __launch_bounds__(512) void k_xgates(
    const unsigned short* __restrict__ xplh, const unsigned short* __restrict__ xpll,
    const unsigned short* __restrict__ Wihb, const unsigned short* __restrict__ Wihf,
    const float* __restrict__ bcb, const float* __restrict__ bcf,
    float* __restrict__ gxb, float* __restrict__ gxf)
{
  __shared__ alignas(16) unsigned short Ah[16384], Al[16384];  // 64 rows x 256 ch
  int bid = blockIdx.x;
  const unsigned short* Wp; const float* bc; float* gx; int r0;
  if (bid < 80) { Wp = Wihb; bc = bcb; gx = gxb; r0 = bid * 64; }
  else          { Wp = Wihf; bc = bcf; gx = gxf; r0 = (bid - 80) * 64; }
  const int tid = threadIdx.x;
  const int lane = tid & 63;
  const int wv = tid >> 6;
  const int mfr = lane & 15;
  const int kq = lane >> 4;
  const int j = wv * 16 + mfr;

#pragma unroll
  for (int q = 0; q < 4; ++q) {
    int off = (q * 512 + wv * 64) * 8;
    gl_lds16(xplh + (size_t)r0 * 256 + off + lane * 8, &Ah[off]);
    gl_lds16(xpll + (size_t)r0 * 256 + off + lane * 8, &Al[off]);
  }

  bfrag8 wr[8][4];
#pragma unroll
  for (int kb = 0; kb < 8; ++kb)
#pragma unroll
    for (int g = 0; g < 4; ++g) {
      int n = g * 128 + j;
      wr[kb][g] = *(const bfrag8*)(Wp + (size_t)kb * 16384 + n * 32 + kq * 8);
    }

  __syncthreads();

  f32x4 acc[4][4];
#pragma unroll
  for (int m = 0; m < 4; ++m)
#pragma unroll
    for (int g = 0; g < 4; ++g) acc[m][g] = (f32x4){0.f, 0.f, 0.f, 0.f};

  const char* Ab = (const char*)Ah;
  const char* Al8 = (const char*)Al;
#pragma unroll
  for (int kb = 0; kb < 8; ++kb) {
    bfrag8 ah[4], al[4];
#pragma unroll
    for (int m = 0; m < 4; ++m) {
      int rr = m * 16 + mfr;
      int cs = ((((kb * 4 + kq)) ^ (rr & 7)) << 4);
      ah[m] = *(const bfrag8*)(Ab + rr * 512 + cs);
      al[m] = *(const bfrag8*)(Al8 + rr * 512 + cs);
    }
#pragma unroll
    for (int m = 0; m < 4; ++m)
#pragma unroll
      for (int g = 0; g < 4; ++g) {
        acc[m][g] = __builtin_amdgcn_mfma_f32_16x16x32_bf16(ah[m], wr[kb][g], acc[m][g], 0, 0, 0);
        acc[m][g] = __builtin_amdgcn_mfma_f32_16x16x32_bf16(al[m], wr[kb][g], acc[m][g], 0, 0, 0);
      }
  }

#pragma unroll
  for (int g = 0; g < 4; ++g) {
    float b = bc[g * 128 + j];
#pragma unroll
    for (int m = 0; m < 4; ++m)
#pragma unroll
      for (int reg = 0; reg < 4; ++reg) {
        int rr = m * 16 + kq * 4 + reg;
        gx[((size_t)(r0 + rr)) * 512 + g * 128 + j] = acc[m][g][reg] + b;
      }
  }
}

// ---------------- fwd LSTM step 0 (h0=c0=0): pure pointwise ----------------
__global__ __launch_bounds__(256) void k_lstm0(const float* __restrict__ gxf, float* __restrict__ yf)
{
  int i = blockIdx.x * 256 + threadIdx.x;  // 131072
  int row = i >> 7, j = i & 127;
  const float* gp = gxf + (size_t)row * 512;
  float cn = sig_(gp[j]) * tanhf(gp[256 + j]);
  yf[i] = sig_(gp[384 + j]) * tanhf(cn);
}

// ---------------- bwd LSTM recurrence: 5 steps in one kernel ----------------
__global__ __launch_bounds__(512) void k_lstm_rec(
    const float* __restrict__ gxb, const unsigned short* __restrict__ Whh,
    float* __restrict__ yb)
{
  __shared__ alignas(16) unsigned short Hh[4096], Hl[4096];  // 32 rows x 128 ch
  const int tid = threadIdx.x;
  const int lane = tid & 63;
  const int wv = tid >> 6;
  const int mfr = lane & 15;
  const int kq = lane >> 4;
  const int r0 = blockIdx.x * 32;
  const int j = wv * 16 + mfr;

  bfrag8 whh[4][4];
#pragma unroll
  for (int kb = 0; kb < 4; ++kb)
#pragma unroll
    for (int g = 0; g < 4; ++g) {
      int n = g * 128 + j;
      whh[kb][g] = *(const bfrag8*)(Whh + (size_t)kb * 16384 + n * 32 + kq * 8);
    }

  float cc[2][4];
#pragma unroll
  for (int m = 0; m < 2; ++m)
#pragma unroll
    for (int reg = 0; reg < 4; ++reg) {
      int rr = m * 16 + kq * 4 + reg;
      const float* gp = gxb + ((size_t)(4 * NG) + r0 + rr) * 512;
      float cn = sig_(gp[j]) * tanhf(gp[256 + j]);
      cc[m][reg] = cn;
      float hh = sig_(gp[384 + j]) * tanhf(cn);
      unsigned short hb16 = bf16r_(hh);
      unsigned short lb16 = bf16r_(hh - bf16tof_(hb16));
      int si = rr * 128 + (((j >> 3) ^ (rr & 7)) << 3) + (j & 7);
      Hh[si] = hb16; Hl[si] = lb16;
    }
  __syncthreads();

  for (int t = 3; t >= 0; --t) {
    f32x4 acc[2][4];
#pragma unroll
    for (int m = 0; m < 2; ++m)
#pragma unroll
      for (int g = 0; g < 4; ++g) acc[m][g] = (f32x4){0.f, 0.f, 0.f, 0.f};
    const char* Bh = (const char*)Hh;
    const char* Bl = (const char*)Hl;
#pragma unroll
    for (int kb = 0; kb < 4; ++kb) {
      bfrag8 ah[2], al[2];
#pragma unroll
      for (int m = 0; m < 2; ++m) {
        int rr = m * 16 + mfr;
        int cs = (((kb * 4 + kq) ^ (rr & 7)) << 4);
        ah[m] = *(const bfrag8*)(Bh + rr * 256 + cs);
        al[m] = *(const bfrag8*)(Bl + rr * 256 + cs);
      }
#pragma unroll
      for (int m = 0; m < 2; ++m)
#pragma unroll
        for (int g = 0; g < 4; ++g) {
          acc[m][g] = __builtin_amdgcn_mfma_f32_16x16x32_bf16(ah[m], whh[kb][g], acc[m][g], 0, 0, 0);
          acc[m][g] = __builtin_amdgcn_mfma_f32_16x16x32_bf16(al[m], whh[kb][g], acc[m][g], 0, 0, 0);
        }
    }
    __syncthreads();
#pragma unroll
    for (int m = 0; m < 2; ++m)
#pragma unroll
      for (int reg = 0; reg < 4; ++reg) {
        int rr = m * 16 + kq * 4 + reg;
        const float* gp = gxb + ((size_t)(t * NG) + r0 + rr) * 512;
        float g0 = acc[m][0][reg] + gp[j];
        float g1 = acc[m][1][reg] + gp[128 + j];
        float g2 = acc[m][2][reg] + gp[256 + j];
        float g3 = acc[m][3][reg] + gp[384 + j];
        float cn = fmaf(sig_(g1), cc[m][reg], sig_(g0) * tanhf(g2));
        cc[m][reg] = cn;
        float hh = sig_(g3) * tanhf(cn);
        if (t > 0) {
          unsigned short hb16 = bf16r_(hh);
          unsigned short lb16 = bf16r_(hh - bf16tof_(hb16));
          int si = rr * 128 + (((j >> 3) ^ (rr & 7)) << 3) + (j & 7);
          Hh[si] = hb16; Hl[si] = lb16;
        } else {
          yb[(size_t)(r0 + rr) * 128 + j] = hh;
        }
      }
    if (t > 0) __syncthreads();
  }
}

// ---------------- final projection ----------------
__global__ __launch_bounds__(256) void k_final(
    const float* __restrict__ yf, const float* __restrict__ yb,
    const float* __restrict__ W_out, const float* __restrict__ b_out,
    float* __restrict__ out)
{
  int tid = threadIdx.x;
  int g = blockIdx.x * 4 + (tid >> 6);
  int lane = tid & 63;
  float a0 = 0.f, a1 = 0.f;
  for (int k = lane; k < 128; k += 64) {
    float v = yf[g * 128 + k];
    a0 = fmaf(v, W_out[k * 2 + 0], a0);
    a1 = fmaf(v, W_out[k * 2 + 1], a1);
    float u = yb[g * 128 + k];
    a0 = fmaf(u, W_out[(128 + k) * 2 + 0], a0);
    a1 = fmaf(u, W_out[(128 + k) * 2 + 1], a1);
  }
#pragma unroll
  for (int o = 32; o > 0; o >>= 1) { a0 += __shfl_xor(a0, o); a1 += __shfl_xor(a1, o); }
  if (lane == 0) {
    out[g * 2 + 0] = a0 + b_out[0];
    out[g * 2 + 1] = a1 + b_out[1];
  }
}

extern "C" void kernel_launch(void* const* d_in, const int* in_sizes, int n_in,
                              void* d_out, int out_size, void* d_ws, size_t ws_size,
                              hipStream_t stream)
{
  (void)in_sizes; (void)n_in; (void)out_size; (void)ws_size;
  const float* feats   = (const float*)d_in[0];
  const int*   src     = (const int*)d_in[1];
  const int*   dst     = (const int*)d_in[2];
  const int*   n2g     = (const int*)d_in[3];
  const float* W_in    = (const float*)d_in[4];
  const float* b_in    = (const float*)d_in[5];
  const float* bng     = (const float*)d_in[6];
  const float* bnb     = (const float*)d_in[7];
  const float* bnm     = (const float*)d_in[8];
  const float* bnv     = (const float*)d_in[9];
  const float* gw_ih   = (const float*)d_in[10];
  const float* gw_hh   = (const float*)d_in[11];
  const float* gb_ih   = (const float*)d_in[12];
  const float* gb_hh   = (const float*)d_in[13];
  const float* w_aw    = (const float*)d_in[14];
  const float* b_aw    = (const float*)d_in[15];
  const float* lwih_f  = (const float*)d_in[16];
  const float* lwhh_f  = (const float*)d_in[17];
  const float* lbih_f  = (const float*)d_in[18];
  const float* lbhh_f  = (const float*)d_in[19];
  const float* lwih_b  = (const float*)d_in[20];
  const float* lwhh_b  = (const float*)d_in[21];
  const float* lbih_b  = (const float*)d_in[22];
  const float* lbhh_b  = (const float*)d_in[23];
  const float* W_out   = (const float*)d_in[24];
  const float* b_out   = (const float*)d_in[25];
  float* out = (float*)d_out;
  (void)lwhh_f;  // fwd w_hh unused: h0 = 0 and only step 0 of fwd LSTM is needed

  float* ws = (float*)d_ws;
  size_t off = 0;
  auto alloc = [&](size_t n) { float* p = ws + off; off += (n + 63) & ~(size_t)63; return p; };
  float* h      = alloc((size_t)NP * 128);
  unsigned short* xhi   = (unsigned short*)alloc((size_t)NP * 64);
  unsigned short* xlo   = (unsigned short*)alloc((size_t)NP * 64);
  unsigned short* agghi = (unsigned short*)alloc((size_t)NP * 64);
  unsigned short* agglo = (unsigned short*)alloc((size_t)NP * 64);
  unsigned short* Wp    = (unsigned short*)alloc(65536);
  float* bcat   = alloc(512);
  float* wnode  = alloc(NN);
  float* bnp    = alloc(NL * 256);
  unsigned short* xplh = (unsigned short*)alloc((size_t)NL * NG * 128);
  unsigned short* xpll = (unsigned short*)alloc((size_t)NL * NG * 128);
  unsigned short* Wihf = (unsigned short*)alloc(65536);
  unsigned short* Wihb = (unsigned short*)alloc(65536);
  unsigned short* Whhb = (unsigned short*)alloc(32768);
  float* bcf    = alloc(512);
  float* bcb    = alloc(512);
  float* gxb    = alloc((size_t)NL * NG * 512);
  float* gxf    = alloc((size_t)NG * 512);
  float* yf     = alloc((size_t)NG * 128);
  float* yb     = alloc((size_t)NG * 128);
  int* deg    = (int*)alloc(NN);
  int* rowptr = (int*)alloc(NN + 1);
  int* pos    = (int*)alloc(NN);
  int* colidx = (int*)alloc(NE);
  int* bsum   = (int*)alloc(256);
  int* boff   = (int*)alloc(256);

  // ---- one-time: CSR build + weight prepacks + BN prep (all layers) ----
  hipMemsetAsync(deg, 0, (size_t)NN * sizeof(int), stream);
  k_hist<<<(NE + 255) / 256, 256, 0, stream>>>(dst, deg);
  k_scan1<<<196, 256, 0, stream>>>(deg, bsum);
  k_scan2<<<1, 256, 0, stream>>>(bsum, boff, rowptr);
  k_scan3<<<196, 256, 0, stream>>>(deg, boff, rowptr);
  hipMemcpyAsync(pos, rowptr, (size_t)NN * sizeof(int), hipMemcpyDeviceToDevice, stream);
  k_fill<<<(NE + 255) / 256, 256, 0, stream>>>(src, dst, pos, colidx);
  k_wpack<<<512, 256, 0, stream>>>(gw_ih, gw_hh, gb_ih, gb_hh, Wp, bcat);
  k_wpack_lstm<<<1280, 256, 0, stream>>>(lwih_f, lwih_b, lwhh_b, lbih_f, lbhh_f, lbih_b, lbhh_b,
                                         Wihf, Wihb, Whhb, bcf, bcb);
  k_bnprep_all<<<NL, 128, 0, stream>>>(bng, bnb, bnm, bnv, bnp);

  k_input_proj<<<1024, 256, 0, stream>>>(feats, W_in, b_in, h);

  for (int l = 0; l < NL; ++l) {
    const float* bnpl = bnp + l * 256;
    k_prep<<<3125, 256, 0, stream>>>(h, bnpl, w_aw, b_aw, xhi, xlo, wnode);
    k_gather<<<NN / 4, 256, 0, stream>>>(xhi, rowptr, colidx, agghi, agglo);
    k_readout<<<NG, 256, 0, stream>>>(h, wnode, n2g, xplh, xpll, l);
    k_gru_mfma<<<GRUGRID, 512, 0, stream>>>(h, xhi, xlo, agghi, agglo, Wp, bcat, bnpl);
  }

  // ---- LSTM: x-gates for all steps (fwd step0 + bwd 5 steps), then recurrence ----
  k_xgates<<<96, 512, 0, stream>>>(xplh, xpll, Wihb, Wihf, bcb, bcf, gxb, gxf);
  k_lstm0<<<512, 256, 0, stream>>>(gxf, yf);
  k_lstm_rec<<<32, 512, 0, stream>>>(gxb, Whhb, yb);

  k_final<<<NG / 4, 256, 0, stream>>>(yf, yb, W_out, b_out, out);
}